// Round 7
// baseline (1288.832 us; speedup 1.0000x reference)
//
#include <hip/hip_runtime.h>
#include <math.h>

// ---------------------------------------------------------------------------
// IsgnBeatMeasEncoder — round 11: fuse gather_act INTO gate_gemm.
// Round-10 post-mortem: occupancy fixes delivered (1576 -> 1259us). Remainder
// minus rec64 is ~1018us over ~35 sub-120us dispatches; models put real work
// at ~400us -> ~500us is dispatch-boundary tax (~13us each). Lever: fewer
// dispatches + less intermediate traffic.
// Round 11: k_gate_gemm gathers its own A-tile inline from nh/nh2 via CSR
// lists cached in LDS (16KB). act buffer + 8 gather dispatches + 210MB HBM
// round-trip eliminated. Sum order per element identical (list order) ->
// bit-identical. LDS 38KB -> still 2 blocks/CU. All else = round 10.
// Falsification: if total >=1240, boundary tax theory wrong -> round 12
// measures it directly before further fusion.
// ---------------------------------------------------------------------------

#define NN    1024
#define EE    10
#define INDIM 78
#define SS    320
#define SECD  128
#define NB    256
#define NM    64
#define CAP   64     // max nonzeros per adjacency column (mean ~10.2)

typedef float v2f __attribute__((ext_vector_type(2)));

__device__ __forceinline__ void pkfma(v2f& a, v2f x, v2f y){
    asm("v_pk_fma_f32 %0, %1, %2, %0" : "+v"(a) : "v"(x), "v"(y));
}
// a.lo += x.lo*b.lo ; a.hi += x.hi*b.lo   (broadcast LOW half of b)
__device__ __forceinline__ void pkfma_blo(v2f& a, v2f x, v2f b){
    asm("v_pk_fma_f32 %0, %1, %2, %0 op_sel:[0,0,0] op_sel_hi:[1,0,1]"
        : "+v"(a) : "v"(x), "v"(b));
}
// a.lo += x.lo*b.hi ; a.hi += x.hi*b.hi   (broadcast HIGH half of b)
__device__ __forceinline__ void pkfma_bhi(v2f& a, v2f x, v2f b){
    asm("v_pk_fma_f32 %0, %1, %2, %0 op_sel:[0,1,0] op_sel_hi:[1,1,1]"
        : "+v"(a) : "v"(x), "v"(b));
}

__device__ __forceinline__ float fsig(float x){
    return __builtin_amdgcn_rcpf(1.f + __expf(-x));
}
__device__ __forceinline__ float ftanh(float x){
    // tanh(x) = 1 - 2/(exp(2x)+1); exp overflow -> inf -> rcp -> 0 -> 1 (correct)
    return 1.f - 2.f*__builtin_amdgcn_rcpf(1.f + __expf(2.f*x));
}

// ---------------- note_fc: x0 = tanh(nodes @ W + b); nh = [0(192) | x0] ------------
__global__ void k_note_fc(const float* __restrict__ nodes, const float* __restrict__ W,
                          const float* __restrict__ b, float* __restrict__ nh){
    int n = blockIdx.x, s = threadIdx.x;           // 128 threads
    __shared__ float xrow[INDIM];
    if (s < INDIM) xrow[s] = nodes[n*INDIM + s];
    __syncthreads();
    float acc = b[s];
    for (int k = 0; k < INDIM; ++k) acc += xrow[k]*W[k*128 + s];
    nh[n*SS + 192 + s] = ftanh(acc);
    nh[n*SS + s] = 0.f;
    if (s < 64) nh[n*SS + 128 + s] = 0.f;
}

// ---------------- CSR build: float4 scan of each adj row ---------------------------
__global__ void k_csr_build(const float* __restrict__ adj, int* __restrict__ cnt,
                            int* __restrict__ idx){
    int em = blockIdx.x;                   // e*NN + m  (row of adj[e])
    int e = em / NN, m = em % NN;
    const float4* row4 = (const float4*)(adj + (size_t)em * NN);
    int q = threadIdx.x;                   // 256 threads, 256 float4 = 1024 cols
    float4 v = row4[q];
    int n0 = q*4;
    if (v.x != 0.f){ int p = atomicAdd(&cnt[e*NN + n0+0], 1); if (p < CAP) idx[((size_t)e*NN + n0+0)*CAP + p] = m; }
    if (v.y != 0.f){ int p = atomicAdd(&cnt[e*NN + n0+1], 1); if (p < CAP) idx[((size_t)e*NN + n0+1)*CAP + p] = m; }
    if (v.z != 0.f){ int p = atomicAdd(&cnt[e*NN + n0+2], 1); if (p < CAP) idx[((size_t)e*NN + n0+2)*CAP + p] = m; }
    if (v.w != 0.f){ int p = atomicAdd(&cnt[e*NN + n0+3], 1); if (p < CAP) idx[((size_t)e*NN + n0+3)*CAP + p] = m; }
}

// ---------------- gate GEMM w/ inline CSR gather -----------------------------------
// Block (nt,g,z): rows nt*32..+31, gate g, e-pair z. A-tile gathered on the
// fly from x (nh/nh2) via CSR lists cached in LDS; act never materialized.
// Inner loop: 8 pkfma/k (A row-pairs packed, B broadcast via op_sel halves).
__global__ __launch_bounds__(256) void k_gate_gemm(const float* __restrict__ x,
        const int* __restrict__ cnt, const int* __restrict__ idx,
        const float* __restrict__ wz, const float* __restrict__ wr,
        const float* __restrict__ wh, float* __restrict__ part){
    __shared__ float A[32*36];     // [kk][row], 32 rows pad 36
    __shared__ float B[32*132];    // [kk][col], pad 132
    __shared__ int   idx_l[2][32][CAP];
    __shared__ int   cnt_l[2][32];
    int nt = blockIdx.x, g = blockIdx.y, z = blockIdx.z;
    const float* W = (g==0) ? wz : ((g==1) ? wr : wh);
    int tid = threadIdx.x;
    int tx = tid & 31;             // cols tx*4 .. +3
    int ty = tid >> 5;             // rows ty*4 .. +3
    {   // cache CSR lists: 64 (eh,row) pairs, 4 threads each
        int pr = tid >> 2;                 // 0..63
        int eh = pr >> 5, r = pr & 31;
        int en = (2*z + eh)*NN + nt*32 + r;
        int c = cnt[en]; if (c > CAP) c = CAP;
        if ((tid & 3) == 0) cnt_l[eh][r] = c;
        const int* gl = idx + (size_t)en*CAP;
        for (int j = tid & 3; j < c; j += 4) idx_l[eh][r][j] = gl[j];
    }
    v2f acc[2][4];                 // [row-pair][col]; .x=row ty*4+2rp, .y=+1
    #pragma unroll
    for (int i=0;i<2;i++)
        #pragma unroll
        for (int j=0;j<4;j++) acc[i][j] = (v2f){0.f,0.f};
    __syncthreads();
    for (int eh = 0; eh < 2; ++eh){
        const float* We = W + (size_t)(2*z + eh)*SS*SECD;
        for (int kc = 0; kc < SS; kc += 32){
            {                                      // gather A: 32 rows x 32 k
                int r = tid >> 3, q = tid & 7;     // thread: row r, f-quad q
                int c = cnt_l[eh][r];
                float ax=0.f, ay=0.f, az=0.f, aw=0.f;
                const float* xb = x + kc + q*4;
                for (int j = 0; j < c; ++j){
                    int m = idx_l[eh][r][j];
                    float4 v = *(const float4*)(xb + (size_t)m*SS);
                    ax += v.x; ay += v.y; az += v.z; aw += v.w;
                }
                int k4 = q*4;
                A[(k4+0)*36 + r] = ax; A[(k4+1)*36 + r] = ay;
                A[(k4+2)*36 + r] = az; A[(k4+3)*36 + r] = aw;
            }
            #pragma unroll
            for (int i=0;i<4;i++){                 // B: 32 k x 128 cols
                int lin4 = tid + i*256;            // 1024 float4
                int kk = lin4 >> 5;
                int c4 = (lin4 & 31) << 2;
                *((float4*)(B + kk*132 + c4)) = *(const float4*)(We + (kc+kk)*SECD + c4);
            }
            __syncthreads();
            #pragma unroll 8
            for (int k=0;k<32;k++){
                const v2f* A2 = (const v2f*)(A + k*36 + ty*4);   // wave-uniform
                v2f a01 = A2[0], a23 = A2[1];
                float4 b = *(const float4*)(B + k*132 + tx*4);   // r8-proven pattern
                v2f b01 = {b.x, b.y}, b23 = {b.z, b.w};
                pkfma_blo(acc[0][0], a01, b01); pkfma_bhi(acc[0][1], a01, b01);
                pkfma_blo(acc[0][2], a01, b23); pkfma_bhi(acc[0][3], a01, b23);
                pkfma_blo(acc[1][0], a23, b01); pkfma_bhi(acc[1][1], a23, b01);
                pkfma_blo(acc[1][2], a23, b23); pkfma_bhi(acc[1][3], a23, b23);
            }
            __syncthreads();
        }
    }
    float* P = part + ((size_t)z*NN + (size_t)nt*32)*384 + g*SECD;
    int r0 = ty*4;
    *(float4*)(P + (size_t)(r0+0)*384 + tx*4) =
        make_float4(acc[0][0].x, acc[0][1].x, acc[0][2].x, acc[0][3].x);
    *(float4*)(P + (size_t)(r0+1)*384 + tx*4) =
        make_float4(acc[0][0].y, acc[0][1].y, acc[0][2].y, acc[0][3].y);
    *(float4*)(P + (size_t)(r0+2)*384 + tx*4) =
        make_float4(acc[1][0].x, acc[1][1].x, acc[1][2].x, acc[1][3].x);
    *(float4*)(P + (size_t)(r0+3)*384 + tx*4) =
        make_float4(acc[1][0].y, acc[1][1].y, acc[1][2].y, acc[1][3].y);
}

// ---------------- GRU update, 2 notes/block (512 blocks, 2/CU) ---------------------
__global__ void k_gru(float* __restrict__ x, const float* __restrict__ part,
        const float* __restrict__ uz, const float* __restrict__ ur, const float* __restrict__ uh,
        const float* __restrict__ bz, const float* __restrict__ br, const float* __restrict__ bh){
    int n0 = blockIdx.x*2, s = threadIdx.x;        // 128 threads
    __shared__ float xs[2][SECD], rx[2][SECD];
    #pragma unroll
    for (int j=0;j<2;j++) xs[j][s] = x[(n0+j)*SS + 192 + s];
    __syncthreads();
    float mz[2]={0,0}, mr[2]={0,0}, mh[2]={0,0};
    for (int sp=0; sp<5; sp++){
        const float* Pp = part + ((size_t)sp*NN + n0)*384;
        #pragma unroll
        for (int j=0;j<2;j++){
            mz[j] += Pp[j*384 + s];
            mr[j] += Pp[j*384 + 128 + s];
            mh[j] += Pp[j*384 + 256 + s];
        }
    }
    float dz[2]={0,0}, dr[2]={0,0};
    for (int k=0;k<SECD;k++){
        float wz_ = uz[k*SECD + s], wr_ = ur[k*SECD + s];
        #pragma unroll
        for (int j=0;j<2;j++){ float xv = xs[j][k]; dz[j] += xv*wz_; dr[j] += xv*wr_; }
    }
    float zz[2], rr[2];
    #pragma unroll
    for (int j=0;j<2;j++){
        zz[j] = fsig(mz[j] + dz[j] + bz[s]);
        rr[j] = fsig(mr[j] + dr[j] + br[s]);
        rx[j][s] = rr[j]*xs[j][s];
    }
    __syncthreads();
    float dh[2]={0,0};
    for (int k=0;k<SECD;k++){
        float wh_ = uh[k*SECD + s];
        #pragma unroll
        for (int j=0;j<2;j++) dh[j] += rx[j][k]*wh_;
    }
    #pragma unroll
    for (int j=0;j<2;j++){
        float h = ftanh(mh[j] + dh[j] + bh[s]);
        x[(n0+j)*SS + 192 + s] = (1.f - zz[j])*xs[j][s] + rr[j]*h;
    }
}

// ---------------- nb = relu(nh @ gb_w + gb_b) -> nh2, transposed tile + pkfma ------
__global__ void k_gb(const float* __restrict__ nh, const float* __restrict__ W,
                     const float* __restrict__ b, float* __restrict__ nb){
    int n0 = blockIdx.x*8, s = threadIdx.x;        // 320 threads
    __shared__ float xr_t[SS*8];                   // [k][j] — j-pairs adjacent
    {
        float v0 = nh[(n0+0)*SS + s], v1 = nh[(n0+1)*SS + s];
        float v2 = nh[(n0+2)*SS + s], v3 = nh[(n0+3)*SS + s];
        float v4 = nh[(n0+4)*SS + s], v5 = nh[(n0+5)*SS + s];
        float v6 = nh[(n0+6)*SS + s], v7 = nh[(n0+7)*SS + s];
        *(float4*)(xr_t + s*8 + 0) = make_float4(v0,v1,v2,v3);
        *(float4*)(xr_t + s*8 + 4) = make_float4(v4,v5,v6,v7);
    }
    __syncthreads();
    float bv = b[s];
    v2f a01={bv,bv}, a23={bv,bv}, a45={bv,bv}, a67={bv,bv};
    for (int k=0;k<SS;k++){
        float wv = W[k*SS + s];
        v2f ws = {wv, wv};
        const v2f* xp = (const v2f*)(xr_t + k*8);  // uniform addr -> broadcast
        pkfma(a01, xp[0], ws);
        pkfma(a23, xp[1], ws);
        pkfma(a45, xp[2], ws);
        pkfma(a67, xp[3], ws);
    }
    nb[(n0+0)*SS + s] = fmaxf(a01.x, 0.f);
    nb[(n0+1)*SS + s] = fmaxf(a01.y, 0.f);
    nb[(n0+2)*SS + s] = fmaxf(a23.x, 0.f);
    nb[(n0+3)*SS + s] = fmaxf(a23.y, 0.f);
    nb[(n0+4)*SS + s] = fmaxf(a45.x, 0.f);
    nb[(n0+5)*SS + s] = fmaxf(a45.y, 0.f);
    nb[(n0+6)*SS + s] = fmaxf(a67.x, 0.f);
    nb[(n0+7)*SS + s] = fmaxf(a67.y, 0.f);
}

// ---------------- FUSED beat attention + lstm_pre (transposed tile + pkfma) --------
__global__ __launch_bounds__(256) void k_batt_fused(
        const float* __restrict__ nh, const float* __restrict__ nh2,
        const float* __restrict__ W, const float* __restrict__ b,
        const float* __restrict__ cvec,
        const float* __restrict__ wi_f, const float* __restrict__ b_f,
        const float* __restrict__ wi_b, const float* __restrict__ b_b,
        float* __restrict__ gf, float* __restrict__ gbo){
    int g = blockIdx.x, s = threadIdx.x;           // 256 threads
    __shared__ float xr_t[256*4];                  // [k][j]
    __shared__ float simw[4][8];
    __shared__ float wgt[4][8];
    __shared__ float bnode[256];
    {
        float c0,c1,c2,c3;
        if (s < 128){
            c0 = nh[(g*4+0)*SS + 192 + s]; c1 = nh[(g*4+1)*SS + 192 + s];
            c2 = nh[(g*4+2)*SS + 192 + s]; c3 = nh[(g*4+3)*SS + 192 + s];
        } else {
            c0 = nh2[(g*4+0)*SS + 64 + s]; c1 = nh2[(g*4+1)*SS + 64 + s];
            c2 = nh2[(g*4+2)*SS + 64 + s]; c3 = nh2[(g*4+3)*SS + 64 + s];
        }
        *(float4*)(xr_t + s*4) = make_float4(c0,c1,c2,c3);
    }
    __syncthreads();
    float bias = b[s];
    v2f ac01 = {bias,bias}, ac23 = {bias,bias};
    for (int k=0;k<256;k++){
        float wv = W[k*256 + s];
        v2f ws = {wv, wv};
        const v2f* xp = (const v2f*)(xr_t + k*4);
        pkfma(ac01, xp[0], ws);
        pkfma(ac23, xp[1], ws);
    }
    float accj[4] = {ac01.x, ac01.y, ac23.x, ac23.y};
    float cv = cvec[s];
    int h = s >> 5;                                // head (HD=32)
    #pragma unroll
    for (int j=0;j<4;j++){
        float p = ftanh(accj[j])*cv;
        #pragma unroll
        for (int off=16; off>0; off>>=1) p += __shfl_down(p, off);
        if ((s & 31) == 0) simw[j][h] = p;
    }
    __syncthreads();
    if (s < 8){
        float v0=simw[0][s], v1=simw[1][s], v2=simw[2][s], v3=simw[3][s];
        float mx = fmaxf(fmaxf(v0,v1), fmaxf(v2,v3));
        float e0=__expf(v0-mx), e1=__expf(v1-mx), e2=__expf(v2-mx), e3=__expf(v3-mx);
        float den = e0+e1+e2+e3;
        wgt[0][s]=e0/den; wgt[1][s]=e1/den; wgt[2][s]=e2/den; wgt[3][s]=e3/den;
    }
    __syncthreads();
    float4 xs4 = *(const float4*)(xr_t + s*4);
    float o = xs4.x*wgt[0][h] + xs4.y*wgt[1][h] + xs4.z*wgt[2][h] + xs4.w*wgt[3][h];
    bnode[s] = o;
    __syncthreads();
    // pre-GEMV, both directions: contiguous weight rows as v2f, elementwise pkfma
    v2f afA = {b_f[s], 0.f}, afB = {0.f, 0.f};
    v2f abA = {b_b[s], 0.f}, abB = {0.f, 0.f};
    const v2f* wfp = (const v2f*)(wi_f + (size_t)s*256);
    const v2f* wbp = (const v2f*)(wi_b + (size_t)s*256);
    const v2f* bp  = (const v2f*)bnode;
    for (int k2=0;k2<128;k2+=2){
        v2f x01 = bp[k2], x23 = bp[k2+1];
        pkfma(afA, wfp[k2], x01); pkfma(afB, wfp[k2+1], x23);
        pkfma(abA, wbp[k2], x01); pkfma(abB, wbp[k2+1], x23);
    }
    gf [g*256 + s] = (afA.x + afA.y) + (afB.x + afB.y);
    gbo[g*256 + s] = (abA.x + abA.y) + (abB.x + abB.y);
}

// ---------------- FUSED measure attention + lstm_pre -------------------------------
__global__ __launch_bounds__(128) void k_matt_fused(
        const float* __restrict__ bh,   // beat_hidden [256][128]
        const float* __restrict__ W, const float* __restrict__ b,
        const float* __restrict__ cvec,
        const float* __restrict__ wi_f, const float* __restrict__ b_f,
        const float* __restrict__ wi_b, const float* __restrict__ b_b,
        float* __restrict__ gf, float* __restrict__ gbo){
    int g = blockIdx.x, s = threadIdx.x;           // 128 threads
    __shared__ float xr_t[128*4];                  // [k][j]
    __shared__ float simw[4][8];
    __shared__ float wgt[4][8];
    __shared__ float mnode[128];
    {
        float c0 = bh[(g*4+0)*128 + s], c1 = bh[(g*4+1)*128 + s];
        float c2 = bh[(g*4+2)*128 + s], c3 = bh[(g*4+3)*128 + s];
        *(float4*)(xr_t + s*4) = make_float4(c0,c1,c2,c3);
    }
    __syncthreads();
    float bias = b[s];
    v2f ac01 = {bias,bias}, ac23 = {bias,bias};
    for (int k=0;k<128;k++){
        float wv = W[k*128 + s];
        v2f ws = {wv, wv};
        const v2f* xp = (const v2f*)(xr_t + k*4);
        pkfma(ac01, xp[0], ws);
        pkfma(ac23, xp[1], ws);
    }
    float accj[4] = {ac01.x, ac01.y, ac23.x, ac23.y};
    float cv = cvec[s];
    int h = s >> 4;                                // head (HD=16)
    #pragma unroll
    for (int j=0;j<4;j++){
        float p = ftanh(accj[j])*cv;
        #pragma unroll
        for (int off=8; off>0; off>>=1) p += __shfl_down(p, off);
        if ((s & 15) == 0) simw[j][h] = p;
    }
    __syncthreads();
    if (s < 8){
        float v0=simw[0][s], v1=simw[1][s], v2=simw[2][s], v3=simw[3][s];
        float mx = fmaxf(fmaxf(v0,v1), fmaxf(v2,v3));
        float e0=__expf(v0-mx), e1=__expf(v1-mx), e2=__expf(v2-mx), e3=__expf(v3-mx);
        float den = e0+e1+e2+e3;
        wgt[0][s]=e0/den; wgt[1][s]=e1/den; wgt[2][s]=e2/den; wgt[3][s]=e3/den;
    }
    __syncthreads();
    float4 xs4 = *(const float4*)(xr_t + s*4);
    float o = xs4.x*wgt[0][h] + xs4.y*wgt[1][h] + xs4.z*wgt[2][h] + xs4.w*wgt[3][h];
    mnode[s] = o;
    __syncthreads();
    v2f afA = {b_f[s], 0.f}, afB = {0.f, 0.f};
    v2f abA = {b_b[s], 0.f}, abB = {0.f, 0.f};
    const v2f* wfp = (const v2f*)(wi_f + (size_t)s*128);
    const v2f* wbp = (const v2f*)(wi_b + (size_t)s*128);
    const v2f* bp  = (const v2f*)mnode;
    for (int k2=0;k2<64;k2+=2){
        v2f x01 = bp[k2], x23 = bp[k2+1];
        pkfma(afA, wfp[k2], x01); pkfma(afB, wfp[k2+1], x23);
        pkfma(abA, wbp[k2], x01); pkfma(abB, wbp[k2+1], x23);
    }
    gf [g*128 + s] = (afA.x + afA.y) + (afB.x + afB.y);
    gbo[g*128 + s] = (abA.x + abA.y) + (abB.x + abB.y);
}

// ---------------- LSTM recurrence, H=64 T=256: round-9 form (best measured) --------
__global__ __launch_bounds__(256)
__attribute__((amdgpu_waves_per_eu(1, 1)))
void k_lstm_rec64(
        const float* __restrict__ gin_f, const float* __restrict__ wh_f,
        const float* __restrict__ gin_b, const float* __restrict__ wh_b,
        float* __restrict__ hid /* [T][128] */){
    const int H = 64, T = 256;
    int dir = blockIdx.x;
    const float* gin = dir ? gin_b : gin_f;
    const float* wh  = dir ? wh_b  : wh_f;
    int gi = threadIdx.x;                  // gate-row in [0, 256)
    int l  = gi & 63;                      // h-index this gate feeds
    const v2f* wp = (const v2f*)(wh + (size_t)gi*H);
    v2f w00=wp[0], w01=wp[1], w02=wp[2], w03=wp[3], w04=wp[4], w05=wp[5], w06=wp[6], w07=wp[7],
        w08=wp[8], w09=wp[9], w10=wp[10],w11=wp[11],w12=wp[12],w13=wp[13],w14=wp[14],w15=wp[15],
        w16=wp[16],w17=wp[17],w18=wp[18],w19=wp[19],w20=wp[20],w21=wp[21],w22=wp[22],w23=wp[23],
        w24=wp[24],w25=wp[25],w26=wp[26],w27=wp[27],w28=wp[28],w29=wp[29],w30=wp[30],w31=wp[31];
    __shared__ __align__(16) float hs[H];
    __shared__ float gsum[2][4*H];
    float c = 0.f;
    if (gi < H) hs[gi] = 0.f;
    __syncthreads();
    float gcur = gin[(dir ? (T-1) : 0)*4*H + gi];
    for (int step=0; step<T; step++){
        int t = dir ? (T-1-step) : step;
        float gnext = 0.f;
        if (step+1 < T) gnext = gin[(dir ? (T-2-step) : (step+1))*4*H + gi];
        const v2f* hv = (const v2f*)hs;            // uniform addr -> LDS broadcast
        v2f h00=hv[0], h01=hv[1], h02=hv[2], h03=hv[3], h04=hv[4], h05=hv[5], h06=hv[6], h07=hv[7],
            h08=hv[8], h09=hv[9], h10=hv[10],h11=hv[11],h12=hv[12],h13=hv[13],h14=hv[14],h15=hv[15],
            h16=hv[16],h17=hv[17],h18=hv[18],h19=hv[19],h20=hv[20],h21=hv[21],h22=hv[22],h23=hv[23],
            h24=hv[24],h25=hv[25],h26=hv[26],h27=hv[27],h28=hv[28],h29=hv[29],h30=hv[30],h31=hv[31];
        v2f A0={gcur,0.f}, A1={0.f,0.f}, A2={0.f,0.f}, A3={0.f,0.f};
        pkfma(A0,w00,h00); pkfma(A1,w01,h01); pkfma(A2,w02,h02); pkfma(A3,w03,h03);
        pkfma(A0,w04,h04); pkfma(A1,w05,h05); pkfma(A2,w06,h06); pkfma(A3,w07,h07);
        pkfma(A0,w08,h08); pkfma(A1,w09,h09); pkfma(A2,w10,h10); pkfma(A3,w11,h11);
        pkfma(A0,w12,h12); pkfma(A1,w13,h13); pkfma(A2,w14,h14); pkfma(A3,w15,h15);
        pkfma(A0,w16,h16); pkfma(A1,w17,h17); pkfma(A2,w18,h18); pkfma(A3,w19,h19);
        pkfma(A0,w20,h20); pkfma(A1,w21,h21); pkfma(A2,w22,h22); pkfma(A3,w23,h23);
        pkfma(A0,w24,h24); pkfma(A1,w25,h25); pkfma(A2,w26,h26); pkfma(A3,w27,h27);
        pkfma(A0,w28,h28); pkfma(A1,w29,h29); pkfma(A2,w30,h30); pkfma(A3,w31,h31);
        float* gs = gsum[step & 1];
        gs[gi] = ((A0.x+A0.y) + (A1.x+A1.y)) + ((A2.x+A2.y) + (A3.x+A3.y));
        __syncthreads();                           // the ONLY barrier per step
        float ig = gs[l], fg = gs[H+l], gg = gs[2*H+l], og = gs[3*H+l];
        c = fsig(fg)*c + fsig(ig)*ftanh(gg);       // all waves: identical update
        float hn = fsig(og)*ftanh(c);
        hs[l] = hn;                                // every wave writes full hs
        if (gi < H) hid[t*2*H + dir*H + gi] = hn;  // one wave publishes
        gcur = gnext;
    }
}

// ---------------- LSTM recurrence, H=32 T=64: single wave, NO barrier --------------
__global__ __launch_bounds__(64)
__attribute__((amdgpu_waves_per_eu(1, 1)))
void k_lstm_rec32(
        const float* __restrict__ gin_f, const float* __restrict__ wh_f,
        const float* __restrict__ gin_b, const float* __restrict__ wh_b,
        float* __restrict__ hid /* [T][64] */){
    const int H = 32, T = 64;
    int dir = blockIdx.x;
    const float* gin = dir ? gin_b : gin_f;
    const float* wh  = dir ? wh_b  : wh_f;
    int gi = threadIdx.x;                  // 0..63
    v2f wA[16], wB[16];
    {
        const v2f* rA = (const v2f*)(wh + (size_t)(     gi)*H);   // rows 0..63:  i|f
        const v2f* rB = (const v2f*)(wh + (size_t)(64 + gi)*H);   // rows 64..127: g|o
        #pragma unroll
        for (int k=0;k<16;k++){ wA[k]=rA[k]; wB[k]=rB[k]; }
    }
    __shared__ __align__(16) float hs[H];
    float c = 0.f;
    if (gi < H) hs[gi] = 0.f;
    __syncthreads();
    const float* gp = gin + gi;
    int ts0 = dir ? (T-1) : 0, ts1 = dir ? (T-2) : 1;
    float g0 = gp[ts0*128], g1 = gp[ts0*128 + 64];
    float n0 = gp[ts1*128], n1 = gp[ts1*128 + 64];
    bool lo = (gi < H);
    for (int step=0; step<T; step++){
        int t = dir ? (T-1-step) : step;
        float p0=0.f, p1=0.f;
        if (step+2 < T){
            int tp = dir ? (T-3-step) : (step+2);
            p0 = gp[tp*128]; p1 = gp[tp*128 + 64];
        }
        v2f aA = {g0, 0.f}, aB = {g1, 0.f};
        const v2f* hv = (const v2f*)hs;
        #pragma unroll
        for (int k=0;k<16;k++){
            v2f h2 = hv[k];
            pkfma(aA, wA[k], h2);
            pkfma(aB, wB[k], h2);
        }
        float sA = aA.x + aA.y;            // lane<32: i ; lane>=32: f
        float sB = aB.x + aB.y;            // lane<32: g ; lane>=32: o
        float pA = __shfl(sA, gi ^ 32);
        float pB = __shfl(sB, gi ^ 32);
        float i_ = lo ? sA : pA;
        float f_ = lo ? pA : sA;
        float g_ = lo ? sB : pB;
        float o_ = lo ? pB : sB;
        c = fsig(f_)*c + fsig(i_)*ftanh(g_);
        float hn = fsig(o_)*ftanh(c);
        if (lo){
            hid[t*2*H + dir*H + gi] = hn;
            hs[gi] = hn;                   // same wave: in-order LDS, no barrier
        }
        g0 = n0; g1 = n1; n0 = p0; n1 = p1;
    }
}

// ---------------- si=0: rebuild nh in place = [beat_span | meas_span | nh_sec] -----
__global__ void k_spans(float* __restrict__ nh, const float* __restrict__ bh,
                        const float* __restrict__ mh,
                        const int* __restrict__ bn, const int* __restrict__ mn){
    int n = blockIdx.x, s = threadIdx.x;           // 320 threads
    float v;
    if (s < 128)      v = bh[bn[n]*128 + s];
    else if (s < 192) v = mh[mn[n]*64 + (s-128)];
    else              v = nh[n*SS + s];            // own-thread read-then-write: safe
    nh[n*SS + s] = v;
}

// ---------------- si=1: spans + final output fused ---------------------------------
__global__ void k_spans_out(const float* __restrict__ bh, const float* __restrict__ mh,
                            const float* __restrict__ nh, const float* __restrict__ nh2,
                            const int* __restrict__ bn, const int* __restrict__ mn,
                            float* __restrict__ out){
    int n = blockIdx.x, s = threadIdx.x;           // 448 threads
    float v;
    if (s < 128)      v = bh[bn[n]*128 + s];
    else if (s < 192) v = mh[mn[n]*64 + (s-128)];
    else if (s < 320) v = nh[n*SS + s];
    else              v = nh2[n*SS + 192 + (s-320)];
    out[n*448 + s] = v;
}

// ===========================================================================
extern "C" void kernel_launch(void* const* d_in, const int* in_sizes, int n_in,
                              void* d_out, int out_size, void* d_ws, size_t ws_size,
                              hipStream_t stream) {
    const float* nodes    = (const float*)d_in[0];
    const float* adj      = (const float*)d_in[1];
    const int*   bn       = (const int*)  d_in[2];
    const int*   mn       = (const int*)  d_in[3];
    const float* fc_w     = (const float*)d_in[6];
    const float* fc_b     = (const float*)d_in[7];
    const float* g_wz[2]  = {(const float*)d_in[8],  (const float*)d_in[17]};
    const float* g_wr[2]  = {(const float*)d_in[9],  (const float*)d_in[18]};
    const float* g_wh[2]  = {(const float*)d_in[10], (const float*)d_in[19]};
    const float* g_uz[2]  = {(const float*)d_in[11], (const float*)d_in[20]};
    const float* g_ur[2]  = {(const float*)d_in[12], (const float*)d_in[21]};
    const float* g_uh[2]  = {(const float*)d_in[13], (const float*)d_in[22]};
    const float* g_bz[2]  = {(const float*)d_in[14], (const float*)d_in[23]};
    const float* g_br[2]  = {(const float*)d_in[15], (const float*)d_in[24]};
    const float* g_bh[2]  = {(const float*)d_in[16], (const float*)d_in[25]};
    const float* gb_w     = (const float*)d_in[26];
    const float* gb_b     = (const float*)d_in[27];
    const float* batt_w   = (const float*)d_in[28];
    const float* batt_b   = (const float*)d_in[29];
    const float* batt_c   = (const float*)d_in[30];
    const float* matt_w   = (const float*)d_in[31];
    const float* matt_b   = (const float*)d_in[32];
    const float* matt_c   = (const float*)d_in[33];
    const float* bwi_f    = (const float*)d_in[34];
    const float* bwh_f    = (const float*)d_in[35];
    const float* bb_f     = (const float*)d_in[36];
    const float* bwi_b    = (const float*)d_in[37];
    const float* bwh_b    = (const float*)d_in[38];
    const float* bb_b     = (const float*)d_in[39];
    const float* mwi_f    = (const float*)d_in[40];
    const float* mwh_f    = (const float*)d_in[41];
    const float* mb_f     = (const float*)d_in[42];
    const float* mwi_b    = (const float*)d_in[43];
    const float* mwh_b    = (const float*)d_in[44];
    const float* mb_b     = (const float*)d_in[45];
    float* out = (float*)d_out;

    // --- workspace layout (floats; ~14 MB) ---
    float* W_   = (float*)d_ws;
    float* nh   = W_;                       // 1024*320
    float* nh2  = nh   + 327680;            // 1024*320
    float* part = nh2  + 327680;            // 5*1024*384
    float* bgf  = part + 1966080;           // 256*256
    float* bgb  = bgf  + 65536;             // 256*256
    float* beat_hidden = bgb + 65536;       // 256*128
    float* mgf  = beat_hidden + 32768;      // 64*128
    float* mgb  = mgf  + 8192;              // 64*128
    float* meas_hidden = mgb + 8192;        // 64*64
    int*   cnt  = (int*)(meas_hidden + 4096);  // 10*1024
    int*   idx  = cnt + 10240;                  // 10*1024*64

    hipMemsetAsync(cnt, 0, EE*NN*sizeof(int), stream);
    k_csr_build<<<EE*NN, 256, 0, stream>>>(adj, cnt, idx);
    k_note_fc<<<NN, 128, 0, stream>>>(nodes, fc_w, fc_b, nh);

    for (int si = 0; si < 2; ++si){
        for (int it = 0; it < 2; ++it){
            k_gate_gemm<<<dim3(32,3,5), 256, 0, stream>>>(nh, cnt, idx,
                                g_wz[0], g_wr[0], g_wh[0], part);
            k_gru<<<NN/2, 128, 0, stream>>>(nh, part, g_uz[0], g_ur[0], g_uh[0],
                                            g_bz[0], g_br[0], g_bh[0]);
        }
        k_gb<<<NN/8, SS, 0, stream>>>(nh, gb_w, gb_b, nh2);
        for (int it = 0; it < 2; ++it){
            k_gate_gemm<<<dim3(32,3,5), 256, 0, stream>>>(nh2, cnt, idx,
                                g_wz[1], g_wr[1], g_wh[1], part);
            k_gru<<<NN/2, 128, 0, stream>>>(nh2, part, g_uz[1], g_ur[1], g_uh[1],
                                            g_bz[1], g_br[1], g_bh[1]);
        }
        k_batt_fused<<<NB, 256, 0, stream>>>(nh, nh2, batt_w, batt_b, batt_c,
                                             bwi_f, bb_f, bwi_b, bb_b, bgf, bgb);
        k_lstm_rec64<<<2, 256, 0, stream>>>(bgf, bwh_f, bgb, bwh_b, beat_hidden);
        k_matt_fused<<<NM, 128, 0, stream>>>(beat_hidden, matt_w, matt_b, matt_c,
                                             mwi_f, mb_f, mwi_b, mb_b, mgf, mgb);
        k_lstm_rec32<<<2, 64, 0, stream>>>(mgf, mwh_f, mgb, mwh_b, meas_hidden);
        if (si == 0)
            k_spans<<<NN, SS, 0, stream>>>(nh, beat_hidden, meas_hidden, bn, mn);
        else
            k_spans_out<<<NN, 448, 0, stream>>>(beat_hidden, meas_hidden, nh, nh2,
                                                bn, mn, out);
    }
}

// Round 8
// 1236.396 us; speedup vs baseline: 1.0424x; 1.0424x over previous
//
#include <hip/hip_runtime.h>
#include <math.h>

// ---------------------------------------------------------------------------
// IsgnBeatMeasEncoder — round 12: revert gather fusion; rec64 LDS-issue fix.
// Round-11 post-mortem: fused gather REGRESSED (1259 -> 1288). Falsification
// fired: boundary tax is ~2us/dispatch (not 13) -> the ~1018us non-rec64
// remainder is REAL kernel time. Revert to r10's separate gather_act.
// New rec64 theory: 660 cy/step = LDS ISSUE bound — per step each of 4 waves
// issues 32 uniform ds_read_b64 for hs (128 issues on the shared LDS pipe
// ~600cy); FMA is only 64 cy/SIMD. Fix: read hs as 16 x float4
// (ds_read_b128) per wave — halves issue count. Same for rec32.
// Also: k_gb was 128 blocks (half the CUs idle) -> 4 notes/block, 256 blocks.
// Falsification: rec64 unchanged ~120us -> step is barrier/VALU-bound; stop
// touching rec64.
// ---------------------------------------------------------------------------

#define NN    1024
#define EE    10
#define INDIM 78
#define SS    320
#define SECD  128
#define NB    256
#define NM    64
#define CAP   64     // max nonzeros per adjacency column (mean ~10.2)

typedef float v2f __attribute__((ext_vector_type(2)));

__device__ __forceinline__ void pkfma(v2f& a, v2f x, v2f y){
    asm("v_pk_fma_f32 %0, %1, %2, %0" : "+v"(a) : "v"(x), "v"(y));
}
// a.lo += x.lo*b.lo ; a.hi += x.hi*b.lo   (broadcast LOW half of b)
__device__ __forceinline__ void pkfma_blo(v2f& a, v2f x, v2f b){
    asm("v_pk_fma_f32 %0, %1, %2, %0 op_sel:[0,0,0] op_sel_hi:[1,0,1]"
        : "+v"(a) : "v"(x), "v"(b));
}
// a.lo += x.lo*b.hi ; a.hi += x.hi*b.hi   (broadcast HIGH half of b)
__device__ __forceinline__ void pkfma_bhi(v2f& a, v2f x, v2f b){
    asm("v_pk_fma_f32 %0, %1, %2, %0 op_sel:[0,1,0] op_sel_hi:[1,1,1]"
        : "+v"(a) : "v"(x), "v"(b));
}

#define LO2(F) ((v2f){F.x, F.y})
#define HI2(F) ((v2f){F.z, F.w})

__device__ __forceinline__ float fsig(float x){
    return __builtin_amdgcn_rcpf(1.f + __expf(-x));
}
__device__ __forceinline__ float ftanh(float x){
    // tanh(x) = 1 - 2/(exp(2x)+1); exp overflow -> inf -> rcp -> 0 -> 1 (correct)
    return 1.f - 2.f*__builtin_amdgcn_rcpf(1.f + __expf(2.f*x));
}

// ---------------- note_fc: x0 = tanh(nodes @ W + b); nh = [0(192) | x0] ------------
__global__ void k_note_fc(const float* __restrict__ nodes, const float* __restrict__ W,
                          const float* __restrict__ b, float* __restrict__ nh){
    int n = blockIdx.x, s = threadIdx.x;           // 128 threads
    __shared__ float xrow[INDIM];
    if (s < INDIM) xrow[s] = nodes[n*INDIM + s];
    __syncthreads();
    float acc = b[s];
    for (int k = 0; k < INDIM; ++k) acc += xrow[k]*W[k*128 + s];
    nh[n*SS + 192 + s] = ftanh(acc);
    nh[n*SS + s] = 0.f;
    if (s < 64) nh[n*SS + 128 + s] = 0.f;
}

// ---------------- CSR build: float4 scan of each adj row ---------------------------
__global__ void k_csr_build(const float* __restrict__ adj, int* __restrict__ cnt,
                            int* __restrict__ idx){
    int em = blockIdx.x;                   // e*NN + m  (row of adj[e])
    int e = em / NN, m = em % NN;
    const float4* row4 = (const float4*)(adj + (size_t)em * NN);
    int q = threadIdx.x;                   // 256 threads, 256 float4 = 1024 cols
    float4 v = row4[q];
    int n0 = q*4;
    if (v.x != 0.f){ int p = atomicAdd(&cnt[e*NN + n0+0], 1); if (p < CAP) idx[((size_t)e*NN + n0+0)*CAP + p] = m; }
    if (v.y != 0.f){ int p = atomicAdd(&cnt[e*NN + n0+1], 1); if (p < CAP) idx[((size_t)e*NN + n0+1)*CAP + p] = m; }
    if (v.z != 0.f){ int p = atomicAdd(&cnt[e*NN + n0+2], 1); if (p < CAP) idx[((size_t)e*NN + n0+2)*CAP + p] = m; }
    if (v.w != 0.f){ int p = atomicAdd(&cnt[e*NN + n0+3], 1); if (p < CAP) idx[((size_t)e*NN + n0+3)*CAP + p] = m; }
}

// ---------------- act[e,n,f] = sum over column list of x[m,f] ----------------------
__global__ void k_gather_act(const float* __restrict__ x, const int* __restrict__ cnt,
                             const int* __restrict__ idx, float* __restrict__ act){
    int en = blockIdx.x, f = threadIdx.x;  // 320 threads
    int c = cnt[en]; if (c > CAP) c = CAP;
    const int* lst = idx + (size_t)en*CAP;
    float acc = 0.f;
    for (int j = 0; j < c; ++j) acc += x[lst[j]*SS + f];
    act[(size_t)en*SS + f] = acc;
}

// ---------------- gate GEMM (r10 form): 32-row tiles, 480 blocks -------------------
__global__ __launch_bounds__(256) void k_gate_gemm(const float* __restrict__ act,
        const float* __restrict__ wz, const float* __restrict__ wr,
        const float* __restrict__ wh, float* __restrict__ part){
    __shared__ float A[32*36];     // [kk][row], 32 rows pad 36
    __shared__ float B[32*132];    // [kk][col], pad 132
    int nt = blockIdx.x, g = blockIdx.y, z = blockIdx.z;
    const float* W = (g==0) ? wz : ((g==1) ? wr : wh);
    int tid = threadIdx.x;
    int tx = tid & 31;             // cols tx*4 .. +3
    int ty = tid >> 5;             // rows ty*4 .. +3
    v2f acc[2][4];                 // [row-pair][col]; .x=row ty*4+2rp, .y=+1
    #pragma unroll
    for (int i=0;i<2;i++)
        #pragma unroll
        for (int j=0;j<4;j++) acc[i][j] = (v2f){0.f,0.f};
    for (int eh = 0; eh < 2; ++eh){
        int e = z*2 + eh;
        const float* Ae = act + (size_t)e*NN*SS + (size_t)nt*32*SS;
        const float* We = W   + (size_t)e*SS*SECD;
        for (int kc = 0; kc < SS; kc += 32){
            {                                      // A: 32 rows x 32 k = 256 float4
                int r  = tid >> 3;
                int k4 = (tid & 7) << 2;
                float4 v = *(const float4*)(Ae + r*SS + kc + k4);
                A[(k4+0)*36 + r] = v.x; A[(k4+1)*36 + r] = v.y;
                A[(k4+2)*36 + r] = v.z; A[(k4+3)*36 + r] = v.w;
            }
            #pragma unroll
            for (int i=0;i<4;i++){                 // B: 32 k x 128 cols
                int lin4 = tid + i*256;            // 1024 float4
                int kk = lin4 >> 5;
                int c4 = (lin4 & 31) << 2;
                *((float4*)(B + kk*132 + c4)) = *(const float4*)(We + (kc+kk)*SECD + c4);
            }
            __syncthreads();
            #pragma unroll 8
            for (int k=0;k<32;k++){
                const v2f* A2 = (const v2f*)(A + k*36 + ty*4);   // wave-uniform
                v2f a01 = A2[0], a23 = A2[1];
                float4 b = *(const float4*)(B + k*132 + tx*4);   // r8-proven pattern
                v2f b01 = {b.x, b.y}, b23 = {b.z, b.w};
                pkfma_blo(acc[0][0], a01, b01); pkfma_bhi(acc[0][1], a01, b01);
                pkfma_blo(acc[0][2], a01, b23); pkfma_bhi(acc[0][3], a01, b23);
                pkfma_blo(acc[1][0], a23, b01); pkfma_bhi(acc[1][1], a23, b01);
                pkfma_blo(acc[1][2], a23, b23); pkfma_bhi(acc[1][3], a23, b23);
            }
            __syncthreads();
        }
    }
    float* P = part + ((size_t)z*NN + (size_t)nt*32)*384 + g*SECD;
    int r0 = ty*4;
    *(float4*)(P + (size_t)(r0+0)*384 + tx*4) =
        make_float4(acc[0][0].x, acc[0][1].x, acc[0][2].x, acc[0][3].x);
    *(float4*)(P + (size_t)(r0+1)*384 + tx*4) =
        make_float4(acc[0][0].y, acc[0][1].y, acc[0][2].y, acc[0][3].y);
    *(float4*)(P + (size_t)(r0+2)*384 + tx*4) =
        make_float4(acc[1][0].x, acc[1][1].x, acc[1][2].x, acc[1][3].x);
    *(float4*)(P + (size_t)(r0+3)*384 + tx*4) =
        make_float4(acc[1][0].y, acc[1][1].y, acc[1][2].y, acc[1][3].y);
}

// ---------------- GRU update, 2 notes/block (512 blocks, 2/CU) ---------------------
__global__ void k_gru(float* __restrict__ x, const float* __restrict__ part,
        const float* __restrict__ uz, const float* __restrict__ ur, const float* __restrict__ uh,
        const float* __restrict__ bz, const float* __restrict__ br, const float* __restrict__ bh){
    int n0 = blockIdx.x*2, s = threadIdx.x;        // 128 threads
    __shared__ float xs[2][SECD], rx[2][SECD];
    #pragma unroll
    for (int j=0;j<2;j++) xs[j][s] = x[(n0+j)*SS + 192 + s];
    __syncthreads();
    float mz[2]={0,0}, mr[2]={0,0}, mh[2]={0,0};
    for (int sp=0; sp<5; sp++){
        const float* Pp = part + ((size_t)sp*NN + n0)*384;
        #pragma unroll
        for (int j=0;j<2;j++){
            mz[j] += Pp[j*384 + s];
            mr[j] += Pp[j*384 + 128 + s];
            mh[j] += Pp[j*384 + 256 + s];
        }
    }
    float dz[2]={0,0}, dr[2]={0,0};
    for (int k=0;k<SECD;k++){
        float wz_ = uz[k*SECD + s], wr_ = ur[k*SECD + s];
        #pragma unroll
        for (int j=0;j<2;j++){ float xv = xs[j][k]; dz[j] += xv*wz_; dr[j] += xv*wr_; }
    }
    float zz[2], rr[2];
    #pragma unroll
    for (int j=0;j<2;j++){
        zz[j] = fsig(mz[j] + dz[j] + bz[s]);
        rr[j] = fsig(mr[j] + dr[j] + br[s]);
        rx[j][s] = rr[j]*xs[j][s];
    }
    __syncthreads();
    float dh[2]={0,0};
    for (int k=0;k<SECD;k++){
        float wh_ = uh[k*SECD + s];
        #pragma unroll
        for (int j=0;j<2;j++) dh[j] += rx[j][k]*wh_;
    }
    #pragma unroll
    for (int j=0;j<2;j++){
        float h = ftanh(mh[j] + dh[j] + bh[s]);
        x[(n0+j)*SS + 192 + s] = (1.f - zz[j])*xs[j][s] + rr[j]*h;
    }
}

// ---------------- nb = relu(nh @ gb_w + gb_b) -> nh2; 4 notes/block, 256 blocks ----
__global__ void k_gb(const float* __restrict__ nh, const float* __restrict__ W,
                     const float* __restrict__ b, float* __restrict__ nb){
    int n0 = blockIdx.x*4, s = threadIdx.x;        // 320 threads
    __shared__ float xr_t[SS*4];                   // [k][j] — j-pairs adjacent
    {
        float v0 = nh[(n0+0)*SS + s], v1 = nh[(n0+1)*SS + s];
        float v2 = nh[(n0+2)*SS + s], v3 = nh[(n0+3)*SS + s];
        *(float4*)(xr_t + s*4) = make_float4(v0,v1,v2,v3);
    }
    __syncthreads();
    float bv = b[s];
    v2f a01={bv,bv}, a23={bv,bv};
    for (int k=0;k<SS;k++){
        float wv = W[k*SS + s];
        v2f ws = {wv, wv};
        const v2f* xp = (const v2f*)(xr_t + k*4);  // uniform addr -> broadcast
        pkfma(a01, xp[0], ws);
        pkfma(a23, xp[1], ws);
    }
    nb[(n0+0)*SS + s] = fmaxf(a01.x, 0.f);
    nb[(n0+1)*SS + s] = fmaxf(a01.y, 0.f);
    nb[(n0+2)*SS + s] = fmaxf(a23.x, 0.f);
    nb[(n0+3)*SS + s] = fmaxf(a23.y, 0.f);
}

// ---------------- FUSED beat attention + lstm_pre (transposed tile + pkfma) --------
__global__ __launch_bounds__(256) void k_batt_fused(
        const float* __restrict__ nh, const float* __restrict__ nh2,
        const float* __restrict__ W, const float* __restrict__ b,
        const float* __restrict__ cvec,
        const float* __restrict__ wi_f, const float* __restrict__ b_f,
        const float* __restrict__ wi_b, const float* __restrict__ b_b,
        float* __restrict__ gf, float* __restrict__ gbo){
    int g = blockIdx.x, s = threadIdx.x;           // 256 threads
    __shared__ float xr_t[256*4];                  // [k][j]
    __shared__ float simw[4][8];
    __shared__ float wgt[4][8];
    __shared__ float bnode[256];
    {
        float c0,c1,c2,c3;
        if (s < 128){
            c0 = nh[(g*4+0)*SS + 192 + s]; c1 = nh[(g*4+1)*SS + 192 + s];
            c2 = nh[(g*4+2)*SS + 192 + s]; c3 = nh[(g*4+3)*SS + 192 + s];
        } else {
            c0 = nh2[(g*4+0)*SS + 64 + s]; c1 = nh2[(g*4+1)*SS + 64 + s];
            c2 = nh2[(g*4+2)*SS + 64 + s]; c3 = nh2[(g*4+3)*SS + 64 + s];
        }
        *(float4*)(xr_t + s*4) = make_float4(c0,c1,c2,c3);
    }
    __syncthreads();
    float bias = b[s];
    v2f ac01 = {bias,bias}, ac23 = {bias,bias};
    for (int k=0;k<256;k++){
        float wv = W[k*256 + s];
        v2f ws = {wv, wv};
        const v2f* xp = (const v2f*)(xr_t + k*4);
        pkfma(ac01, xp[0], ws);
        pkfma(ac23, xp[1], ws);
    }
    float accj[4] = {ac01.x, ac01.y, ac23.x, ac23.y};
    float cv = cvec[s];
    int h = s >> 5;                                // head (HD=32)
    #pragma unroll
    for (int j=0;j<4;j++){
        float p = ftanh(accj[j])*cv;
        #pragma unroll
        for (int off=16; off>0; off>>=1) p += __shfl_down(p, off);
        if ((s & 31) == 0) simw[j][h] = p;
    }
    __syncthreads();
    if (s < 8){
        float v0=simw[0][s], v1=simw[1][s], v2=simw[2][s], v3=simw[3][s];
        float mx = fmaxf(fmaxf(v0,v1), fmaxf(v2,v3));
        float e0=__expf(v0-mx), e1=__expf(v1-mx), e2=__expf(v2-mx), e3=__expf(v3-mx);
        float den = e0+e1+e2+e3;
        wgt[0][s]=e0/den; wgt[1][s]=e1/den; wgt[2][s]=e2/den; wgt[3][s]=e3/den;
    }
    __syncthreads();
    float4 xs4 = *(const float4*)(xr_t + s*4);
    float o = xs4.x*wgt[0][h] + xs4.y*wgt[1][h] + xs4.z*wgt[2][h] + xs4.w*wgt[3][h];
    bnode[s] = o;
    __syncthreads();
    // pre-GEMV, both directions: contiguous weight rows as v2f, elementwise pkfma
    v2f afA = {b_f[s], 0.f}, afB = {0.f, 0.f};
    v2f abA = {b_b[s], 0.f}, abB = {0.f, 0.f};
    const v2f* wfp = (const v2f*)(wi_f + (size_t)s*256);
    const v2f* wbp = (const v2f*)(wi_b + (size_t)s*256);
    const v2f* bp  = (const v2f*)bnode;
    for (int k2=0;k2<128;k2+=2){
        v2f x01 = bp[k2], x23 = bp[k2+1];
        pkfma(afA, wfp[k2], x01); pkfma(afB, wfp[k2+1], x23);
        pkfma(abA, wbp[k2], x01); pkfma(abB, wbp[k2+1], x23);
    }
    gf [g*256 + s] = (afA.x + afA.y) + (afB.x + afB.y);
    gbo[g*256 + s] = (abA.x + abA.y) + (abB.x + abB.y);
}

// ---------------- FUSED measure attention + lstm_pre -------------------------------
__global__ __launch_bounds__(128) void k_matt_fused(
        const float* __restrict__ bh,   // beat_hidden [256][128]
        const float* __restrict__ W, const float* __restrict__ b,
        const float* __restrict__ cvec,
        const float* __restrict__ wi_f, const float* __restrict__ b_f,
        const float* __restrict__ wi_b, const float* __restrict__ b_b,
        float* __restrict__ gf, float* __restrict__ gbo){
    int g = blockIdx.x, s = threadIdx.x;           // 128 threads
    __shared__ float xr_t[128*4];                  // [k][j]
    __shared__ float simw[4][8];
    __shared__ float wgt[4][8];
    __shared__ float mnode[128];
    {
        float c0 = bh[(g*4+0)*128 + s], c1 = bh[(g*4+1)*128 + s];
        float c2 = bh[(g*4+2)*128 + s], c3 = bh[(g*4+3)*128 + s];
        *(float4*)(xr_t + s*4) = make_float4(c0,c1,c2,c3);
    }
    __syncthreads();
    float bias = b[s];
    v2f ac01 = {bias,bias}, ac23 = {bias,bias};
    for (int k=0;k<128;k++){
        float wv = W[k*128 + s];
        v2f ws = {wv, wv};
        const v2f* xp = (const v2f*)(xr_t + k*4);
        pkfma(ac01, xp[0], ws);
        pkfma(ac23, xp[1], ws);
    }
    float accj[4] = {ac01.x, ac01.y, ac23.x, ac23.y};
    float cv = cvec[s];
    int h = s >> 4;                                // head (HD=16)
    #pragma unroll
    for (int j=0;j<4;j++){
        float p = ftanh(accj[j])*cv;
        #pragma unroll
        for (int off=8; off>0; off>>=1) p += __shfl_down(p, off);
        if ((s & 15) == 0) simw[j][h] = p;
    }
    __syncthreads();
    if (s < 8){
        float v0=simw[0][s], v1=simw[1][s], v2=simw[2][s], v3=simw[3][s];
        float mx = fmaxf(fmaxf(v0,v1), fmaxf(v2,v3));
        float e0=__expf(v0-mx), e1=__expf(v1-mx), e2=__expf(v2-mx), e3=__expf(v3-mx);
        float den = e0+e1+e2+e3;
        wgt[0][s]=e0/den; wgt[1][s]=e1/den; wgt[2][s]=e2/den; wgt[3][s]=e3/den;
    }
    __syncthreads();
    float4 xs4 = *(const float4*)(xr_t + s*4);
    float o = xs4.x*wgt[0][h] + xs4.y*wgt[1][h] + xs4.z*wgt[2][h] + xs4.w*wgt[3][h];
    mnode[s] = o;
    __syncthreads();
    v2f afA = {b_f[s], 0.f}, afB = {0.f, 0.f};
    v2f abA = {b_b[s], 0.f}, abB = {0.f, 0.f};
    const v2f* wfp = (const v2f*)(wi_f + (size_t)s*128);
    const v2f* wbp = (const v2f*)(wi_b + (size_t)s*128);
    const v2f* bp  = (const v2f*)mnode;
    for (int k2=0;k2<64;k2+=2){
        v2f x01 = bp[k2], x23 = bp[k2+1];
        pkfma(afA, wfp[k2], x01); pkfma(afB, wfp[k2+1], x23);
        pkfma(abA, wbp[k2], x01); pkfma(abB, wbp[k2+1], x23);
    }
    gf [g*128 + s] = (afA.x + afA.y) + (afB.x + afB.y);
    gbo[g*128 + s] = (abA.x + abA.y) + (abB.x + abB.y);
}

// ---------------- LSTM recurrence, H=64 T=256: float4 hs reads (LDS-issue fix) -----
// 4 waves, redundant gate phase, gsum parity double-buffer, 1 barrier/step.
// hs read as 16 ds_read_b128 per wave (was 32 b64) — halves LDS issue count
// on the shared per-CU LDS pipe (the r11 theory for the 660cy step).
__global__ __launch_bounds__(256)
__attribute__((amdgpu_waves_per_eu(1, 1)))
void k_lstm_rec64(
        const float* __restrict__ gin_f, const float* __restrict__ wh_f,
        const float* __restrict__ gin_b, const float* __restrict__ wh_b,
        float* __restrict__ hid /* [T][128] */){
    const int H = 64, T = 256;
    int dir = blockIdx.x;
    const float* gin = dir ? gin_b : gin_f;
    const float* wh  = dir ? wh_b  : wh_f;
    int gi = threadIdx.x;                  // gate-row in [0, 256)
    int l  = gi & 63;                      // h-index this gate feeds
    const v2f* wp = (const v2f*)(wh + (size_t)gi*H);
    v2f w00=wp[0], w01=wp[1], w02=wp[2], w03=wp[3], w04=wp[4], w05=wp[5], w06=wp[6], w07=wp[7],
        w08=wp[8], w09=wp[9], w10=wp[10],w11=wp[11],w12=wp[12],w13=wp[13],w14=wp[14],w15=wp[15],
        w16=wp[16],w17=wp[17],w18=wp[18],w19=wp[19],w20=wp[20],w21=wp[21],w22=wp[22],w23=wp[23],
        w24=wp[24],w25=wp[25],w26=wp[26],w27=wp[27],w28=wp[28],w29=wp[29],w30=wp[30],w31=wp[31];
    __shared__ __align__(16) float hs[H];
    __shared__ float gsum[2][4*H];
    float c = 0.f;
    if (gi < H) hs[gi] = 0.f;
    __syncthreads();
    float gcur = gin[(dir ? (T-1) : 0)*4*H + gi];
    for (int step=0; step<T; step++){
        int t = dir ? (T-1-step) : step;
        float gnext = 0.f;
        if (step+1 < T) gnext = gin[(dir ? (T-2-step) : (step+1))*4*H + gi];
        const float4* hv = (const float4*)hs;      // uniform addr, b128 reads
        float4 H0=hv[0],  H1=hv[1],  H2=hv[2],  H3=hv[3];
        float4 H4=hv[4],  H5=hv[5],  H6=hv[6],  H7=hv[7];
        float4 H8=hv[8],  H9=hv[9],  H10=hv[10],H11=hv[11];
        float4 H12=hv[12],H13=hv[13],H14=hv[14],H15=hv[15];
        v2f A0={gcur,0.f}, A1={0.f,0.f}, A2={0.f,0.f}, A3={0.f,0.f};
        pkfma(A0,w00,LO2(H0));  pkfma(A1,w01,HI2(H0));  pkfma(A2,w02,LO2(H1));  pkfma(A3,w03,HI2(H1));
        pkfma(A0,w04,LO2(H2));  pkfma(A1,w05,HI2(H2));  pkfma(A2,w06,LO2(H3));  pkfma(A3,w07,HI2(H3));
        pkfma(A0,w08,LO2(H4));  pkfma(A1,w09,HI2(H4));  pkfma(A2,w10,LO2(H5));  pkfma(A3,w11,HI2(H5));
        pkfma(A0,w12,LO2(H6));  pkfma(A1,w13,HI2(H6));  pkfma(A2,w14,LO2(H7));  pkfma(A3,w15,HI2(H7));
        pkfma(A0,w16,LO2(H8));  pkfma(A1,w17,HI2(H8));  pkfma(A2,w18,LO2(H9));  pkfma(A3,w19,HI2(H9));
        pkfma(A0,w20,LO2(H10)); pkfma(A1,w21,HI2(H10)); pkfma(A2,w22,LO2(H11)); pkfma(A3,w23,HI2(H11));
        pkfma(A0,w24,LO2(H12)); pkfma(A1,w25,HI2(H12)); pkfma(A2,w26,LO2(H13)); pkfma(A3,w27,HI2(H13));
        pkfma(A0,w28,LO2(H14)); pkfma(A1,w29,HI2(H14)); pkfma(A2,w30,LO2(H15)); pkfma(A3,w31,HI2(H15));
        float* gs = gsum[step & 1];
        gs[gi] = ((A0.x+A0.y) + (A1.x+A1.y)) + ((A2.x+A2.y) + (A3.x+A3.y));
        __syncthreads();                           // the ONLY barrier per step
        float ig = gs[l], fg = gs[H+l], gg = gs[2*H+l], og = gs[3*H+l];
        c = fsig(fg)*c + fsig(ig)*ftanh(gg);       // all waves: identical update
        float hn = fsig(og)*ftanh(c);
        hs[l] = hn;                                // every wave writes full hs
        if (gi < H) hid[t*2*H + dir*H + gi] = hn;  // one wave publishes
        gcur = gnext;
    }
}

// ---------------- LSTM recurrence, H=32 T=64: single wave, float4 hs reads ---------
__global__ __launch_bounds__(64)
__attribute__((amdgpu_waves_per_eu(1, 1)))
void k_lstm_rec32(
        const float* __restrict__ gin_f, const float* __restrict__ wh_f,
        const float* __restrict__ gin_b, const float* __restrict__ wh_b,
        float* __restrict__ hid /* [T][64] */){
    const int H = 32, T = 64;
    int dir = blockIdx.x;
    const float* gin = dir ? gin_b : gin_f;
    const float* wh  = dir ? wh_b  : wh_f;
    int gi = threadIdx.x;                  // 0..63
    v2f wA[16], wB[16];
    {
        const v2f* rA = (const v2f*)(wh + (size_t)(     gi)*H);   // rows 0..63:  i|f
        const v2f* rB = (const v2f*)(wh + (size_t)(64 + gi)*H);   // rows 64..127: g|o
        #pragma unroll
        for (int k=0;k<16;k++){ wA[k]=rA[k]; wB[k]=rB[k]; }
    }
    __shared__ __align__(16) float hs[H];
    float c = 0.f;
    if (gi < H) hs[gi] = 0.f;
    __syncthreads();
    const float* gp = gin + gi;
    int ts0 = dir ? (T-1) : 0, ts1 = dir ? (T-2) : 1;
    float g0 = gp[ts0*128], g1 = gp[ts0*128 + 64];
    float n0 = gp[ts1*128], n1 = gp[ts1*128 + 64];
    bool lo = (gi < H);
    for (int step=0; step<T; step++){
        int t = dir ? (T-1-step) : step;
        float p0=0.f, p1=0.f;
        if (step+2 < T){
            int tp = dir ? (T-3-step) : (step+2);
            p0 = gp[tp*128]; p1 = gp[tp*128 + 64];
        }
        v2f aA = {g0, 0.f}, aB = {g1, 0.f};
        const float4* hv = (const float4*)hs;      // uniform addr, b128 reads
        #pragma unroll
        for (int k=0;k<8;k++){
            float4 h4 = hv[k];
            pkfma(aA, wA[2*k],   LO2(h4));
            pkfma(aB, wB[2*k],   LO2(h4));
            pkfma(aA, wA[2*k+1], HI2(h4));
            pkfma(aB, wB[2*k+1], HI2(h4));
        }
        float sA = aA.x + aA.y;            // lane<32: i ; lane>=32: f
        float sB = aB.x + aB.y;            // lane<32: g ; lane>=32: o
        float pA = __shfl(sA, gi ^ 32);
        float pB = __shfl(sB, gi ^ 32);
        float i_ = lo ? sA : pA;
        float f_ = lo ? pA : sA;
        float g_ = lo ? sB : pB;
        float o_ = lo ? pB : sB;
        c = fsig(f_)*c + fsig(i_)*ftanh(g_);
        float hn = fsig(o_)*ftanh(c);
        if (lo){
            hid[t*2*H + dir*H + gi] = hn;
            hs[gi] = hn;                   // same wave: in-order LDS, no barrier
        }
        g0 = n0; g1 = n1; n0 = p0; n1 = p1;
    }
}

// ---------------- si=0: rebuild nh in place = [beat_span | meas_span | nh_sec] -----
__global__ void k_spans(float* __restrict__ nh, const float* __restrict__ bh,
                        const float* __restrict__ mh,
                        const int* __restrict__ bn, const int* __restrict__ mn){
    int n = blockIdx.x, s = threadIdx.x;           // 320 threads
    float v;
    if (s < 128)      v = bh[bn[n]*128 + s];
    else if (s < 192) v = mh[mn[n]*64 + (s-128)];
    else              v = nh[n*SS + s];            // own-thread read-then-write: safe
    nh[n*SS + s] = v;
}

// ---------------- si=1: spans + final output fused ---------------------------------
__global__ void k_spans_out(const float* __restrict__ bh, const float* __restrict__ mh,
                            const float* __restrict__ nh, const float* __restrict__ nh2,
                            const int* __restrict__ bn, const int* __restrict__ mn,
                            float* __restrict__ out){
    int n = blockIdx.x, s = threadIdx.x;           // 448 threads
    float v;
    if (s < 128)      v = bh[bn[n]*128 + s];
    else if (s < 192) v = mh[mn[n]*64 + (s-128)];
    else if (s < 320) v = nh[n*SS + s];
    else              v = nh2[n*SS + 192 + (s-320)];
    out[n*448 + s] = v;
}

// ===========================================================================
extern "C" void kernel_launch(void* const* d_in, const int* in_sizes, int n_in,
                              void* d_out, int out_size, void* d_ws, size_t ws_size,
                              hipStream_t stream) {
    const float* nodes    = (const float*)d_in[0];
    const float* adj      = (const float*)d_in[1];
    const int*   bn       = (const int*)  d_in[2];
    const int*   mn       = (const int*)  d_in[3];
    const float* fc_w     = (const float*)d_in[6];
    const float* fc_b     = (const float*)d_in[7];
    const float* g_wz[2]  = {(const float*)d_in[8],  (const float*)d_in[17]};
    const float* g_wr[2]  = {(const float*)d_in[9],  (const float*)d_in[18]};
    const float* g_wh[2]  = {(const float*)d_in[10], (const float*)d_in[19]};
    const float* g_uz[2]  = {(const float*)d_in[11], (const float*)d_in[20]};
    const float* g_ur[2]  = {(const float*)d_in[12], (const float*)d_in[21]};
    const float* g_uh[2]  = {(const float*)d_in[13], (const float*)d_in[22]};
    const float* g_bz[2]  = {(const float*)d_in[14], (const float*)d_in[23]};
    const float* g_br[2]  = {(const float*)d_in[15], (const float*)d_in[24]};
    const float* g_bh[2]  = {(const float*)d_in[16], (const float*)d_in[25]};
    const float* gb_w     = (const float*)d_in[26];
    const float* gb_b     = (const float*)d_in[27];
    const float* batt_w   = (const float*)d_in[28];
    const float* batt_b   = (const float*)d_in[29];
    const float* batt_c   = (const float*)d_in[30];
    const float* matt_w   = (const float*)d_in[31];
    const float* matt_b   = (const float*)d_in[32];
    const float* matt_c   = (const float*)d_in[33];
    const float* bwi_f    = (const float*)d_in[34];
    const float* bwh_f    = (const float*)d_in[35];
    const float* bb_f     = (const float*)d_in[36];
    const float* bwi_b    = (const float*)d_in[37];
    const float* bwh_b    = (const float*)d_in[38];
    const float* bb_b     = (const float*)d_in[39];
    const float* mwi_f    = (const float*)d_in[40];
    const float* mwh_f    = (const float*)d_in[41];
    const float* mb_f     = (const float*)d_in[42];
    const float* mwi_b    = (const float*)d_in[43];
    const float* mwh_b    = (const float*)d_in[44];
    const float* mb_b     = (const float*)d_in[45];
    float* out = (float*)d_out;

    // --- workspace layout (floats; ~27 MB) ---
    float* W_   = (float*)d_ws;
    float* nh   = W_;                       // 1024*320
    float* nh2  = nh   + 327680;            // 1024*320
    float* act  = nh2  + 327680;            // 10*1024*320
    float* part = act  + 3276800;           // 5*1024*384
    float* bgf  = part + 1966080;           // 256*256
    float* bgb  = bgf  + 65536;             // 256*256
    float* beat_hidden = bgb + 65536;       // 256*128
    float* mgf  = beat_hidden + 32768;      // 64*128
    float* mgb  = mgf  + 8192;              // 64*128
    float* meas_hidden = mgb + 8192;        // 64*64
    int*   cnt  = (int*)(meas_hidden + 4096);  // 10*1024
    int*   idx  = cnt + 10240;                  // 10*1024*64

    hipMemsetAsync(cnt, 0, EE*NN*sizeof(int), stream);
    k_csr_build<<<EE*NN, 256, 0, stream>>>(adj, cnt, idx);
    k_note_fc<<<NN, 128, 0, stream>>>(nodes, fc_w, fc_b, nh);

    for (int si = 0; si < 2; ++si){
        for (int it = 0; it < 2; ++it){
            k_gather_act<<<EE*NN, SS, 0, stream>>>(nh, cnt, idx, act);
            k_gate_gemm<<<dim3(32,3,5), 256, 0, stream>>>(act, g_wz[0], g_wr[0], g_wh[0], part);
            k_gru<<<NN/2, 128, 0, stream>>>(nh, part, g_uz[0], g_ur[0], g_uh[0],
                                            g_bz[0], g_br[0], g_bh[0]);
        }
        k_gb<<<NN/4, SS, 0, stream>>>(nh, gb_w, gb_b, nh2);
        for (int it = 0; it < 2; ++it){
            k_gather_act<<<EE*NN, SS, 0, stream>>>(nh2, cnt, idx, act);
            k_gate_gemm<<<dim3(32,3,5), 256, 0, stream>>>(act, g_wz[1], g_wr[1], g_wh[1], part);
            k_gru<<<NN/2, 128, 0, stream>>>(nh2, part, g_uz[1], g_ur[1], g_uh[1],
                                            g_bz[1], g_br[1], g_bh[1]);
        }
        k_batt_fused<<<NB, 256, 0, stream>>>(nh, nh2, batt_w, batt_b, batt_c,
                                             bwi_f, bb_f, bwi_b, bb_b, bgf, bgb);
        k_lstm_rec64<<<2, 256, 0, stream>>>(bgf, bwh_f, bgb, bwh_b, beat_hidden);
        k_matt_fused<<<NM, 128, 0, stream>>>(beat_hidden, matt_w, matt_b, matt_c,
                                             mwi_f, mb_f, mwi_b, mb_b, mgf, mgb);
        k_lstm_rec32<<<2, 64, 0, stream>>>(mgf, mwh_f, mgb, mwh_b, meas_hidden);
        if (si == 0)
            k_spans<<<NN, SS, 0, stream>>>(nh, beat_hidden, meas_hidden, bn, mn);
        else
            k_spans_out<<<NN, 448, 0, stream>>>(beat_hidden, meas_hidden, nh, nh2,
                                                bn, mn, out);
    }
}

// Round 9
// 1085.184 us; speedup vs baseline: 1.1877x; 1.1393x over previous
//
#include <hip/hip_runtime.h>
#include <math.h>

// ---------------------------------------------------------------------------
// IsgnBeatMeasEncoder — round 13: static/dynamic split of the gate pre-GEMM.
// Round-12 post-mortem: total 1288 -> 1236 (gather revert + gb occupancy);
// rec64 float4-hs fix NULL -> rec64 is latency/barrier-bound, frozen at
// 120us. Non-rec64 remainder ~996us.
// Algorithmic lever: within one gated_graph (2 GRU iterations), k_gru only
// updates x[:,192:320]; cols 0..191 are CONSTANT -> act[:, :, 0:192] and its
// GEMM contribution are identical across the 2 iterations. And for si=0's
// first gated_graph, nh[:,0:192]==0 -> static part is exactly zero.
// Round 13:
//   - per gated_graph: static gather (192 cols) + static GEMM (K=192) ONCE
//     into part slices 5-9; per iteration: dyn gather (128 cols) + dyn GEMM
//     (K=128) into slices 0-4; k_gru sums nsp in {5,10} slices.
//   - si=0 g1: static pass skipped entirely (zero), gru nsp=5.
//   - gather/gemm work -30%; rec64/rec32/batt/matt/gb/spans unchanged.
// Falsification: total >=1220 -> cost model wrong; instrument mid-tier next.
// ---------------------------------------------------------------------------

#define NN    1024
#define EE    10
#define INDIM 78
#define SS    320
#define SECD  128
#define NB    256
#define NM    64
#define CAP   64     // max nonzeros per adjacency column (mean ~10.2)

typedef float v2f __attribute__((ext_vector_type(2)));

__device__ __forceinline__ void pkfma(v2f& a, v2f x, v2f y){
    asm("v_pk_fma_f32 %0, %1, %2, %0" : "+v"(a) : "v"(x), "v"(y));
}
// a.lo += x.lo*b.lo ; a.hi += x.hi*b.lo   (broadcast LOW half of b)
__device__ __forceinline__ void pkfma_blo(v2f& a, v2f x, v2f b){
    asm("v_pk_fma_f32 %0, %1, %2, %0 op_sel:[0,0,0] op_sel_hi:[1,0,1]"
        : "+v"(a) : "v"(x), "v"(b));
}
// a.lo += x.lo*b.hi ; a.hi += x.hi*b.hi   (broadcast HIGH half of b)
__device__ __forceinline__ void pkfma_bhi(v2f& a, v2f x, v2f b){
    asm("v_pk_fma_f32 %0, %1, %2, %0 op_sel:[0,1,0] op_sel_hi:[1,1,1]"
        : "+v"(a) : "v"(x), "v"(b));
}

#define LO2(F) ((v2f){F.x, F.y})
#define HI2(F) ((v2f){F.z, F.w})

__device__ __forceinline__ float fsig(float x){
    return __builtin_amdgcn_rcpf(1.f + __expf(-x));
}
__device__ __forceinline__ float ftanh(float x){
    // tanh(x) = 1 - 2/(exp(2x)+1); exp overflow -> inf -> rcp -> 0 -> 1 (correct)
    return 1.f - 2.f*__builtin_amdgcn_rcpf(1.f + __expf(2.f*x));
}

// ---------------- note_fc: x0 = tanh(nodes @ W + b); nh = [0(192) | x0] ------------
__global__ void k_note_fc(const float* __restrict__ nodes, const float* __restrict__ W,
                          const float* __restrict__ b, float* __restrict__ nh){
    int n = blockIdx.x, s = threadIdx.x;           // 128 threads
    __shared__ float xrow[INDIM];
    if (s < INDIM) xrow[s] = nodes[n*INDIM + s];
    __syncthreads();
    float acc = b[s];
    for (int k = 0; k < INDIM; ++k) acc += xrow[k]*W[k*128 + s];
    nh[n*SS + 192 + s] = ftanh(acc);
    nh[n*SS + s] = 0.f;
    if (s < 64) nh[n*SS + 128 + s] = 0.f;
}

// ---------------- CSR build: float4 scan of each adj row ---------------------------
__global__ void k_csr_build(const float* __restrict__ adj, int* __restrict__ cnt,
                            int* __restrict__ idx){
    int em = blockIdx.x;                   // e*NN + m  (row of adj[e])
    int e = em / NN, m = em % NN;
    const float4* row4 = (const float4*)(adj + (size_t)em * NN);
    int q = threadIdx.x;                   // 256 threads, 256 float4 = 1024 cols
    float4 v = row4[q];
    int n0 = q*4;
    if (v.x != 0.f){ int p = atomicAdd(&cnt[e*NN + n0+0], 1); if (p < CAP) idx[((size_t)e*NN + n0+0)*CAP + p] = m; }
    if (v.y != 0.f){ int p = atomicAdd(&cnt[e*NN + n0+1], 1); if (p < CAP) idx[((size_t)e*NN + n0+1)*CAP + p] = m; }
    if (v.z != 0.f){ int p = atomicAdd(&cnt[e*NN + n0+2], 1); if (p < CAP) idx[((size_t)e*NN + n0+2)*CAP + p] = m; }
    if (v.w != 0.f){ int p = atomicAdd(&cnt[e*NN + n0+3], 1); if (p < CAP) idx[((size_t)e*NN + n0+3)*CAP + p] = m; }
}

// ---------------- act[e,n,F0+f] = sum over column list of x[m,F0+f] ----------------
// Launched with blockDim = number of columns in the range (192 static, 128 dyn).
__global__ void k_gather_act_rng(const float* __restrict__ x, const int* __restrict__ cnt,
                                 const int* __restrict__ idx, float* __restrict__ act,
                                 int F0){
    int en = blockIdx.x, f = F0 + threadIdx.x;
    int c = cnt[en]; if (c > CAP) c = CAP;
    const int* lst = idx + (size_t)en*CAP;
    float acc = 0.f;
    for (int j = 0; j < c; ++j) acc += x[lst[j]*SS + f];
    act[(size_t)en*SS + f] = acc;
}

// ---------------- gate GEMM over K range [K0,K1): 32-row tiles, 480 blocks ---------
// part layout per base: [5 z][1024 n][384] (3 gates x 128).
template<int K0, int K1>
__global__ __launch_bounds__(256) void k_gate_gemm_rng(const float* __restrict__ act,
        const float* __restrict__ wz, const float* __restrict__ wr,
        const float* __restrict__ wh, float* __restrict__ part){
    __shared__ float A[32*36];     // [kk][row], 32 rows pad 36
    __shared__ float B[32*132];    // [kk][col], pad 132
    int nt = blockIdx.x, g = blockIdx.y, z = blockIdx.z;
    const float* W = (g==0) ? wz : ((g==1) ? wr : wh);
    int tid = threadIdx.x;
    int tx = tid & 31;             // cols tx*4 .. +3
    int ty = tid >> 5;             // rows ty*4 .. +3
    v2f acc[2][4];                 // [row-pair][col]; .x=row ty*4+2rp, .y=+1
    #pragma unroll
    for (int i=0;i<2;i++)
        #pragma unroll
        for (int j=0;j<4;j++) acc[i][j] = (v2f){0.f,0.f};
    for (int eh = 0; eh < 2; ++eh){
        int e = z*2 + eh;
        const float* Ae = act + (size_t)e*NN*SS + (size_t)nt*32*SS;
        const float* We = W   + (size_t)e*SS*SECD;
        for (int kc = K0; kc < K1; kc += 32){
            {                                      // A: 32 rows x 32 k = 256 float4
                int r  = tid >> 3;
                int k4 = (tid & 7) << 2;
                float4 v = *(const float4*)(Ae + r*SS + kc + k4);
                A[(k4+0)*36 + r] = v.x; A[(k4+1)*36 + r] = v.y;
                A[(k4+2)*36 + r] = v.z; A[(k4+3)*36 + r] = v.w;
            }
            #pragma unroll
            for (int i=0;i<4;i++){                 // B: 32 k x 128 cols
                int lin4 = tid + i*256;            // 1024 float4
                int kk = lin4 >> 5;
                int c4 = (lin4 & 31) << 2;
                *((float4*)(B + kk*132 + c4)) = *(const float4*)(We + (kc+kk)*SECD + c4);
            }
            __syncthreads();
            #pragma unroll 8
            for (int k=0;k<32;k++){
                const v2f* A2 = (const v2f*)(A + k*36 + ty*4);   // wave-uniform
                v2f a01 = A2[0], a23 = A2[1];
                float4 b = *(const float4*)(B + k*132 + tx*4);   // r8-proven pattern
                v2f b01 = {b.x, b.y}, b23 = {b.z, b.w};
                pkfma_blo(acc[0][0], a01, b01); pkfma_bhi(acc[0][1], a01, b01);
                pkfma_blo(acc[0][2], a01, b23); pkfma_bhi(acc[0][3], a01, b23);
                pkfma_blo(acc[1][0], a23, b01); pkfma_bhi(acc[1][1], a23, b01);
                pkfma_blo(acc[1][2], a23, b23); pkfma_bhi(acc[1][3], a23, b23);
            }
            __syncthreads();
        }
    }
    float* P = part + ((size_t)z*NN + (size_t)nt*32)*384 + g*SECD;
    int r0 = ty*4;
    *(float4*)(P + (size_t)(r0+0)*384 + tx*4) =
        make_float4(acc[0][0].x, acc[0][1].x, acc[0][2].x, acc[0][3].x);
    *(float4*)(P + (size_t)(r0+1)*384 + tx*4) =
        make_float4(acc[0][0].y, acc[0][1].y, acc[0][2].y, acc[0][3].y);
    *(float4*)(P + (size_t)(r0+2)*384 + tx*4) =
        make_float4(acc[1][0].x, acc[1][1].x, acc[1][2].x, acc[1][3].x);
    *(float4*)(P + (size_t)(r0+3)*384 + tx*4) =
        make_float4(acc[1][0].y, acc[1][1].y, acc[1][2].y, acc[1][3].y);
}

// ---------------- GRU update, 2 notes/block; sums nsp part slices ------------------
// part slices 0-4 = dynamic (this iteration), 5-9 = static (per gated_graph).
__global__ void k_gru(float* __restrict__ x, const float* __restrict__ part, int nsp,
        const float* __restrict__ uz, const float* __restrict__ ur, const float* __restrict__ uh,
        const float* __restrict__ bz, const float* __restrict__ br, const float* __restrict__ bh){
    int n0 = blockIdx.x*2, s = threadIdx.x;        // 128 threads
    __shared__ float xs[2][SECD], rx[2][SECD];
    #pragma unroll
    for (int j=0;j<2;j++) xs[j][s] = x[(n0+j)*SS + 192 + s];
    __syncthreads();
    float mz[2]={0,0}, mr[2]={0,0}, mh[2]={0,0};
    for (int sp=0; sp<nsp; sp++){
        const float* Pp = part + ((size_t)sp*NN + n0)*384;
        #pragma unroll
        for (int j=0;j<2;j++){
            mz[j] += Pp[j*384 + s];
            mr[j] += Pp[j*384 + 128 + s];
            mh[j] += Pp[j*384 + 256 + s];
        }
    }
    float dz[2]={0,0}, dr[2]={0,0};
    for (int k=0;k<SECD;k++){
        float wz_ = uz[k*SECD + s], wr_ = ur[k*SECD + s];
        #pragma unroll
        for (int j=0;j<2;j++){ float xv = xs[j][k]; dz[j] += xv*wz_; dr[j] += xv*wr_; }
    }
    float zz[2], rr[2];
    #pragma unroll
    for (int j=0;j<2;j++){
        zz[j] = fsig(mz[j] + dz[j] + bz[s]);
        rr[j] = fsig(mr[j] + dr[j] + br[s]);
        rx[j][s] = rr[j]*xs[j][s];
    }
    __syncthreads();
    float dh[2]={0,0};
    for (int k=0;k<SECD;k++){
        float wh_ = uh[k*SECD + s];
        #pragma unroll
        for (int j=0;j<2;j++) dh[j] += rx[j][k]*wh_;
    }
    #pragma unroll
    for (int j=0;j<2;j++){
        float h = ftanh(mh[j] + dh[j] + bh[s]);
        x[(n0+j)*SS + 192 + s] = (1.f - zz[j])*xs[j][s] + rr[j]*h;
    }
}

// ---------------- nb = relu(nh @ gb_w + gb_b) -> nh2; 4 notes/block, 256 blocks ----
__global__ void k_gb(const float* __restrict__ nh, const float* __restrict__ W,
                     const float* __restrict__ b, float* __restrict__ nb){
    int n0 = blockIdx.x*4, s = threadIdx.x;        // 320 threads
    __shared__ float xr_t[SS*4];                   // [k][j] — j-pairs adjacent
    {
        float v0 = nh[(n0+0)*SS + s], v1 = nh[(n0+1)*SS + s];
        float v2 = nh[(n0+2)*SS + s], v3 = nh[(n0+3)*SS + s];
        *(float4*)(xr_t + s*4) = make_float4(v0,v1,v2,v3);
    }
    __syncthreads();
    float bv = b[s];
    v2f a01={bv,bv}, a23={bv,bv};
    for (int k=0;k<SS;k++){
        float wv = W[k*SS + s];
        v2f ws = {wv, wv};
        const v2f* xp = (const v2f*)(xr_t + k*4);  // uniform addr -> broadcast
        pkfma(a01, xp[0], ws);
        pkfma(a23, xp[1], ws);
    }
    nb[(n0+0)*SS + s] = fmaxf(a01.x, 0.f);
    nb[(n0+1)*SS + s] = fmaxf(a01.y, 0.f);
    nb[(n0+2)*SS + s] = fmaxf(a23.x, 0.f);
    nb[(n0+3)*SS + s] = fmaxf(a23.y, 0.f);
}

// ---------------- FUSED beat attention + lstm_pre (transposed tile + pkfma) --------
__global__ __launch_bounds__(256) void k_batt_fused(
        const float* __restrict__ nh, const float* __restrict__ nh2,
        const float* __restrict__ W, const float* __restrict__ b,
        const float* __restrict__ cvec,
        const float* __restrict__ wi_f, const float* __restrict__ b_f,
        const float* __restrict__ wi_b, const float* __restrict__ b_b,
        float* __restrict__ gf, float* __restrict__ gbo){
    int g = blockIdx.x, s = threadIdx.x;           // 256 threads
    __shared__ float xr_t[256*4];                  // [k][j]
    __shared__ float simw[4][8];
    __shared__ float wgt[4][8];
    __shared__ float bnode[256];
    {
        float c0,c1,c2,c3;
        if (s < 128){
            c0 = nh[(g*4+0)*SS + 192 + s]; c1 = nh[(g*4+1)*SS + 192 + s];
            c2 = nh[(g*4+2)*SS + 192 + s]; c3 = nh[(g*4+3)*SS + 192 + s];
        } else {
            c0 = nh2[(g*4+0)*SS + 64 + s]; c1 = nh2[(g*4+1)*SS + 64 + s];
            c2 = nh2[(g*4+2)*SS + 64 + s]; c3 = nh2[(g*4+3)*SS + 64 + s];
        }
        *(float4*)(xr_t + s*4) = make_float4(c0,c1,c2,c3);
    }
    __syncthreads();
    float bias = b[s];
    v2f ac01 = {bias,bias}, ac23 = {bias,bias};
    for (int k=0;k<256;k++){
        float wv = W[k*256 + s];
        v2f ws = {wv, wv};
        const v2f* xp = (const v2f*)(xr_t + k*4);
        pkfma(ac01, xp[0], ws);
        pkfma(ac23, xp[1], ws);
    }
    float accj[4] = {ac01.x, ac01.y, ac23.x, ac23.y};
    float cv = cvec[s];
    int h = s >> 5;                                // head (HD=32)
    #pragma unroll
    for (int j=0;j<4;j++){
        float p = ftanh(accj[j])*cv;
        #pragma unroll
        for (int off=16; off>0; off>>=1) p += __shfl_down(p, off);
        if ((s & 31) == 0) simw[j][h] = p;
    }
    __syncthreads();
    if (s < 8){
        float v0=simw[0][s], v1=simw[1][s], v2=simw[2][s], v3=simw[3][s];
        float mx = fmaxf(fmaxf(v0,v1), fmaxf(v2,v3));
        float e0=__expf(v0-mx), e1=__expf(v1-mx), e2=__expf(v2-mx), e3=__expf(v3-mx);
        float den = e0+e1+e2+e3;
        wgt[0][s]=e0/den; wgt[1][s]=e1/den; wgt[2][s]=e2/den; wgt[3][s]=e3/den;
    }
    __syncthreads();
    float4 xs4 = *(const float4*)(xr_t + s*4);
    float o = xs4.x*wgt[0][h] + xs4.y*wgt[1][h] + xs4.z*wgt[2][h] + xs4.w*wgt[3][h];
    bnode[s] = o;
    __syncthreads();
    // pre-GEMV, both directions: contiguous weight rows as v2f, elementwise pkfma
    v2f afA = {b_f[s], 0.f}, afB = {0.f, 0.f};
    v2f abA = {b_b[s], 0.f}, abB = {0.f, 0.f};
    const v2f* wfp = (const v2f*)(wi_f + (size_t)s*256);
    const v2f* wbp = (const v2f*)(wi_b + (size_t)s*256);
    const v2f* bp  = (const v2f*)bnode;
    for (int k2=0;k2<128;k2+=2){
        v2f x01 = bp[k2], x23 = bp[k2+1];
        pkfma(afA, wfp[k2], x01); pkfma(afB, wfp[k2+1], x23);
        pkfma(abA, wbp[k2], x01); pkfma(abB, wbp[k2+1], x23);
    }
    gf [g*256 + s] = (afA.x + afA.y) + (afB.x + afB.y);
    gbo[g*256 + s] = (abA.x + abA.y) + (abB.x + abB.y);
}

// ---------------- FUSED measure attention + lstm_pre -------------------------------
__global__ __launch_bounds__(128) void k_matt_fused(
        const float* __restrict__ bh,   // beat_hidden [256][128]
        const float* __restrict__ W, const float* __restrict__ b,
        const float* __restrict__ cvec,
        const float* __restrict__ wi_f, const float* __restrict__ b_f,
        const float* __restrict__ wi_b, const float* __restrict__ b_b,
        float* __restrict__ gf, float* __restrict__ gbo){
    int g = blockIdx.x, s = threadIdx.x;           // 128 threads
    __shared__ float xr_t[128*4];                  // [k][j]
    __shared__ float simw[4][8];
    __shared__ float wgt[4][8];
    __shared__ float mnode[128];
    {
        float c0 = bh[(g*4+0)*128 + s], c1 = bh[(g*4+1)*128 + s];
        float c2 = bh[(g*4+2)*128 + s], c3 = bh[(g*4+3)*128 + s];
        *(float4*)(xr_t + s*4) = make_float4(c0,c1,c2,c3);
    }
    __syncthreads();
    float bias = b[s];
    v2f ac01 = {bias,bias}, ac23 = {bias,bias};
    for (int k=0;k<128;k++){
        float wv = W[k*128 + s];
        v2f ws = {wv, wv};
        const v2f* xp = (const v2f*)(xr_t + k*4);
        pkfma(ac01, xp[0], ws);
        pkfma(ac23, xp[1], ws);
    }
    float accj[4] = {ac01.x, ac01.y, ac23.x, ac23.y};
    float cv = cvec[s];
    int h = s >> 4;                                // head (HD=16)
    #pragma unroll
    for (int j=0;j<4;j++){
        float p = ftanh(accj[j])*cv;
        #pragma unroll
        for (int off=8; off>0; off>>=1) p += __shfl_down(p, off);
        if ((s & 15) == 0) simw[j][h] = p;
    }
    __syncthreads();
    if (s < 8){
        float v0=simw[0][s], v1=simw[1][s], v2=simw[2][s], v3=simw[3][s];
        float mx = fmaxf(fmaxf(v0,v1), fmaxf(v2,v3));
        float e0=__expf(v0-mx), e1=__expf(v1-mx), e2=__expf(v2-mx), e3=__expf(v3-mx);
        float den = e0+e1+e2+e3;
        wgt[0][s]=e0/den; wgt[1][s]=e1/den; wgt[2][s]=e2/den; wgt[3][s]=e3/den;
    }
    __syncthreads();
    float4 xs4 = *(const float4*)(xr_t + s*4);
    float o = xs4.x*wgt[0][h] + xs4.y*wgt[1][h] + xs4.z*wgt[2][h] + xs4.w*wgt[3][h];
    mnode[s] = o;
    __syncthreads();
    v2f afA = {b_f[s], 0.f}, afB = {0.f, 0.f};
    v2f abA = {b_b[s], 0.f}, abB = {0.f, 0.f};
    const v2f* wfp = (const v2f*)(wi_f + (size_t)s*128);
    const v2f* wbp = (const v2f*)(wi_b + (size_t)s*128);
    const v2f* bp  = (const v2f*)mnode;
    for (int k2=0;k2<64;k2+=2){
        v2f x01 = bp[k2], x23 = bp[k2+1];
        pkfma(afA, wfp[k2], x01); pkfma(afB, wfp[k2+1], x23);
        pkfma(abA, wbp[k2], x01); pkfma(abB, wbp[k2+1], x23);
    }
    gf [g*128 + s] = (afA.x + afA.y) + (afB.x + afB.y);
    gbo[g*128 + s] = (abA.x + abA.y) + (abB.x + abB.y);
}

// ---------------- LSTM recurrence, H=64 T=256: frozen r12 form ---------------------
__global__ __launch_bounds__(256)
__attribute__((amdgpu_waves_per_eu(1, 1)))
void k_lstm_rec64(
        const float* __restrict__ gin_f, const float* __restrict__ wh_f,
        const float* __restrict__ gin_b, const float* __restrict__ wh_b,
        float* __restrict__ hid /* [T][128] */){
    const int H = 64, T = 256;
    int dir = blockIdx.x;
    const float* gin = dir ? gin_b : gin_f;
    const float* wh  = dir ? wh_b  : wh_f;
    int gi = threadIdx.x;                  // gate-row in [0, 256)
    int l  = gi & 63;                      // h-index this gate feeds
    const v2f* wp = (const v2f*)(wh + (size_t)gi*H);
    v2f w00=wp[0], w01=wp[1], w02=wp[2], w03=wp[3], w04=wp[4], w05=wp[5], w06=wp[6], w07=wp[7],
        w08=wp[8], w09=wp[9], w10=wp[10],w11=wp[11],w12=wp[12],w13=wp[13],w14=wp[14],w15=wp[15],
        w16=wp[16],w17=wp[17],w18=wp[18],w19=wp[19],w20=wp[20],w21=wp[21],w22=wp[22],w23=wp[23],
        w24=wp[24],w25=wp[25],w26=wp[26],w27=wp[27],w28=wp[28],w29=wp[29],w30=wp[30],w31=wp[31];
    __shared__ __align__(16) float hs[H];
    __shared__ float gsum[2][4*H];
    float c = 0.f;
    if (gi < H) hs[gi] = 0.f;
    __syncthreads();
    float gcur = gin[(dir ? (T-1) : 0)*4*H + gi];
    for (int step=0; step<T; step++){
        int t = dir ? (T-1-step) : step;
        float gnext = 0.f;
        if (step+1 < T) gnext = gin[(dir ? (T-2-step) : (step+1))*4*H + gi];
        const float4* hv = (const float4*)hs;      // uniform addr, b128 reads
        float4 H0=hv[0],  H1=hv[1],  H2=hv[2],  H3=hv[3];
        float4 H4=hv[4],  H5=hv[5],  H6=hv[6],  H7=hv[7];
        float4 H8=hv[8],  H9=hv[9],  H10=hv[10],H11=hv[11];
        float4 H12=hv[12],H13=hv[13],H14=hv[14],H15=hv[15];
        v2f A0={gcur,0.f}, A1={0.f,0.f}, A2={0.f,0.f}, A3={0.f,0.f};
        pkfma(A0,w00,LO2(H0));  pkfma(A1,w01,HI2(H0));  pkfma(A2,w02,LO2(H1));  pkfma(A3,w03,HI2(H1));
        pkfma(A0,w04,LO2(H2));  pkfma(A1,w05,HI2(H2));  pkfma(A2,w06,LO2(H3));  pkfma(A3,w07,HI2(H3));
        pkfma(A0,w08,LO2(H4));  pkfma(A1,w09,HI2(H4));  pkfma(A2,w10,LO2(H5));  pkfma(A3,w11,HI2(H5));
        pkfma(A0,w12,LO2(H6));  pkfma(A1,w13,HI2(H6));  pkfma(A2,w14,LO2(H7));  pkfma(A3,w15,HI2(H7));
        pkfma(A0,w16,LO2(H8));  pkfma(A1,w17,HI2(H8));  pkfma(A2,w18,LO2(H9));  pkfma(A3,w19,HI2(H9));
        pkfma(A0,w20,LO2(H10)); pkfma(A1,w21,HI2(H10)); pkfma(A2,w22,LO2(H11)); pkfma(A3,w23,HI2(H11));
        pkfma(A0,w24,LO2(H12)); pkfma(A1,w25,HI2(H12)); pkfma(A2,w26,LO2(H13)); pkfma(A3,w27,HI2(H13));
        pkfma(A0,w28,LO2(H14)); pkfma(A1,w29,HI2(H14)); pkfma(A2,w30,LO2(H15)); pkfma(A3,w31,HI2(H15));
        float* gs = gsum[step & 1];
        gs[gi] = ((A0.x+A0.y) + (A1.x+A1.y)) + ((A2.x+A2.y) + (A3.x+A3.y));
        __syncthreads();                           // the ONLY barrier per step
        float ig = gs[l], fg = gs[H+l], gg = gs[2*H+l], og = gs[3*H+l];
        c = fsig(fg)*c + fsig(ig)*ftanh(gg);       // all waves: identical update
        float hn = fsig(og)*ftanh(c);
        hs[l] = hn;                                // every wave writes full hs
        if (gi < H) hid[t*2*H + dir*H + gi] = hn;  // one wave publishes
        gcur = gnext;
    }
}

// ---------------- LSTM recurrence, H=32 T=64: single wave, NO barrier --------------
__global__ __launch_bounds__(64)
__attribute__((amdgpu_waves_per_eu(1, 1)))
void k_lstm_rec32(
        const float* __restrict__ gin_f, const float* __restrict__ wh_f,
        const float* __restrict__ gin_b, const float* __restrict__ wh_b,
        float* __restrict__ hid /* [T][64] */){
    const int H = 32, T = 64;
    int dir = blockIdx.x;
    const float* gin = dir ? gin_b : gin_f;
    const float* wh  = dir ? wh_b  : wh_f;
    int gi = threadIdx.x;                  // 0..63
    v2f wA[16], wB[16];
    {
        const v2f* rA = (const v2f*)(wh + (size_t)(     gi)*H);   // rows 0..63:  i|f
        const v2f* rB = (const v2f*)(wh + (size_t)(64 + gi)*H);   // rows 64..127: g|o
        #pragma unroll
        for (int k=0;k<16;k++){ wA[k]=rA[k]; wB[k]=rB[k]; }
    }
    __shared__ __align__(16) float hs[H];
    float c = 0.f;
    if (gi < H) hs[gi] = 0.f;
    __syncthreads();
    const float* gp = gin + gi;
    int ts0 = dir ? (T-1) : 0, ts1 = dir ? (T-2) : 1;
    float g0 = gp[ts0*128], g1 = gp[ts0*128 + 64];
    float n0 = gp[ts1*128], n1 = gp[ts1*128 + 64];
    bool lo = (gi < H);
    for (int step=0; step<T; step++){
        int t = dir ? (T-1-step) : step;
        float p0=0.f, p1=0.f;
        if (step+2 < T){
            int tp = dir ? (T-3-step) : (step+2);
            p0 = gp[tp*128]; p1 = gp[tp*128 + 64];
        }
        v2f aA = {g0, 0.f}, aB = {g1, 0.f};
        const float4* hv = (const float4*)hs;      // uniform addr, b128 reads
        #pragma unroll
        for (int k=0;k<8;k++){
            float4 h4 = hv[k];
            pkfma(aA, wA[2*k],   LO2(h4));
            pkfma(aB, wB[2*k],   LO2(h4));
            pkfma(aA, wA[2*k+1], HI2(h4));
            pkfma(aB, wB[2*k+1], HI2(h4));
        }
        float sA = aA.x + aA.y;            // lane<32: i ; lane>=32: f
        float sB = aB.x + aB.y;            // lane<32: g ; lane>=32: o
        float pA = __shfl(sA, gi ^ 32);
        float pB = __shfl(sB, gi ^ 32);
        float i_ = lo ? sA : pA;
        float f_ = lo ? pA : sA;
        float g_ = lo ? sB : pB;
        float o_ = lo ? pB : sB;
        c = fsig(f_)*c + fsig(i_)*ftanh(g_);
        float hn = fsig(o_)*ftanh(c);
        if (lo){
            hid[t*2*H + dir*H + gi] = hn;
            hs[gi] = hn;                   // same wave: in-order LDS, no barrier
        }
        g0 = n0; g1 = n1; n0 = p0; n1 = p1;
    }
}

// ---------------- si=0: rebuild nh in place = [beat_span | meas_span | nh_sec] -----
__global__ void k_spans(float* __restrict__ nh, const float* __restrict__ bh,
                        const float* __restrict__ mh,
                        const int* __restrict__ bn, const int* __restrict__ mn){
    int n = blockIdx.x, s = threadIdx.x;           // 320 threads
    float v;
    if (s < 128)      v = bh[bn[n]*128 + s];
    else if (s < 192) v = mh[mn[n]*64 + (s-128)];
    else              v = nh[n*SS + s];            // own-thread read-then-write: safe
    nh[n*SS + s] = v;
}

// ---------------- si=1: spans + final output fused ---------------------------------
__global__ void k_spans_out(const float* __restrict__ bh, const float* __restrict__ mh,
                            const float* __restrict__ nh, const float* __restrict__ nh2,
                            const int* __restrict__ bn, const int* __restrict__ mn,
                            float* __restrict__ out){
    int n = blockIdx.x, s = threadIdx.x;           // 448 threads
    float v;
    if (s < 128)      v = bh[bn[n]*128 + s];
    else if (s < 192) v = mh[mn[n]*64 + (s-128)];
    else if (s < 320) v = nh[n*SS + s];
    else              v = nh2[n*SS + 192 + (s-320)];
    out[n*448 + s] = v;
}

// ===========================================================================
extern "C" void kernel_launch(void* const* d_in, const int* in_sizes, int n_in,
                              void* d_out, int out_size, void* d_ws, size_t ws_size,
                              hipStream_t stream) {
    const float* nodes    = (const float*)d_in[0];
    const float* adj      = (const float*)d_in[1];
    const int*   bn       = (const int*)  d_in[2];
    const int*   mn       = (const int*)  d_in[3];
    const float* fc_w     = (const float*)d_in[6];
    const float* fc_b     = (const float*)d_in[7];
    const float* g_wz[2]  = {(const float*)d_in[8],  (const float*)d_in[17]};
    const float* g_wr[2]  = {(const float*)d_in[9],  (const float*)d_in[18]};
    const float* g_wh[2]  = {(const float*)d_in[10], (const float*)d_in[19]};
    const float* g_uz[2]  = {(const float*)d_in[11], (const float*)d_in[20]};
    const float* g_ur[2]  = {(const float*)d_in[12], (const float*)d_in[21]};
    const float* g_uh[2]  = {(const float*)d_in[13], (const float*)d_in[22]};
    const float* g_bz[2]  = {(const float*)d_in[14], (const float*)d_in[23]};
    const float* g_br[2]  = {(const float*)d_in[15], (const float*)d_in[24]};
    const float* g_bh[2]  = {(const float*)d_in[16], (const float*)d_in[25]};
    const float* gb_w     = (const float*)d_in[26];
    const float* gb_b     = (const float*)d_in[27];
    const float* batt_w   = (const float*)d_in[28];
    const float* batt_b   = (const float*)d_in[29];
    const float* batt_c   = (const float*)d_in[30];
    const float* matt_w   = (const float*)d_in[31];
    const float* matt_b   = (const float*)d_in[32];
    const float* matt_c   = (const float*)d_in[33];
    const float* bwi_f    = (const float*)d_in[34];
    const float* bwh_f    = (const float*)d_in[35];
    const float* bb_f     = (const float*)d_in[36];
    const float* bwi_b    = (const float*)d_in[37];
    const float* bwh_b    = (const float*)d_in[38];
    const float* bb_b     = (const float*)d_in[39];
    const float* mwi_f    = (const float*)d_in[40];
    const float* mwh_f    = (const float*)d_in[41];
    const float* mb_f     = (const float*)d_in[42];
    const float* mwi_b    = (const float*)d_in[43];
    const float* mwh_b    = (const float*)d_in[44];
    const float* mb_b     = (const float*)d_in[45];
    float* out = (float*)d_out;

    // --- workspace layout (floats; ~27.7 MB, under the 31.2MB proven in r0) ---
    float* W_   = (float*)d_ws;
    float* nh   = W_;                       // 1024*320
    float* nh2  = nh   + 327680;            // 1024*320
    float* act  = nh2  + 327680;            // 10*1024*320
    float* part = act  + 3276800;           // 10*1024*384 (slices 0-4 dyn, 5-9 static)
    float* bgf  = part + 3932160;           // 256*256
    float* bgb  = bgf  + 65536;             // 256*256
    float* beat_hidden = bgb + 65536;       // 256*128
    float* mgf  = beat_hidden + 32768;      // 64*128
    float* mgb  = mgf  + 8192;              // 64*128
    float* meas_hidden = mgb + 8192;        // 64*64
    int*   cnt  = (int*)(meas_hidden + 4096);  // 10*1024
    int*   idx  = cnt + 10240;                  // 10*1024*64

    float* part_s = part + 5*NN*384;        // static slices base

    hipMemsetAsync(cnt, 0, EE*NN*sizeof(int), stream);
    k_csr_build<<<EE*NN, 256, 0, stream>>>(adj, cnt, idx);
    k_note_fc<<<NN, 128, 0, stream>>>(nodes, fc_w, fc_b, nh);

    for (int si = 0; si < 2; ++si){
        for (int half = 0; half < 2; ++half){
            float* x = half ? nh2 : nh;
            int w = half;                     // weight set index
            bool zerostatic = (si == 0 && half == 0);   // nh[:, :192] == 0
            if (half == 1)                    // nb = relu(nh @ gb_w) -> nh2
                k_gb<<<NN/4, SS, 0, stream>>>(nh, gb_w, gb_b, nh2);
            if (!zerostatic){
                k_gather_act_rng<<<EE*NN, 192, 0, stream>>>(x, cnt, idx, act, 0);
                k_gate_gemm_rng<0,192><<<dim3(32,3,5), 256, 0, stream>>>(
                        act, g_wz[w], g_wr[w], g_wh[w], part_s);
            }
            int nsp = zerostatic ? 5 : 10;
            for (int it = 0; it < 2; ++it){
                k_gather_act_rng<<<EE*NN, 128, 0, stream>>>(x, cnt, idx, act, 192);
                k_gate_gemm_rng<192,320><<<dim3(32,3,5), 256, 0, stream>>>(
                        act, g_wz[w], g_wr[w], g_wh[w], part);
                k_gru<<<NN/2, 128, 0, stream>>>(x, part, nsp,
                        g_uz[w], g_ur[w], g_uh[w], g_bz[w], g_br[w], g_bh[w]);
            }
        }
        k_batt_fused<<<NB, 256, 0, stream>>>(nh, nh2, batt_w, batt_b, batt_c,
                                             bwi_f, bb_f, bwi_b, bb_b, bgf, bgb);
        k_lstm_rec64<<<2, 256, 0, stream>>>(bgf, bwh_f, bgb, bwh_b, beat_hidden);
        k_matt_fused<<<NM, 128, 0, stream>>>(beat_hidden, matt_w, matt_b, matt_c,
                                             mwi_f, mb_f, mwi_b, mb_b, mgf, mgb);
        k_lstm_rec32<<<2, 64, 0, stream>>>(mgf, mwh_f, mgb, mwh_b, meas_hidden);
        if (si == 0)
            k_spans<<<NN, SS, 0, stream>>>(nh, beat_hidden, meas_hidden, bn, mn);
        else
            k_spans_out<<<NN, 448, 0, stream>>>(beat_hidden, meas_hidden, nh, nh2,
                                                bn, mn, out);
    }
}

// Round 10
// 1041.377 us; speedup vs baseline: 1.2376x; 1.0421x over previous
//
#include <hip/hip_runtime.h>
#include <math.h>

// ---------------------------------------------------------------------------
// IsgnBeatMeasEncoder — round 14: rec64 intra-wave gate exchange + float4 gather.
// Round-13: static/dyn split delivered (1236 -> 1085). gather+gemm block is
// real and ∝work (-37% work -> -151us); boundaries small.
// Round 14:
//   - rec64 v2: wave w owns h[16w..16w+16), lane = gate*16+offset (still 64
//     weight VGPRs/lane = proven size). i/f/g/o combine via 4 intra-wave
//     __shfl (~50cy) replacing the gsum LDS round-trip (~240cy). hs double-
//     buffered on step parity -> partitioned writes race-free with ONE
//     barrier/step. Chain ~660 -> ~450 cy/step.
//   - gathers vectorized to float4 (4 cols/thread, 4x fewer load issues);
//     it0 of non-zerostatic halves uses ONE full 320-col gather feeding both
//     static and dyn GEMMs (-3 dispatches, CSR lists read once).
//   - all else unchanged from r13.
// Falsification: rec64 >=115us -> chain is hv+gates bound, freeze forever.
// ---------------------------------------------------------------------------

#define NN    1024
#define EE    10
#define INDIM 78
#define SS    320
#define SECD  128
#define NB    256
#define NM    64
#define CAP   64     // max nonzeros per adjacency column (mean ~10.2)

typedef float v2f __attribute__((ext_vector_type(2)));

__device__ __forceinline__ void pkfma(v2f& a, v2f x, v2f y){
    asm("v_pk_fma_f32 %0, %1, %2, %0" : "+v"(a) : "v"(x), "v"(y));
}
// a.lo += x.lo*b.lo ; a.hi += x.hi*b.lo   (broadcast LOW half of b)
__device__ __forceinline__ void pkfma_blo(v2f& a, v2f x, v2f b){
    asm("v_pk_fma_f32 %0, %1, %2, %0 op_sel:[0,0,0] op_sel_hi:[1,0,1]"
        : "+v"(a) : "v"(x), "v"(b));
}
// a.lo += x.lo*b.hi ; a.hi += x.hi*b.hi   (broadcast HIGH half of b)
__device__ __forceinline__ void pkfma_bhi(v2f& a, v2f x, v2f b){
    asm("v_pk_fma_f32 %0, %1, %2, %0 op_sel:[0,1,0] op_sel_hi:[1,1,1]"
        : "+v"(a) : "v"(x), "v"(b));
}

#define LO2(F) ((v2f){F.x, F.y})
#define HI2(F) ((v2f){F.z, F.w})

__device__ __forceinline__ float fsig(float x){
    return __builtin_amdgcn_rcpf(1.f + __expf(-x));
}
__device__ __forceinline__ float ftanh(float x){
    // tanh(x) = 1 - 2/(exp(2x)+1); exp overflow -> inf -> rcp -> 0 -> 1 (correct)
    return 1.f - 2.f*__builtin_amdgcn_rcpf(1.f + __expf(2.f*x));
}

// ---------------- note_fc: x0 = tanh(nodes @ W + b); nh = [0(192) | x0] ------------
__global__ void k_note_fc(const float* __restrict__ nodes, const float* __restrict__ W,
                          const float* __restrict__ b, float* __restrict__ nh){
    int n = blockIdx.x, s = threadIdx.x;           // 128 threads
    __shared__ float xrow[INDIM];
    if (s < INDIM) xrow[s] = nodes[n*INDIM + s];
    __syncthreads();
    float acc = b[s];
    for (int k = 0; k < INDIM; ++k) acc += xrow[k]*W[k*128 + s];
    nh[n*SS + 192 + s] = ftanh(acc);
    nh[n*SS + s] = 0.f;
    if (s < 64) nh[n*SS + 128 + s] = 0.f;
}

// ---------------- CSR build: float4 scan of each adj row ---------------------------
__global__ void k_csr_build(const float* __restrict__ adj, int* __restrict__ cnt,
                            int* __restrict__ idx){
    int em = blockIdx.x;                   // e*NN + m  (row of adj[e])
    int e = em / NN, m = em % NN;
    const float4* row4 = (const float4*)(adj + (size_t)em * NN);
    int q = threadIdx.x;                   // 256 threads, 256 float4 = 1024 cols
    float4 v = row4[q];
    int n0 = q*4;
    if (v.x != 0.f){ int p = atomicAdd(&cnt[e*NN + n0+0], 1); if (p < CAP) idx[((size_t)e*NN + n0+0)*CAP + p] = m; }
    if (v.y != 0.f){ int p = atomicAdd(&cnt[e*NN + n0+1], 1); if (p < CAP) idx[((size_t)e*NN + n0+1)*CAP + p] = m; }
    if (v.z != 0.f){ int p = atomicAdd(&cnt[e*NN + n0+2], 1); if (p < CAP) idx[((size_t)e*NN + n0+2)*CAP + p] = m; }
    if (v.w != 0.f){ int p = atomicAdd(&cnt[e*NN + n0+3], 1); if (p < CAP) idx[((size_t)e*NN + n0+3)*CAP + p] = m; }
}

// ---------------- full gather (320 cols), float4: 80 quads/en, 4 en/block ----------
__global__ void k_gather_full(const float* __restrict__ x, const int* __restrict__ cnt,
                              const int* __restrict__ idx, float* __restrict__ act){
    int en = blockIdx.x*4 + threadIdx.x/80;        // 320 threads
    int q  = threadIdx.x % 80;
    int c = cnt[en]; if (c > CAP) c = CAP;
    const int* lst = idx + (size_t)en*CAP;
    float4 acc = {0.f,0.f,0.f,0.f};
    const float* xb = x + q*4;
    for (int j = 0; j < c; ++j){
        float4 v = *(const float4*)(xb + (size_t)lst[j]*SS);
        acc.x += v.x; acc.y += v.y; acc.z += v.z; acc.w += v.w;
    }
    *(float4*)(act + (size_t)en*SS + q*4) = acc;
}

// ---------------- dyn gather (cols 192..320), float4: 32 quads/en, 8 en/block ------
__global__ void k_gather_dyn(const float* __restrict__ x, const int* __restrict__ cnt,
                             const int* __restrict__ idx, float* __restrict__ act){
    int en = blockIdx.x*8 + (threadIdx.x >> 5);    // 256 threads
    int q  = threadIdx.x & 31;
    int c = cnt[en]; if (c > CAP) c = CAP;
    const int* lst = idx + (size_t)en*CAP;
    float4 acc = {0.f,0.f,0.f,0.f};
    const float* xb = x + 192 + q*4;
    for (int j = 0; j < c; ++j){
        float4 v = *(const float4*)(xb + (size_t)lst[j]*SS);
        acc.x += v.x; acc.y += v.y; acc.z += v.z; acc.w += v.w;
    }
    *(float4*)(act + (size_t)en*SS + 192 + q*4) = acc;
}

// ---------------- gate GEMM over K range [K0,K1): 32-row tiles, 480 blocks ---------
// part layout per base: [5 z][1024 n][384] (3 gates x 128).
template<int K0, int K1>
__global__ __launch_bounds__(256) void k_gate_gemm_rng(const float* __restrict__ act,
        const float* __restrict__ wz, const float* __restrict__ wr,
        const float* __restrict__ wh, float* __restrict__ part){
    __shared__ float A[32*36];     // [kk][row], 32 rows pad 36
    __shared__ float B[32*132];    // [kk][col], pad 132
    int nt = blockIdx.x, g = blockIdx.y, z = blockIdx.z;
    const float* W = (g==0) ? wz : ((g==1) ? wr : wh);
    int tid = threadIdx.x;
    int tx = tid & 31;             // cols tx*4 .. +3
    int ty = tid >> 5;             // rows ty*4 .. +3
    v2f acc[2][4];                 // [row-pair][col]; .x=row ty*4+2rp, .y=+1
    #pragma unroll
    for (int i=0;i<2;i++)
        #pragma unroll
        for (int j=0;j<4;j++) acc[i][j] = (v2f){0.f,0.f};
    for (int eh = 0; eh < 2; ++eh){
        int e = z*2 + eh;
        const float* Ae = act + (size_t)e*NN*SS + (size_t)nt*32*SS;
        const float* We = W   + (size_t)e*SS*SECD;
        for (int kc = K0; kc < K1; kc += 32){
            {                                      // A: 32 rows x 32 k = 256 float4
                int r  = tid >> 3;
                int k4 = (tid & 7) << 2;
                float4 v = *(const float4*)(Ae + r*SS + kc + k4);
                A[(k4+0)*36 + r] = v.x; A[(k4+1)*36 + r] = v.y;
                A[(k4+2)*36 + r] = v.z; A[(k4+3)*36 + r] = v.w;
            }
            #pragma unroll
            for (int i=0;i<4;i++){                 // B: 32 k x 128 cols
                int lin4 = tid + i*256;            // 1024 float4
                int kk = lin4 >> 5;
                int c4 = (lin4 & 31) << 2;
                *((float4*)(B + kk*132 + c4)) = *(const float4*)(We + (kc+kk)*SECD + c4);
            }
            __syncthreads();
            #pragma unroll 8
            for (int k=0;k<32;k++){
                const v2f* A2 = (const v2f*)(A + k*36 + ty*4);   // wave-uniform
                v2f a01 = A2[0], a23 = A2[1];
                float4 b = *(const float4*)(B + k*132 + tx*4);   // r8-proven pattern
                v2f b01 = {b.x, b.y}, b23 = {b.z, b.w};
                pkfma_blo(acc[0][0], a01, b01); pkfma_bhi(acc[0][1], a01, b01);
                pkfma_blo(acc[0][2], a01, b23); pkfma_bhi(acc[0][3], a01, b23);
                pkfma_blo(acc[1][0], a23, b01); pkfma_bhi(acc[1][1], a23, b01);
                pkfma_blo(acc[1][2], a23, b23); pkfma_bhi(acc[1][3], a23, b23);
            }
            __syncthreads();
        }
    }
    float* P = part + ((size_t)z*NN + (size_t)nt*32)*384 + g*SECD;
    int r0 = ty*4;
    *(float4*)(P + (size_t)(r0+0)*384 + tx*4) =
        make_float4(acc[0][0].x, acc[0][1].x, acc[0][2].x, acc[0][3].x);
    *(float4*)(P + (size_t)(r0+1)*384 + tx*4) =
        make_float4(acc[0][0].y, acc[0][1].y, acc[0][2].y, acc[0][3].y);
    *(float4*)(P + (size_t)(r0+2)*384 + tx*4) =
        make_float4(acc[1][0].x, acc[1][1].x, acc[1][2].x, acc[1][3].x);
    *(float4*)(P + (size_t)(r0+3)*384 + tx*4) =
        make_float4(acc[1][0].y, acc[1][1].y, acc[1][2].y, acc[1][3].y);
}

// ---------------- GRU update, 2 notes/block; sums nsp part slices ------------------
__global__ void k_gru(float* __restrict__ x, const float* __restrict__ part, int nsp,
        const float* __restrict__ uz, const float* __restrict__ ur, const float* __restrict__ uh,
        const float* __restrict__ bz, const float* __restrict__ br, const float* __restrict__ bh){
    int n0 = blockIdx.x*2, s = threadIdx.x;        // 128 threads
    __shared__ float xs[2][SECD], rx[2][SECD];
    #pragma unroll
    for (int j=0;j<2;j++) xs[j][s] = x[(n0+j)*SS + 192 + s];
    __syncthreads();
    float mz[2]={0,0}, mr[2]={0,0}, mh[2]={0,0};
    for (int sp=0; sp<nsp; sp++){
        const float* Pp = part + ((size_t)sp*NN + n0)*384;
        #pragma unroll
        for (int j=0;j<2;j++){
            mz[j] += Pp[j*384 + s];
            mr[j] += Pp[j*384 + 128 + s];
            mh[j] += Pp[j*384 + 256 + s];
        }
    }
    float dz[2]={0,0}, dr[2]={0,0};
    for (int k=0;k<SECD;k++){
        float wz_ = uz[k*SECD + s], wr_ = ur[k*SECD + s];
        #pragma unroll
        for (int j=0;j<2;j++){ float xv = xs[j][k]; dz[j] += xv*wz_; dr[j] += xv*wr_; }
    }
    float zz[2], rr[2];
    #pragma unroll
    for (int j=0;j<2;j++){
        zz[j] = fsig(mz[j] + dz[j] + bz[s]);
        rr[j] = fsig(mr[j] + dr[j] + br[s]);
        rx[j][s] = rr[j]*xs[j][s];
    }
    __syncthreads();
    float dh[2]={0,0};
    for (int k=0;k<SECD;k++){
        float wh_ = uh[k*SECD + s];
        #pragma unroll
        for (int j=0;j<2;j++) dh[j] += rx[j][k]*wh_;
    }
    #pragma unroll
    for (int j=0;j<2;j++){
        float h = ftanh(mh[j] + dh[j] + bh[s]);
        x[(n0+j)*SS + 192 + s] = (1.f - zz[j])*xs[j][s] + rr[j]*h;
    }
}

// ---------------- nb = relu(nh @ gb_w + gb_b) -> nh2; 4 notes/block, 256 blocks ----
__global__ void k_gb(const float* __restrict__ nh, const float* __restrict__ W,
                     const float* __restrict__ b, float* __restrict__ nb){
    int n0 = blockIdx.x*4, s = threadIdx.x;        // 320 threads
    __shared__ float xr_t[SS*4];                   // [k][j] — j-pairs adjacent
    {
        float v0 = nh[(n0+0)*SS + s], v1 = nh[(n0+1)*SS + s];
        float v2 = nh[(n0+2)*SS + s], v3 = nh[(n0+3)*SS + s];
        *(float4*)(xr_t + s*4) = make_float4(v0,v1,v2,v3);
    }
    __syncthreads();
    float bv = b[s];
    v2f a01={bv,bv}, a23={bv,bv};
    for (int k=0;k<SS;k++){
        float wv = W[k*SS + s];
        v2f ws = {wv, wv};
        const v2f* xp = (const v2f*)(xr_t + k*4);  // uniform addr -> broadcast
        pkfma(a01, xp[0], ws);
        pkfma(a23, xp[1], ws);
    }
    nb[(n0+0)*SS + s] = fmaxf(a01.x, 0.f);
    nb[(n0+1)*SS + s] = fmaxf(a01.y, 0.f);
    nb[(n0+2)*SS + s] = fmaxf(a23.x, 0.f);
    nb[(n0+3)*SS + s] = fmaxf(a23.y, 0.f);
}

// ---------------- FUSED beat attention + lstm_pre (transposed tile + pkfma) --------
__global__ __launch_bounds__(256) void k_batt_fused(
        const float* __restrict__ nh, const float* __restrict__ nh2,
        const float* __restrict__ W, const float* __restrict__ b,
        const float* __restrict__ cvec,
        const float* __restrict__ wi_f, const float* __restrict__ b_f,
        const float* __restrict__ wi_b, const float* __restrict__ b_b,
        float* __restrict__ gf, float* __restrict__ gbo){
    int g = blockIdx.x, s = threadIdx.x;           // 256 threads
    __shared__ float xr_t[256*4];                  // [k][j]
    __shared__ float simw[4][8];
    __shared__ float wgt[4][8];
    __shared__ float bnode[256];
    {
        float c0,c1,c2,c3;
        if (s < 128){
            c0 = nh[(g*4+0)*SS + 192 + s]; c1 = nh[(g*4+1)*SS + 192 + s];
            c2 = nh[(g*4+2)*SS + 192 + s]; c3 = nh[(g*4+3)*SS + 192 + s];
        } else {
            c0 = nh2[(g*4+0)*SS + 64 + s]; c1 = nh2[(g*4+1)*SS + 64 + s];
            c2 = nh2[(g*4+2)*SS + 64 + s]; c3 = nh2[(g*4+3)*SS + 64 + s];
        }
        *(float4*)(xr_t + s*4) = make_float4(c0,c1,c2,c3);
    }
    __syncthreads();
    float bias = b[s];
    v2f ac01 = {bias,bias}, ac23 = {bias,bias};
    for (int k=0;k<256;k++){
        float wv = W[k*256 + s];
        v2f ws = {wv, wv};
        const v2f* xp = (const v2f*)(xr_t + k*4);
        pkfma(ac01, xp[0], ws);
        pkfma(ac23, xp[1], ws);
    }
    float accj[4] = {ac01.x, ac01.y, ac23.x, ac23.y};
    float cv = cvec[s];
    int h = s >> 5;                                // head (HD=32)
    #pragma unroll
    for (int j=0;j<4;j++){
        float p = ftanh(accj[j])*cv;
        #pragma unroll
        for (int off=16; off>0; off>>=1) p += __shfl_down(p, off);
        if ((s & 31) == 0) simw[j][h] = p;
    }
    __syncthreads();
    if (s < 8){
        float v0=simw[0][s], v1=simw[1][s], v2=simw[2][s], v3=simw[3][s];
        float mx = fmaxf(fmaxf(v0,v1), fmaxf(v2,v3));
        float e0=__expf(v0-mx), e1=__expf(v1-mx), e2=__expf(v2-mx), e3=__expf(v3-mx);
        float den = e0+e1+e2+e3;
        wgt[0][s]=e0/den; wgt[1][s]=e1/den; wgt[2][s]=e2/den; wgt[3][s]=e3/den;
    }
    __syncthreads();
    float4 xs4 = *(const float4*)(xr_t + s*4);
    float o = xs4.x*wgt[0][h] + xs4.y*wgt[1][h] + xs4.z*wgt[2][h] + xs4.w*wgt[3][h];
    bnode[s] = o;
    __syncthreads();
    // pre-GEMV, both directions: contiguous weight rows as v2f, elementwise pkfma
    v2f afA = {b_f[s], 0.f}, afB = {0.f, 0.f};
    v2f abA = {b_b[s], 0.f}, abB = {0.f, 0.f};
    const v2f* wfp = (const v2f*)(wi_f + (size_t)s*256);
    const v2f* wbp = (const v2f*)(wi_b + (size_t)s*256);
    const v2f* bp  = (const v2f*)bnode;
    for (int k2=0;k2<128;k2+=2){
        v2f x01 = bp[k2], x23 = bp[k2+1];
        pkfma(afA, wfp[k2], x01); pkfma(afB, wfp[k2+1], x23);
        pkfma(abA, wbp[k2], x01); pkfma(abB, wbp[k2+1], x23);
    }
    gf [g*256 + s] = (afA.x + afA.y) + (afB.x + afB.y);
    gbo[g*256 + s] = (abA.x + abA.y) + (abB.x + abB.y);
}

// ---------------- FUSED measure attention + lstm_pre -------------------------------
__global__ __launch_bounds__(128) void k_matt_fused(
        const float* __restrict__ bh,   // beat_hidden [256][128]
        const float* __restrict__ W, const float* __restrict__ b,
        const float* __restrict__ cvec,
        const float* __restrict__ wi_f, const float* __restrict__ b_f,
        const float* __restrict__ wi_b, const float* __restrict__ b_b,
        float* __restrict__ gf, float* __restrict__ gbo){
    int g = blockIdx.x, s = threadIdx.x;           // 128 threads
    __shared__ float xr_t[128*4];                  // [k][j]
    __shared__ float simw[4][8];
    __shared__ float wgt[4][8];
    __shared__ float mnode[128];
    {
        float c0 = bh[(g*4+0)*128 + s], c1 = bh[(g*4+1)*128 + s];
        float c2 = bh[(g*4+2)*128 + s], c3 = bh[(g*4+3)*128 + s];
        *(float4*)(xr_t + s*4) = make_float4(c0,c1,c2,c3);
    }
    __syncthreads();
    float bias = b[s];
    v2f ac01 = {bias,bias}, ac23 = {bias,bias};
    for (int k=0;k<128;k++){
        float wv = W[k*128 + s];
        v2f ws = {wv, wv};
        const v2f* xp = (const v2f*)(xr_t + k*4);
        pkfma(ac01, xp[0], ws);
        pkfma(ac23, xp[1], ws);
    }
    float accj[4] = {ac01.x, ac01.y, ac23.x, ac23.y};
    float cv = cvec[s];
    int h = s >> 4;                                // head (HD=16)
    #pragma unroll
    for (int j=0;j<4;j++){
        float p = ftanh(accj[j])*cv;
        #pragma unroll
        for (int off=8; off>0; off>>=1) p += __shfl_down(p, off);
        if ((s & 15) == 0) simw[j][h] = p;
    }
    __syncthreads();
    if (s < 8){
        float v0=simw[0][s], v1=simw[1][s], v2=simw[2][s], v3=simw[3][s];
        float mx = fmaxf(fmaxf(v0,v1), fmaxf(v2,v3));
        float e0=__expf(v0-mx), e1=__expf(v1-mx), e2=__expf(v2-mx), e3=__expf(v3-mx);
        float den = e0+e1+e2+e3;
        wgt[0][s]=e0/den; wgt[1][s]=e1/den; wgt[2][s]=e2/den; wgt[3][s]=e3/den;
    }
    __syncthreads();
    float4 xs4 = *(const float4*)(xr_t + s*4);
    float o = xs4.x*wgt[0][h] + xs4.y*wgt[1][h] + xs4.z*wgt[2][h] + xs4.w*wgt[3][h];
    mnode[s] = o;
    __syncthreads();
    v2f afA = {b_f[s], 0.f}, afB = {0.f, 0.f};
    v2f abA = {b_b[s], 0.f}, abB = {0.f, 0.f};
    const v2f* wfp = (const v2f*)(wi_f + (size_t)s*128);
    const v2f* wbp = (const v2f*)(wi_b + (size_t)s*128);
    const v2f* bp  = (const v2f*)mnode;
    for (int k2=0;k2<64;k2+=2){
        v2f x01 = bp[k2], x23 = bp[k2+1];
        pkfma(afA, wfp[k2], x01); pkfma(afB, wfp[k2+1], x23);
        pkfma(abA, wbp[k2], x01); pkfma(abB, wbp[k2+1], x23);
    }
    gf [g*128 + s] = (afA.x + afA.y) + (afB.x + afB.y);
    gbo[g*128 + s] = (abA.x + abA.y) + (abB.x + abB.y);
}

// ---------------- LSTM recurrence, H=64 T=256: v2 — intra-wave gate exchange -------
// Wave w owns h[16w..16w+16). Lane j: gate g=j>>4, offset o=j&15, h l=16w+o,
// gate row = g*64+l (64 weight floats -> proven-registerizing size).
// i/f/g/o combine via 4 intra-wave __shfl — no gsum LDS round-trip. hs double-
// buffered on step parity; partitioned writes race-free with ONE barrier/step.
__global__ __launch_bounds__(256)
__attribute__((amdgpu_waves_per_eu(1, 1)))
void k_lstm_rec64(
        const float* __restrict__ gin_f, const float* __restrict__ wh_f,
        const float* __restrict__ gin_b, const float* __restrict__ wh_b,
        float* __restrict__ hid /* [T][128] */){
    const int H = 64, T = 256;
    int dir = blockIdx.x;
    const float* gin = dir ? gin_b : gin_f;
    const float* wh  = dir ? wh_b  : wh_f;
    int gi = threadIdx.x;
    int w  = gi >> 6;                      // wave
    int j  = gi & 63;                      // lane
    int o  = j & 15;                       // h offset within wave's range
    int g  = j >> 4;                       // gate (0=i,1=f,2=g,3=o)
    int l  = (w << 4) + o;                 // h index
    int row = (g << 6) + l;                // gate row in [0,256)
    const v2f* wp = (const v2f*)(wh + (size_t)row*H);
    v2f w00=wp[0], w01=wp[1], w02=wp[2], w03=wp[3], w04=wp[4], w05=wp[5], w06=wp[6], w07=wp[7],
        w08=wp[8], w09=wp[9], w10=wp[10],w11=wp[11],w12=wp[12],w13=wp[13],w14=wp[14],w15=wp[15],
        w16=wp[16],w17=wp[17],w18=wp[18],w19=wp[19],w20=wp[20],w21=wp[21],w22=wp[22],w23=wp[23],
        w24=wp[24],w25=wp[25],w26=wp[26],w27=wp[27],w28=wp[28],w29=wp[29],w30=wp[30],w31=wp[31];
    __shared__ __align__(16) float hsb[2][H];
    float c = 0.f;
    if (gi < H) hsb[0][gi] = 0.f;
    __syncthreads();
    const float* gp = gin + row;
    float gcur = gp[(dir ? (T-1) : 0)*256];
    for (int step=0; step<T; step++){
        int t = dir ? (T-1-step) : step;
        float gnext = 0.f;
        if (step+1 < T) gnext = gp[(dir ? (T-2-step) : (step+1))*256];
        const float4* hv = (const float4*)hsb[step & 1];   // uniform addr, b128
        float4 H0=hv[0],  H1=hv[1],  H2=hv[2],  H3=hv[3];
        float4 H4=hv[4],  H5=hv[5],  H6=hv[6],  H7=hv[7];
        float4 H8=hv[8],  H9=hv[9],  H10=hv[10],H11=hv[11];
        float4 H12=hv[12],H13=hv[13],H14=hv[14],H15=hv[15];
        v2f A0={gcur,0.f}, A1={0.f,0.f}, A2={0.f,0.f}, A3={0.f,0.f};
        pkfma(A0,w00,LO2(H0));  pkfma(A1,w01,HI2(H0));  pkfma(A2,w02,LO2(H1));  pkfma(A3,w03,HI2(H1));
        pkfma(A0,w04,LO2(H2));  pkfma(A1,w05,HI2(H2));  pkfma(A2,w06,LO2(H3));  pkfma(A3,w07,HI2(H3));
        pkfma(A0,w08,LO2(H4));  pkfma(A1,w09,HI2(H4));  pkfma(A2,w10,LO2(H5));  pkfma(A3,w11,HI2(H5));
        pkfma(A0,w12,LO2(H6));  pkfma(A1,w13,HI2(H6));  pkfma(A2,w14,LO2(H7));  pkfma(A3,w15,HI2(H7));
        pkfma(A0,w16,LO2(H8));  pkfma(A1,w17,HI2(H8));  pkfma(A2,w18,LO2(H9));  pkfma(A3,w19,HI2(H9));
        pkfma(A0,w20,LO2(H10)); pkfma(A1,w21,HI2(H10)); pkfma(A2,w22,LO2(H11)); pkfma(A3,w23,HI2(H11));
        pkfma(A0,w24,LO2(H12)); pkfma(A1,w25,HI2(H12)); pkfma(A2,w26,LO2(H13)); pkfma(A3,w27,HI2(H13));
        pkfma(A0,w28,LO2(H14)); pkfma(A1,w29,HI2(H14)); pkfma(A2,w30,LO2(H15)); pkfma(A3,w31,HI2(H15));
        float val = ((A0.x+A0.y) + (A1.x+A1.y)) + ((A2.x+A2.y) + (A3.x+A3.y));
        // intra-wave gate exchange: i/f/g/o for h=l live in lanes o, o+16, o+32, o+48
        float i_ = __shfl(val, o);
        float f_ = __shfl(val, o + 16);
        float g_ = __shfl(val, o + 32);
        float o_ = __shfl(val, o + 48);
        c = fsig(f_)*c + fsig(i_)*ftanh(g_);   // 4 lanes per l: identical update
        float hn = fsig(o_)*ftanh(c);
        if (g == 0){
            hsb[(step+1)&1][l] = hn;           // partitioned write, other buffer
            hid[t*2*H + dir*H + l] = hn;
        }
        __syncthreads();                       // the ONLY barrier per step
        gcur = gnext;
    }
}

// ---------------- LSTM recurrence, H=32 T=64: single wave, NO barrier --------------
__global__ __launch_bounds__(64)
__attribute__((amdgpu_waves_per_eu(1, 1)))
void k_lstm_rec32(
        const float* __restrict__ gin_f, const float* __restrict__ wh_f,
        const float* __restrict__ gin_b, const float* __restrict__ wh_b,
        float* __restrict__ hid /* [T][64] */){
    const int H = 32, T = 64;
    int dir = blockIdx.x;
    const float* gin = dir ? gin_b : gin_f;
    const float* wh  = dir ? wh_b  : wh_f;
    int gi = threadIdx.x;                  // 0..63
    v2f wA[16], wB[16];
    {
        const v2f* rA = (const v2f*)(wh + (size_t)(     gi)*H);   // rows 0..63:  i|f
        const v2f* rB = (const v2f*)(wh + (size_t)(64 + gi)*H);   // rows 64..127: g|o
        #pragma unroll
        for (int k=0;k<16;k++){ wA[k]=rA[k]; wB[k]=rB[k]; }
    }
    __shared__ __align__(16) float hs[H];
    float c = 0.f;
    if (gi < H) hs[gi] = 0.f;
    __syncthreads();
    const float* gp = gin + gi;
    int ts0 = dir ? (T-1) : 0, ts1 = dir ? (T-2) : 1;
    float g0 = gp[ts0*128], g1 = gp[ts0*128 + 64];
    float n0 = gp[ts1*128], n1 = gp[ts1*128 + 64];
    bool lo = (gi < H);
    for (int step=0; step<T; step++){
        int t = dir ? (T-1-step) : step;
        float p0=0.f, p1=0.f;
        if (step+2 < T){
            int tp = dir ? (T-3-step) : (step+2);
            p0 = gp[tp*128]; p1 = gp[tp*128 + 64];
        }
        v2f aA = {g0, 0.f}, aB = {g1, 0.f};
        const float4* hv = (const float4*)hs;      // uniform addr, b128 reads
        #pragma unroll
        for (int k=0;k<8;k++){
            float4 h4 = hv[k];
            pkfma(aA, wA[2*k],   LO2(h4));
            pkfma(aB, wB[2*k],   LO2(h4));
            pkfma(aA, wA[2*k+1], HI2(h4));
            pkfma(aB, wB[2*k+1], HI2(h4));
        }
        float sA = aA.x + aA.y;            // lane<32: i ; lane>=32: f
        float sB = aB.x + aB.y;            // lane<32: g ; lane>=32: o
        float pA = __shfl(sA, gi ^ 32);
        float pB = __shfl(sB, gi ^ 32);
        float i_ = lo ? sA : pA;
        float f_ = lo ? pA : sA;
        float g_ = lo ? sB : pB;
        float o_ = lo ? pB : sB;
        c = fsig(f_)*c + fsig(i_)*ftanh(g_);
        float hn = fsig(o_)*ftanh(c);
        if (lo){
            hid[t*2*H + dir*H + gi] = hn;
            hs[gi] = hn;                   // same wave: in-order LDS, no barrier
        }
        g0 = n0; g1 = n1; n0 = p0; n1 = p1;
    }
}

// ---------------- si=0: rebuild nh in place = [beat_span | meas_span | nh_sec] -----
__global__ void k_spans(float* __restrict__ nh, const float* __restrict__ bh,
                        const float* __restrict__ mh,
                        const int* __restrict__ bn, const int* __restrict__ mn){
    int n = blockIdx.x, s = threadIdx.x;           // 320 threads
    float v;
    if (s < 128)      v = bh[bn[n]*128 + s];
    else if (s < 192) v = mh[mn[n]*64 + (s-128)];
    else              v = nh[n*SS + s];            // own-thread read-then-write: safe
    nh[n*SS + s] = v;
}

// ---------------- si=1: spans + final output fused ---------------------------------
__global__ void k_spans_out(const float* __restrict__ bh, const float* __restrict__ mh,
                            const float* __restrict__ nh, const float* __restrict__ nh2,
                            const int* __restrict__ bn, const int* __restrict__ mn,
                            float* __restrict__ out){
    int n = blockIdx.x, s = threadIdx.x;           // 448 threads
    float v;
    if (s < 128)      v = bh[bn[n]*128 + s];
    else if (s < 192) v = mh[mn[n]*64 + (s-128)];
    else if (s < 320) v = nh[n*SS + s];
    else              v = nh2[n*SS + 192 + (s-320)];
    out[n*448 + s] = v;
}

// ===========================================================================
extern "C" void kernel_launch(void* const* d_in, const int* in_sizes, int n_in,
                              void* d_out, int out_size, void* d_ws, size_t ws_size,
                              hipStream_t stream) {
    const float* nodes    = (const float*)d_in[0];
    const float* adj      = (const float*)d_in[1];
    const int*   bn       = (const int*)  d_in[2];
    const int*   mn       = (const int*)  d_in[3];
    const float* fc_w     = (const float*)d_in[6];
    const float* fc_b     = (const float*)d_in[7];
    const float* g_wz[2]  = {(const float*)d_in[8],  (const float*)d_in[17]};
    const float* g_wr[2]  = {(const float*)d_in[9],  (const float*)d_in[18]};
    const float* g_wh[2]  = {(const float*)d_in[10], (const float*)d_in[19]};
    const float* g_uz[2]  = {(const float*)d_in[11], (const float*)d_in[20]};
    const float* g_ur[2]  = {(const float*)d_in[12], (const float*)d_in[21]};
    const float* g_uh[2]  = {(const float*)d_in[13], (const float*)d_in[22]};
    const float* g_bz[2]  = {(const float*)d_in[14], (const float*)d_in[23]};
    const float* g_br[2]  = {(const float*)d_in[15], (const float*)d_in[24]};
    const float* g_bh[2]  = {(const float*)d_in[16], (const float*)d_in[25]};
    const float* gb_w     = (const float*)d_in[26];
    const float* gb_b     = (const float*)d_in[27];
    const float* batt_w   = (const float*)d_in[28];
    const float* batt_b   = (const float*)d_in[29];
    const float* batt_c   = (const float*)d_in[30];
    const float* matt_w   = (const float*)d_in[31];
    const float* matt_b   = (const float*)d_in[32];
    const float* matt_c   = (const float*)d_in[33];
    const float* bwi_f    = (const float*)d_in[34];
    const float* bwh_f    = (const float*)d_in[35];
    const float* bb_f     = (const float*)d_in[36];
    const float* bwi_b    = (const float*)d_in[37];
    const float* bwh_b    = (const float*)d_in[38];
    const float* bb_b     = (const float*)d_in[39];
    const float* mwi_f    = (const float*)d_in[40];
    const float* mwh_f    = (const float*)d_in[41];
    const float* mb_f     = (const float*)d_in[42];
    const float* mwi_b    = (const float*)d_in[43];
    const float* mwh_b    = (const float*)d_in[44];
    const float* mb_b     = (const float*)d_in[45];
    float* out = (float*)d_out;

    // --- workspace layout (floats; ~27.7 MB, under the 31.2MB proven in r0) ---
    float* W_   = (float*)d_ws;
    float* nh   = W_;                       // 1024*320
    float* nh2  = nh   + 327680;            // 1024*320
    float* act  = nh2  + 327680;            // 10*1024*320
    float* part = act  + 3276800;           // 10*1024*384 (slices 0-4 dyn, 5-9 static)
    float* bgf  = part + 3932160;           // 256*256
    float* bgb  = bgf  + 65536;             // 256*256
    float* beat_hidden = bgb + 65536;       // 256*128
    float* mgf  = beat_hidden + 32768;      // 64*128
    float* mgb  = mgf  + 8192;              // 64*128
    float* meas_hidden = mgb + 8192;        // 64*64
    int*   cnt  = (int*)(meas_hidden + 4096);  // 10*1024
    int*   idx  = cnt + 10240;                  // 10*1024*64

    float* part_s = part + 5*NN*384;        // static slices base

    hipMemsetAsync(cnt, 0, EE*NN*sizeof(int), stream);
    k_csr_build<<<EE*NN, 256, 0, stream>>>(adj, cnt, idx);
    k_note_fc<<<NN, 128, 0, stream>>>(nodes, fc_w, fc_b, nh);

    for (int si = 0; si < 2; ++si){
        for (int half = 0; half < 2; ++half){
            float* x = half ? nh2 : nh;
            int w = half;                     // weight set index
            bool zerostatic = (si == 0 && half == 0);   // nh[:, :192] == 0
            if (half == 1)                    // nb = relu(nh @ gb_w) -> nh2
                k_gb<<<NN/4, SS, 0, stream>>>(nh, gb_w, gb_b, nh2);
            int nsp = zerostatic ? 5 : 10;
            for (int it = 0; it < 2; ++it){
                if (!zerostatic && it == 0){
                    // one full 320-col gather feeds static AND dyn GEMMs
                    k_gather_full<<<EE*NN/4, 320, 0, stream>>>(x, cnt, idx, act);
                    k_gate_gemm_rng<0,192><<<dim3(32,3,5), 256, 0, stream>>>(
                            act, g_wz[w], g_wr[w], g_wh[w], part_s);
                } else {
                    k_gather_dyn<<<EE*NN/8, 256, 0, stream>>>(x, cnt, idx, act);
                }
                k_gate_gemm_rng<192,320><<<dim3(32,3,5), 256, 0, stream>>>(
                        act, g_wz[w], g_wr[w], g_wh[w], part);
                k_gru<<<NN/2, 128, 0, stream>>>(x, part, nsp,
                        g_uz[w], g_ur[w], g_uh[w], g_bz[w], g_br[w], g_bh[w]);
            }
        }
        k_batt_fused<<<NB, 256, 0, stream>>>(nh, nh2, batt_w, batt_b, batt_c,
                                             bwi_f, bb_f, bwi_b, bb_b, bgf, bgb);
        k_lstm_rec64<<<2, 256, 0, stream>>>(bgf, bwh_f, bgb, bwh_b, beat_hidden);
        k_matt_fused<<<NM, 128, 0, stream>>>(beat_hidden, matt_w, matt_b, matt_c,
                                             mwi_f, mb_f, mwi_b, mb_b, mgf, mgb);
        k_lstm_rec32<<<2, 64, 0, stream>>>(mgf, mwh_f, mgb, mwh_b, meas_hidden);
        if (si == 0)
            k_spans<<<NN, SS, 0, stream>>>(nh, beat_hidden, meas_hidden, bn, mn);
        else
            k_spans_out<<<NN, 448, 0, stream>>>(beat_hidden, meas_hidden, nh, nh2,
                                                bn, mn, out);
    }
}

// Round 11
// 1028.277 us; speedup vs baseline: 1.2534x; 1.0127x over previous
//
#include <hip/hip_runtime.h>
#include <math.h>

// ---------------------------------------------------------------------------
// IsgnBeatMeasEncoder — round 15: static-fold into dyn GEMM + leaner LDS reads.
// Round-14 post-mortem: total 1085 -> 1041. rec64 gate-exchange bought only
// 4us -> falsification fired: rec64 is hv-read + gate-chain LATENCY bound at
// ~1.4GHz; FROZEN permanently at ~116us x2. (21ms note_fc row = rocprof
// replay artifact; impossible inside a 1041us graph.)
// Round 15 (non-rec64 block, ~808us):
//   - dyn gemm folds the static slices into its epilogue (part_s tile is
//     congruent); k_gru always sums 5 slices (was 10) -> removes 30 global
//     loads/thread from 6 of 8 latency-bound gru calls, loop fully unrolls.
//   - gemm inner loop reads A as ONE float4 (rows ty*4..+3 contiguous,
//     16B-aligned) instead of 2x v2f: LDS issues per k 3 -> 2 (-33% LDS-pipe
//     pressure, the modeled inner-loop bottleneck).
// Falsification: gain <15us -> micro-modeling exhausted; next round is the
// cooperative mega-kernel experiment or declared plateau.
// ---------------------------------------------------------------------------

#define NN    1024
#define EE    10
#define INDIM 78
#define SS    320
#define SECD  128
#define NB    256
#define NM    64
#define CAP   64     // max nonzeros per adjacency column (mean ~10.2)

typedef float v2f __attribute__((ext_vector_type(2)));

__device__ __forceinline__ void pkfma(v2f& a, v2f x, v2f y){
    asm("v_pk_fma_f32 %0, %1, %2, %0" : "+v"(a) : "v"(x), "v"(y));
}
// a.lo += x.lo*b.lo ; a.hi += x.hi*b.lo   (broadcast LOW half of b)
__device__ __forceinline__ void pkfma_blo(v2f& a, v2f x, v2f b){
    asm("v_pk_fma_f32 %0, %1, %2, %0 op_sel:[0,0,0] op_sel_hi:[1,0,1]"
        : "+v"(a) : "v"(x), "v"(b));
}
// a.lo += x.lo*b.hi ; a.hi += x.hi*b.hi   (broadcast HIGH half of b)
__device__ __forceinline__ void pkfma_bhi(v2f& a, v2f x, v2f b){
    asm("v_pk_fma_f32 %0, %1, %2, %0 op_sel:[0,1,0] op_sel_hi:[1,1,1]"
        : "+v"(a) : "v"(x), "v"(b));
}

#define LO2(F) ((v2f){F.x, F.y})
#define HI2(F) ((v2f){F.z, F.w})

__device__ __forceinline__ float fsig(float x){
    return __builtin_amdgcn_rcpf(1.f + __expf(-x));
}
__device__ __forceinline__ float ftanh(float x){
    // tanh(x) = 1 - 2/(exp(2x)+1); exp overflow -> inf -> rcp -> 0 -> 1 (correct)
    return 1.f - 2.f*__builtin_amdgcn_rcpf(1.f + __expf(2.f*x));
}

// ---------------- note_fc: x0 = tanh(nodes @ W + b); nh = [0(192) | x0] ------------
__global__ void k_note_fc(const float* __restrict__ nodes, const float* __restrict__ W,
                          const float* __restrict__ b, float* __restrict__ nh){
    int n = blockIdx.x, s = threadIdx.x;           // 128 threads
    __shared__ float xrow[INDIM];
    if (s < INDIM) xrow[s] = nodes[n*INDIM + s];
    __syncthreads();
    float acc = b[s];
    for (int k = 0; k < INDIM; ++k) acc += xrow[k]*W[k*128 + s];
    nh[n*SS + 192 + s] = ftanh(acc);
    nh[n*SS + s] = 0.f;
    if (s < 64) nh[n*SS + 128 + s] = 0.f;
}

// ---------------- CSR build: float4 scan of each adj row ---------------------------
__global__ void k_csr_build(const float* __restrict__ adj, int* __restrict__ cnt,
                            int* __restrict__ idx){
    int em = blockIdx.x;                   // e*NN + m  (row of adj[e])
    int e = em / NN, m = em % NN;
    const float4* row4 = (const float4*)(adj + (size_t)em * NN);
    int q = threadIdx.x;                   // 256 threads, 256 float4 = 1024 cols
    float4 v = row4[q];
    int n0 = q*4;
    if (v.x != 0.f){ int p = atomicAdd(&cnt[e*NN + n0+0], 1); if (p < CAP) idx[((size_t)e*NN + n0+0)*CAP + p] = m; }
    if (v.y != 0.f){ int p = atomicAdd(&cnt[e*NN + n0+1], 1); if (p < CAP) idx[((size_t)e*NN + n0+1)*CAP + p] = m; }
    if (v.z != 0.f){ int p = atomicAdd(&cnt[e*NN + n0+2], 1); if (p < CAP) idx[((size_t)e*NN + n0+2)*CAP + p] = m; }
    if (v.w != 0.f){ int p = atomicAdd(&cnt[e*NN + n0+3], 1); if (p < CAP) idx[((size_t)e*NN + n0+3)*CAP + p] = m; }
}

// ---------------- full gather (320 cols), float4: 80 quads/en, 4 en/block ----------
__global__ void k_gather_full(const float* __restrict__ x, const int* __restrict__ cnt,
                              const int* __restrict__ idx, float* __restrict__ act){
    int en = blockIdx.x*4 + threadIdx.x/80;        // 320 threads
    int q  = threadIdx.x % 80;
    int c = cnt[en]; if (c > CAP) c = CAP;
    const int* lst = idx + (size_t)en*CAP;
    float4 acc = {0.f,0.f,0.f,0.f};
    const float* xb = x + q*4;
    for (int j = 0; j < c; ++j){
        float4 v = *(const float4*)(xb + (size_t)lst[j]*SS);
        acc.x += v.x; acc.y += v.y; acc.z += v.z; acc.w += v.w;
    }
    *(float4*)(act + (size_t)en*SS + q*4) = acc;
}

// ---------------- dyn gather (cols 192..320), float4: 32 quads/en, 8 en/block ------
__global__ void k_gather_dyn(const float* __restrict__ x, const int* __restrict__ cnt,
                             const int* __restrict__ idx, float* __restrict__ act){
    int en = blockIdx.x*8 + (threadIdx.x >> 5);    // 256 threads
    int q  = threadIdx.x & 31;
    int c = cnt[en]; if (c > CAP) c = CAP;
    const int* lst = idx + (size_t)en*CAP;
    float4 acc = {0.f,0.f,0.f,0.f};
    const float* xb = x + 192 + q*4;
    for (int j = 0; j < c; ++j){
        float4 v = *(const float4*)(xb + (size_t)lst[j]*SS);
        acc.x += v.x; acc.y += v.y; acc.z += v.z; acc.w += v.w;
    }
    *(float4*)(act + (size_t)en*SS + 192 + q*4) = acc;
}

// ---------------- gate GEMM over K range [K0,K1): 32-row tiles, 480 blocks ---------
// part layout per base: [5 z][1024 n][384] (3 gates x 128).
// addv != nullptr: congruent tile from addv (the static slices) added at the
// epilogue — gru then always reads 5 slices.
template<int K0, int K1>
__global__ __launch_bounds__(256) void k_gate_gemm_rng(const float* __restrict__ act,
        const float* __restrict__ wz, const float* __restrict__ wr,
        const float* __restrict__ wh, float* __restrict__ part,
        const float* __restrict__ addv){
    __shared__ float A[32*36];     // [kk][row], 32 rows pad 36
    __shared__ float B[32*132];    // [kk][col], pad 132
    int nt = blockIdx.x, g = blockIdx.y, z = blockIdx.z;
    const float* W = (g==0) ? wz : ((g==1) ? wr : wh);
    int tid = threadIdx.x;
    int tx = tid & 31;             // cols tx*4 .. +3
    int ty = tid >> 5;             // rows ty*4 .. +3
    v2f acc[2][4];                 // [row-pair][col]; .x=row ty*4+2rp, .y=+1
    #pragma unroll
    for (int i=0;i<2;i++)
        #pragma unroll
        for (int j=0;j<4;j++) acc[i][j] = (v2f){0.f,0.f};
    for (int eh = 0; eh < 2; ++eh){
        int e = z*2 + eh;
        const float* Ae = act + (size_t)e*NN*SS + (size_t)nt*32*SS;
        const float* We = W   + (size_t)e*SS*SECD;
        for (int kc = K0; kc < K1; kc += 32){
            {                                      // A: 32 rows x 32 k = 256 float4
                int r  = tid >> 3;
                int k4 = (tid & 7) << 2;
                float4 v = *(const float4*)(Ae + r*SS + kc + k4);
                A[(k4+0)*36 + r] = v.x; A[(k4+1)*36 + r] = v.y;
                A[(k4+2)*36 + r] = v.z; A[(k4+3)*36 + r] = v.w;
            }
            #pragma unroll
            for (int i=0;i<4;i++){                 // B: 32 k x 128 cols
                int lin4 = tid + i*256;            // 1024 float4
                int kk = lin4 >> 5;
                int c4 = (lin4 & 31) << 2;
                *((float4*)(B + kk*132 + c4)) = *(const float4*)(We + (kc+kk)*SECD + c4);
            }
            __syncthreads();
            #pragma unroll 8
            for (int k=0;k<32;k++){
                // A rows ty*4..+3 contiguous, 16B aligned: ONE ds_read_b128
                float4 a4 = *(const float4*)(A + k*36 + ty*4);   // wave-uniform
                v2f a01 = LO2(a4), a23 = HI2(a4);
                float4 b = *(const float4*)(B + k*132 + tx*4);   // r8-proven pattern
                v2f b01 = {b.x, b.y}, b23 = {b.z, b.w};
                pkfma_blo(acc[0][0], a01, b01); pkfma_bhi(acc[0][1], a01, b01);
                pkfma_blo(acc[0][2], a01, b23); pkfma_bhi(acc[0][3], a01, b23);
                pkfma_blo(acc[1][0], a23, b01); pkfma_bhi(acc[1][1], a23, b01);
                pkfma_blo(acc[1][2], a23, b23); pkfma_bhi(acc[1][3], a23, b23);
            }
            __syncthreads();
        }
    }
    size_t base = ((size_t)z*NN + (size_t)nt*32)*384 + g*SECD;
    float* P = part + base;
    int r0 = ty*4;
    float4 o0 = make_float4(acc[0][0].x, acc[0][1].x, acc[0][2].x, acc[0][3].x);
    float4 o1 = make_float4(acc[0][0].y, acc[0][1].y, acc[0][2].y, acc[0][3].y);
    float4 o2 = make_float4(acc[1][0].x, acc[1][1].x, acc[1][2].x, acc[1][3].x);
    float4 o3 = make_float4(acc[1][0].y, acc[1][1].y, acc[1][2].y, acc[1][3].y);
    if (addv){
        const float* Q = addv + base;
        float4 q0 = *(const float4*)(Q + (size_t)(r0+0)*384 + tx*4);
        float4 q1 = *(const float4*)(Q + (size_t)(r0+1)*384 + tx*4);
        float4 q2 = *(const float4*)(Q + (size_t)(r0+2)*384 + tx*4);
        float4 q3 = *(const float4*)(Q + (size_t)(r0+3)*384 + tx*4);
        o0.x+=q0.x; o0.y+=q0.y; o0.z+=q0.z; o0.w+=q0.w;
        o1.x+=q1.x; o1.y+=q1.y; o1.z+=q1.z; o1.w+=q1.w;
        o2.x+=q2.x; o2.y+=q2.y; o2.z+=q2.z; o2.w+=q2.w;
        o3.x+=q3.x; o3.y+=q3.y; o3.z+=q3.z; o3.w+=q3.w;
    }
    *(float4*)(P + (size_t)(r0+0)*384 + tx*4) = o0;
    *(float4*)(P + (size_t)(r0+1)*384 + tx*4) = o1;
    *(float4*)(P + (size_t)(r0+2)*384 + tx*4) = o2;
    *(float4*)(P + (size_t)(r0+3)*384 + tx*4) = o3;
}

// ---------------- GRU update, 2 notes/block; always 5 part slices ------------------
__global__ void k_gru(float* __restrict__ x, const float* __restrict__ part,
        const float* __restrict__ uz, const float* __restrict__ ur, const float* __restrict__ uh,
        const float* __restrict__ bz, const float* __restrict__ br, const float* __restrict__ bh){
    int n0 = blockIdx.x*2, s = threadIdx.x;        // 128 threads
    __shared__ float xs[2][SECD], rx[2][SECD];
    #pragma unroll
    for (int j=0;j<2;j++) xs[j][s] = x[(n0+j)*SS + 192 + s];
    __syncthreads();
    float mz[2]={0,0}, mr[2]={0,0}, mh[2]={0,0};
    #pragma unroll
    for (int sp=0; sp<5; sp++){
        const float* Pp = part + ((size_t)sp*NN + n0)*384;
        #pragma unroll
        for (int j=0;j<2;j++){
            mz[j] += Pp[j*384 + s];
            mr[j] += Pp[j*384 + 128 + s];
            mh[j] += Pp[j*384 + 256 + s];
        }
    }
    float dz[2]={0,0}, dr[2]={0,0};
    for (int k=0;k<SECD;k++){
        float wz_ = uz[k*SECD + s], wr_ = ur[k*SECD + s];
        #pragma unroll
        for (int j=0;j<2;j++){ float xv = xs[j][k]; dz[j] += xv*wz_; dr[j] += xv*wr_; }
    }
    float zz[2], rr[2];
    #pragma unroll
    for (int j=0;j<2;j++){
        zz[j] = fsig(mz[j] + dz[j] + bz[s]);
        rr[j] = fsig(mr[j] + dr[j] + br[s]);
        rx[j][s] = rr[j]*xs[j][s];
    }
    __syncthreads();
    float dh[2]={0,0};
    for (int k=0;k<SECD;k++){
        float wh_ = uh[k*SECD + s];
        #pragma unroll
        for (int j=0;j<2;j++) dh[j] += rx[j][k]*wh_;
    }
    #pragma unroll
    for (int j=0;j<2;j++){
        float h = ftanh(mh[j] + dh[j] + bh[s]);
        x[(n0+j)*SS + 192 + s] = (1.f - zz[j])*xs[j][s] + rr[j]*h;
    }
}

// ---------------- nb = relu(nh @ gb_w + gb_b) -> nh2; 4 notes/block, 256 blocks ----
__global__ void k_gb(const float* __restrict__ nh, const float* __restrict__ W,
                     const float* __restrict__ b, float* __restrict__ nb){
    int n0 = blockIdx.x*4, s = threadIdx.x;        // 320 threads
    __shared__ float xr_t[SS*4];                   // [k][j] — j-pairs adjacent
    {
        float v0 = nh[(n0+0)*SS + s], v1 = nh[(n0+1)*SS + s];
        float v2 = nh[(n0+2)*SS + s], v3 = nh[(n0+3)*SS + s];
        *(float4*)(xr_t + s*4) = make_float4(v0,v1,v2,v3);
    }
    __syncthreads();
    float bv = b[s];
    v2f a01={bv,bv}, a23={bv,bv};
    for (int k=0;k<SS;k++){
        float wv = W[k*SS + s];
        v2f ws = {wv, wv};
        const v2f* xp = (const v2f*)(xr_t + k*4);  // uniform addr -> broadcast
        pkfma(a01, xp[0], ws);
        pkfma(a23, xp[1], ws);
    }
    nb[(n0+0)*SS + s] = fmaxf(a01.x, 0.f);
    nb[(n0+1)*SS + s] = fmaxf(a01.y, 0.f);
    nb[(n0+2)*SS + s] = fmaxf(a23.x, 0.f);
    nb[(n0+3)*SS + s] = fmaxf(a23.y, 0.f);
}

// ---------------- FUSED beat attention + lstm_pre (transposed tile + pkfma) --------
__global__ __launch_bounds__(256) void k_batt_fused(
        const float* __restrict__ nh, const float* __restrict__ nh2,
        const float* __restrict__ W, const float* __restrict__ b,
        const float* __restrict__ cvec,
        const float* __restrict__ wi_f, const float* __restrict__ b_f,
        const float* __restrict__ wi_b, const float* __restrict__ b_b,
        float* __restrict__ gf, float* __restrict__ gbo){
    int g = blockIdx.x, s = threadIdx.x;           // 256 threads
    __shared__ float xr_t[256*4];                  // [k][j]
    __shared__ float simw[4][8];
    __shared__ float wgt[4][8];
    __shared__ float bnode[256];
    {
        float c0,c1,c2,c3;
        if (s < 128){
            c0 = nh[(g*4+0)*SS + 192 + s]; c1 = nh[(g*4+1)*SS + 192 + s];
            c2 = nh[(g*4+2)*SS + 192 + s]; c3 = nh[(g*4+3)*SS + 192 + s];
        } else {
            c0 = nh2[(g*4+0)*SS + 64 + s]; c1 = nh2[(g*4+1)*SS + 64 + s];
            c2 = nh2[(g*4+2)*SS + 64 + s]; c3 = nh2[(g*4+3)*SS + 64 + s];
        }
        *(float4*)(xr_t + s*4) = make_float4(c0,c1,c2,c3);
    }
    __syncthreads();
    float bias = b[s];
    v2f ac01 = {bias,bias}, ac23 = {bias,bias};
    for (int k=0;k<256;k++){
        float wv = W[k*256 + s];
        v2f ws = {wv, wv};
        const v2f* xp = (const v2f*)(xr_t + k*4);
        pkfma(ac01, xp[0], ws);
        pkfma(ac23, xp[1], ws);
    }
    float accj[4] = {ac01.x, ac01.y, ac23.x, ac23.y};
    float cv = cvec[s];
    int h = s >> 5;                                // head (HD=32)
    #pragma unroll
    for (int j=0;j<4;j++){
        float p = ftanh(accj[j])*cv;
        #pragma unroll
        for (int off=16; off>0; off>>=1) p += __shfl_down(p, off);
        if ((s & 31) == 0) simw[j][h] = p;
    }
    __syncthreads();
    if (s < 8){
        float v0=simw[0][s], v1=simw[1][s], v2=simw[2][s], v3=simw[3][s];
        float mx = fmaxf(fmaxf(v0,v1), fmaxf(v2,v3));
        float e0=__expf(v0-mx), e1=__expf(v1-mx), e2=__expf(v2-mx), e3=__expf(v3-mx);
        float den = e0+e1+e2+e3;
        wgt[0][s]=e0/den; wgt[1][s]=e1/den; wgt[2][s]=e2/den; wgt[3][s]=e3/den;
    }
    __syncthreads();
    float4 xs4 = *(const float4*)(xr_t + s*4);
    float o = xs4.x*wgt[0][h] + xs4.y*wgt[1][h] + xs4.z*wgt[2][h] + xs4.w*wgt[3][h];
    bnode[s] = o;
    __syncthreads();
    // pre-GEMV, both directions: contiguous weight rows as v2f, elementwise pkfma
    v2f afA = {b_f[s], 0.f}, afB = {0.f, 0.f};
    v2f abA = {b_b[s], 0.f}, abB = {0.f, 0.f};
    const v2f* wfp = (const v2f*)(wi_f + (size_t)s*256);
    const v2f* wbp = (const v2f*)(wi_b + (size_t)s*256);
    const v2f* bp  = (const v2f*)bnode;
    for (int k2=0;k2<128;k2+=2){
        v2f x01 = bp[k2], x23 = bp[k2+1];
        pkfma(afA, wfp[k2], x01); pkfma(afB, wfp[k2+1], x23);
        pkfma(abA, wbp[k2], x01); pkfma(abB, wbp[k2+1], x23);
    }
    gf [g*256 + s] = (afA.x + afA.y) + (afB.x + afB.y);
    gbo[g*256 + s] = (abA.x + abA.y) + (abB.x + abB.y);
}

// ---------------- FUSED measure attention + lstm_pre -------------------------------
__global__ __launch_bounds__(128) void k_matt_fused(
        const float* __restrict__ bh,   // beat_hidden [256][128]
        const float* __restrict__ W, const float* __restrict__ b,
        const float* __restrict__ cvec,
        const float* __restrict__ wi_f, const float* __restrict__ b_f,
        const float* __restrict__ wi_b, const float* __restrict__ b_b,
        float* __restrict__ gf, float* __restrict__ gbo){
    int g = blockIdx.x, s = threadIdx.x;           // 128 threads
    __shared__ float xr_t[128*4];                  // [k][j]
    __shared__ float simw[4][8];
    __shared__ float wgt[4][8];
    __shared__ float mnode[128];
    {
        float c0 = bh[(g*4+0)*128 + s], c1 = bh[(g*4+1)*128 + s];
        float c2 = bh[(g*4+2)*128 + s], c3 = bh[(g*4+3)*128 + s];
        *(float4*)(xr_t + s*4) = make_float4(c0,c1,c2,c3);
    }
    __syncthreads();
    float bias = b[s];
    v2f ac01 = {bias,bias}, ac23 = {bias,bias};
    for (int k=0;k<128;k++){
        float wv = W[k*128 + s];
        v2f ws = {wv, wv};
        const v2f* xp = (const v2f*)(xr_t + k*4);
        pkfma(ac01, xp[0], ws);
        pkfma(ac23, xp[1], ws);
    }
    float accj[4] = {ac01.x, ac01.y, ac23.x, ac23.y};
    float cv = cvec[s];
    int h = s >> 4;                                // head (HD=16)
    #pragma unroll
    for (int j=0;j<4;j++){
        float p = ftanh(accj[j])*cv;
        #pragma unroll
        for (int off=8; off>0; off>>=1) p += __shfl_down(p, off);
        if ((s & 15) == 0) simw[j][h] = p;
    }
    __syncthreads();
    if (s < 8){
        float v0=simw[0][s], v1=simw[1][s], v2=simw[2][s], v3=simw[3][s];
        float mx = fmaxf(fmaxf(v0,v1), fmaxf(v2,v3));
        float e0=__expf(v0-mx), e1=__expf(v1-mx), e2=__expf(v2-mx), e3=__expf(v3-mx);
        float den = e0+e1+e2+e3;
        wgt[0][s]=e0/den; wgt[1][s]=e1/den; wgt[2][s]=e2/den; wgt[3][s]=e3/den;
    }
    __syncthreads();
    float4 xs4 = *(const float4*)(xr_t + s*4);
    float o = xs4.x*wgt[0][h] + xs4.y*wgt[1][h] + xs4.z*wgt[2][h] + xs4.w*wgt[3][h];
    mnode[s] = o;
    __syncthreads();
    v2f afA = {b_f[s], 0.f}, afB = {0.f, 0.f};
    v2f abA = {b_b[s], 0.f}, abB = {0.f, 0.f};
    const v2f* wfp = (const v2f*)(wi_f + (size_t)s*128);
    const v2f* wbp = (const v2f*)(wi_b + (size_t)s*128);
    const v2f* bp  = (const v2f*)mnode;
    for (int k2=0;k2<64;k2+=2){
        v2f x01 = bp[k2], x23 = bp[k2+1];
        pkfma(afA, wfp[k2], x01); pkfma(afB, wfp[k2+1], x23);
        pkfma(abA, wbp[k2], x01); pkfma(abB, wbp[k2+1], x23);
    }
    gf [g*128 + s] = (afA.x + afA.y) + (afB.x + afB.y);
    gbo[g*128 + s] = (abA.x + abA.y) + (abB.x + abB.y);
}

// ---------------- LSTM recurrence, H=64 T=256: frozen r14 form ---------------------
// Wave w owns h[16w..16w+16); lane = gate*16+offset; i/f/g/o via 4 __shfl;
// hs double-buffered on parity; one barrier/step. Latency-bound floor ~116us.
__global__ __launch_bounds__(256)
__attribute__((amdgpu_waves_per_eu(1, 1)))
void k_lstm_rec64(
        const float* __restrict__ gin_f, const float* __restrict__ wh_f,
        const float* __restrict__ gin_b, const float* __restrict__ wh_b,
        float* __restrict__ hid /* [T][128] */){
    const int H = 64, T = 256;
    int dir = blockIdx.x;
    const float* gin = dir ? gin_b : gin_f;
    const float* wh  = dir ? wh_b  : wh_f;
    int gi = threadIdx.x;
    int w  = gi >> 6;                      // wave
    int j  = gi & 63;                      // lane
    int o  = j & 15;                       // h offset within wave's range
    int g  = j >> 4;                       // gate (0=i,1=f,2=g,3=o)
    int l  = (w << 4) + o;                 // h index
    int row = (g << 6) + l;                // gate row in [0,256)
    const v2f* wp = (const v2f*)(wh + (size_t)row*H);
    v2f w00=wp[0], w01=wp[1], w02=wp[2], w03=wp[3], w04=wp[4], w05=wp[5], w06=wp[6], w07=wp[7],
        w08=wp[8], w09=wp[9], w10=wp[10],w11=wp[11],w12=wp[12],w13=wp[13],w14=wp[14],w15=wp[15],
        w16=wp[16],w17=wp[17],w18=wp[18],w19=wp[19],w20=wp[20],w21=wp[21],w22=wp[22],w23=wp[23],
        w24=wp[24],w25=wp[25],w26=wp[26],w27=wp[27],w28=wp[28],w29=wp[29],w30=wp[30],w31=wp[31];
    __shared__ __align__(16) float hsb[2][H];
    float c = 0.f;
    if (gi < H) hsb[0][gi] = 0.f;
    __syncthreads();
    const float* gp = gin + row;
    float gcur = gp[(dir ? (T-1) : 0)*256];
    for (int step=0; step<T; step++){
        int t = dir ? (T-1-step) : step;
        float gnext = 0.f;
        if (step+1 < T) gnext = gp[(dir ? (T-2-step) : (step+1))*256];
        const float4* hv = (const float4*)hsb[step & 1];   // uniform addr, b128
        float4 H0=hv[0],  H1=hv[1],  H2=hv[2],  H3=hv[3];
        float4 H4=hv[4],  H5=hv[5],  H6=hv[6],  H7=hv[7];
        float4 H8=hv[8],  H9=hv[9],  H10=hv[10],H11=hv[11];
        float4 H12=hv[12],H13=hv[13],H14=hv[14],H15=hv[15];
        v2f A0={gcur,0.f}, A1={0.f,0.f}, A2={0.f,0.f}, A3={0.f,0.f};
        pkfma(A0,w00,LO2(H0));  pkfma(A1,w01,HI2(H0));  pkfma(A2,w02,LO2(H1));  pkfma(A3,w03,HI2(H1));
        pkfma(A0,w04,LO2(H2));  pkfma(A1,w05,HI2(H2));  pkfma(A2,w06,LO2(H3));  pkfma(A3,w07,HI2(H3));
        pkfma(A0,w08,LO2(H4));  pkfma(A1,w09,HI2(H4));  pkfma(A2,w10,LO2(H5));  pkfma(A3,w11,HI2(H5));
        pkfma(A0,w12,LO2(H6));  pkfma(A1,w13,HI2(H6));  pkfma(A2,w14,LO2(H7));  pkfma(A3,w15,HI2(H7));
        pkfma(A0,w16,LO2(H8));  pkfma(A1,w17,HI2(H8));  pkfma(A2,w18,LO2(H9));  pkfma(A3,w19,HI2(H9));
        pkfma(A0,w20,LO2(H10)); pkfma(A1,w21,HI2(H10)); pkfma(A2,w22,LO2(H11)); pkfma(A3,w23,HI2(H11));
        pkfma(A0,w24,LO2(H12)); pkfma(A1,w25,HI2(H12)); pkfma(A2,w26,LO2(H13)); pkfma(A3,w27,HI2(H13));
        pkfma(A0,w28,LO2(H14)); pkfma(A1,w29,HI2(H14)); pkfma(A2,w30,LO2(H15)); pkfma(A3,w31,HI2(H15));
        float val = ((A0.x+A0.y) + (A1.x+A1.y)) + ((A2.x+A2.y) + (A3.x+A3.y));
        // intra-wave gate exchange: i/f/g/o for h=l live in lanes o, o+16, o+32, o+48
        float i_ = __shfl(val, o);
        float f_ = __shfl(val, o + 16);
        float g_ = __shfl(val, o + 32);
        float o_ = __shfl(val, o + 48);
        c = fsig(f_)*c + fsig(i_)*ftanh(g_);   // 4 lanes per l: identical update
        float hn = fsig(o_)*ftanh(c);
        if (g == 0){
            hsb[(step+1)&1][l] = hn;           // partitioned write, other buffer
            hid[t*2*H + dir*H + l] = hn;
        }
        __syncthreads();                       // the ONLY barrier per step
        gcur = gnext;
    }
}

// ---------------- LSTM recurrence, H=32 T=64: single wave, NO barrier --------------
__global__ __launch_bounds__(64)
__attribute__((amdgpu_waves_per_eu(1, 1)))
void k_lstm_rec32(
        const float* __restrict__ gin_f, const float* __restrict__ wh_f,
        const float* __restrict__ gin_b, const float* __restrict__ wh_b,
        float* __restrict__ hid /* [T][64] */){
    const int H = 32, T = 64;
    int dir = blockIdx.x;
    const float* gin = dir ? gin_b : gin_f;
    const float* wh  = dir ? wh_b  : wh_f;
    int gi = threadIdx.x;                  // 0..63
    v2f wA[16], wB[16];
    {
        const v2f* rA = (const v2f*)(wh + (size_t)(     gi)*H);   // rows 0..63:  i|f
        const v2f* rB = (const v2f*)(wh + (size_t)(64 + gi)*H);   // rows 64..127: g|o
        #pragma unroll
        for (int k=0;k<16;k++){ wA[k]=rA[k]; wB[k]=rB[k]; }
    }
    __shared__ __align__(16) float hs[H];
    float c = 0.f;
    if (gi < H) hs[gi] = 0.f;
    __syncthreads();
    const float* gp = gin + gi;
    int ts0 = dir ? (T-1) : 0, ts1 = dir ? (T-2) : 1;
    float g0 = gp[ts0*128], g1 = gp[ts0*128 + 64];
    float n0 = gp[ts1*128], n1 = gp[ts1*128 + 64];
    bool lo = (gi < H);
    for (int step=0; step<T; step++){
        int t = dir ? (T-1-step) : step;
        float p0=0.f, p1=0.f;
        if (step+2 < T){
            int tp = dir ? (T-3-step) : (step+2);
            p0 = gp[tp*128]; p1 = gp[tp*128 + 64];
        }
        v2f aA = {g0, 0.f}, aB = {g1, 0.f};
        const float4* hv = (const float4*)hs;      // uniform addr, b128 reads
        #pragma unroll
        for (int k=0;k<8;k++){
            float4 h4 = hv[k];
            pkfma(aA, wA[2*k],   LO2(h4));
            pkfma(aB, wB[2*k],   LO2(h4));
            pkfma(aA, wA[2*k+1], HI2(h4));
            pkfma(aB, wB[2*k+1], HI2(h4));
        }
        float sA = aA.x + aA.y;            // lane<32: i ; lane>=32: f
        float sB = aB.x + aB.y;            // lane<32: g ; lane>=32: o
        float pA = __shfl(sA, gi ^ 32);
        float pB = __shfl(sB, gi ^ 32);
        float i_ = lo ? sA : pA;
        float f_ = lo ? pA : sA;
        float g_ = lo ? sB : pB;
        float o_ = lo ? pB : sB;
        c = fsig(f_)*c + fsig(i_)*ftanh(g_);
        float hn = fsig(o_)*ftanh(c);
        if (lo){
            hid[t*2*H + dir*H + gi] = hn;
            hs[gi] = hn;                   // same wave: in-order LDS, no barrier
        }
        g0 = n0; g1 = n1; n0 = p0; n1 = p1;
    }
}

// ---------------- si=0: rebuild nh in place = [beat_span | meas_span | nh_sec] -----
__global__ void k_spans(float* __restrict__ nh, const float* __restrict__ bh,
                        const float* __restrict__ mh,
                        const int* __restrict__ bn, const int* __restrict__ mn){
    int n = blockIdx.x, s = threadIdx.x;           // 320 threads
    float v;
    if (s < 128)      v = bh[bn[n]*128 + s];
    else if (s < 192) v = mh[mn[n]*64 + (s-128)];
    else              v = nh[n*SS + s];            // own-thread read-then-write: safe
    nh[n*SS + s] = v;
}

// ---------------- si=1: spans + final output fused ---------------------------------
__global__ void k_spans_out(const float* __restrict__ bh, const float* __restrict__ mh,
                            const float* __restrict__ nh, const float* __restrict__ nh2,
                            const int* __restrict__ bn, const int* __restrict__ mn,
                            float* __restrict__ out){
    int n = blockIdx.x, s = threadIdx.x;           // 448 threads
    float v;
    if (s < 128)      v = bh[bn[n]*128 + s];
    else if (s < 192) v = mh[mn[n]*64 + (s-128)];
    else if (s < 320) v = nh[n*SS + s];
    else              v = nh2[n*SS + 192 + (s-320)];
    out[n*448 + s] = v;
}

// ===========================================================================
extern "C" void kernel_launch(void* const* d_in, const int* in_sizes, int n_in,
                              void* d_out, int out_size, void* d_ws, size_t ws_size,
                              hipStream_t stream) {
    const float* nodes    = (const float*)d_in[0];
    const float* adj      = (const float*)d_in[1];
    const int*   bn       = (const int*)  d_in[2];
    const int*   mn       = (const int*)  d_in[3];
    const float* fc_w     = (const float*)d_in[6];
    const float* fc_b     = (const float*)d_in[7];
    const float* g_wz[2]  = {(const float*)d_in[8],  (const float*)d_in[17]};
    const float* g_wr[2]  = {(const float*)d_in[9],  (const float*)d_in[18]};
    const float* g_wh[2]  = {(const float*)d_in[10], (const float*)d_in[19]};
    const float* g_uz[2]  = {(const float*)d_in[11], (const float*)d_in[20]};
    const float* g_ur[2]  = {(const float*)d_in[12], (const float*)d_in[21]};
    const float* g_uh[2]  = {(const float*)d_in[13], (const float*)d_in[22]};
    const float* g_bz[2]  = {(const float*)d_in[14], (const float*)d_in[23]};
    const float* g_br[2]  = {(const float*)d_in[15], (const float*)d_in[24]};
    const float* g_bh[2]  = {(const float*)d_in[16], (const float*)d_in[25]};
    const float* gb_w     = (const float*)d_in[26];
    const float* gb_b     = (const float*)d_in[27];
    const float* batt_w   = (const float*)d_in[28];
    const float* batt_b   = (const float*)d_in[29];
    const float* batt_c   = (const float*)d_in[30];
    const float* matt_w   = (const float*)d_in[31];
    const float* matt_b   = (const float*)d_in[32];
    const float* matt_c   = (const float*)d_in[33];
    const float* bwi_f    = (const float*)d_in[34];
    const float* bwh_f    = (const float*)d_in[35];
    const float* bb_f     = (const float*)d_in[36];
    const float* bwi_b    = (const float*)d_in[37];
    const float* bwh_b    = (const float*)d_in[38];
    const float* bb_b     = (const float*)d_in[39];
    const float* mwi_f    = (const float*)d_in[40];
    const float* mwh_f    = (const float*)d_in[41];
    const float* mb_f     = (const float*)d_in[42];
    const float* mwi_b    = (const float*)d_in[43];
    const float* mwh_b    = (const float*)d_in[44];
    const float* mb_b     = (const float*)d_in[45];
    float* out = (float*)d_out;

    // --- workspace layout (floats; ~27.7 MB, under the 31.2MB proven in r0) ---
    float* W_   = (float*)d_ws;
    float* nh   = W_;                       // 1024*320
    float* nh2  = nh   + 327680;            // 1024*320
    float* act  = nh2  + 327680;            // 10*1024*320
    float* part = act  + 3276800;           // 10*1024*384 (slices 0-4 dyn, 5-9 static)
    float* bgf  = part + 3932160;           // 256*256
    float* bgb  = bgf  + 65536;             // 256*256
    float* beat_hidden = bgb + 65536;       // 256*128
    float* mgf  = beat_hidden + 32768;      // 64*128
    float* mgb  = mgf  + 8192;              // 64*128
    float* meas_hidden = mgb + 8192;        // 64*64
    int*   cnt  = (int*)(meas_hidden + 4096);  // 10*1024
    int*   idx  = cnt + 10240;                  // 10*1024*64

    float* part_s = part + 5*NN*384;        // static slices base

    hipMemsetAsync(cnt, 0, EE*NN*sizeof(int), stream);
    k_csr_build<<<EE*NN, 256, 0, stream>>>(adj, cnt, idx);
    k_note_fc<<<NN, 128, 0, stream>>>(nodes, fc_w, fc_b, nh);

    for (int si = 0; si < 2; ++si){
        for (int half = 0; half < 2; ++half){
            float* x = half ? nh2 : nh;
            int w = half;                     // weight set index
            bool zerostatic = (si == 0 && half == 0);   // nh[:, :192] == 0
            if (half == 1)                    // nb = relu(nh @ gb_w) -> nh2
                k_gb<<<NN/4, SS, 0, stream>>>(nh, gb_w, gb_b, nh2);
            const float* addv = zerostatic ? nullptr : part_s;
            for (int it = 0; it < 2; ++it){
                if (!zerostatic && it == 0){
                    // one full 320-col gather feeds static AND dyn GEMMs
                    k_gather_full<<<EE*NN/4, 320, 0, stream>>>(x, cnt, idx, act);
                    k_gate_gemm_rng<0,192><<<dim3(32,3,5), 256, 0, stream>>>(
                            act, g_wz[w], g_wr[w], g_wh[w], part_s, nullptr);
                } else {
                    k_gather_dyn<<<EE*NN/8, 256, 0, stream>>>(x, cnt, idx, act);
                }
                k_gate_gemm_rng<192,320><<<dim3(32,3,5), 256, 0, stream>>>(
                        act, g_wz[w], g_wr[w], g_wh[w], part, addv);
                k_gru<<<NN/2, 128, 0, stream>>>(x, part,
                        g_uz[w], g_ur[w], g_uh[w], g_bz[w], g_br[w], g_bh[w]);
            }
        }
        k_batt_fused<<<NB, 256, 0, stream>>>(nh, nh2, batt_w, batt_b, batt_c,
                                             bwi_f, bb_f, bwi_b, bb_b, bgf, bgb);
        k_lstm_rec64<<<2, 256, 0, stream>>>(bgf, bwh_f, bgb, bwh_b, beat_hidden);
        k_matt_fused<<<NM, 128, 0, stream>>>(beat_hidden, matt_w, matt_b, matt_c,
                                             mwi_f, mb_f, mwi_b, mb_b, mgf, mgb);
        k_lstm_rec32<<<2, 64, 0, stream>>>(mgf, mwh_f, mgb, mwh_b, meas_hidden);
        if (si == 0)
            k_spans<<<NN, SS, 0, stream>>>(nh, beat_hidden, meas_hidden, bn, mn);
        else
            k_spans_out<<<NN, 448, 0, stream>>>(beat_hidden, meas_hidden, nh, nh2,
                                                bn, mn, out);
    }
}

// Round 12
// 999.286 us; speedup vs baseline: 1.2898x; 1.0290x over previous
//
#include <hip/hip_runtime.h>
#include <math.h>

// ---------------------------------------------------------------------------
// IsgnBeatMeasEncoder — round 16: gru k-split + merged it=0 GEMM launch.
// Round-15 post-mortem: static-fold + A-float4 = -13us (threshold fired):
// micro-modeling near-exhausted. Not at roofline (VALU 0.2%, HBM 0.05% —
// latency/Amdahl regime). Remaining sound levers:
//   - k_gru: was 128thr/2 waves -> 1 wave/SIMD with three serial 128-iter
//     load-FMA loops. Split k across two wave-aligned halves (256 thr):
//     loops halve to 64 iters, LDS-reduce partials, occupancy 2x. m-loads
//     overlap half-1's dz/dr partials.
//   - it=0 static+dyn gemms are independent (both read completed full-act):
//     ONE launch, grid (32,6,5)=960 blocks (-3 dispatches, better occupancy).
//     gru regains nsp: 10 at it=0 (slices 0-9 contiguous), 5 at it=1 (addv
//     fold as r15).
//   - all else frozen (rec64 @116us latency floor, VGPR-132 canary).
// Falsification: total >=1020 -> practical plateau; declare next round.
// ---------------------------------------------------------------------------

#define NN    1024
#define EE    10
#define INDIM 78
#define SS    320
#define SECD  128
#define NB    256
#define NM    64
#define CAP   64     // max nonzeros per adjacency column (mean ~10.2)

typedef float v2f __attribute__((ext_vector_type(2)));

__device__ __forceinline__ void pkfma(v2f& a, v2f x, v2f y){
    asm("v_pk_fma_f32 %0, %1, %2, %0" : "+v"(a) : "v"(x), "v"(y));
}
// a.lo += x.lo*b.lo ; a.hi += x.hi*b.lo   (broadcast LOW half of b)
__device__ __forceinline__ void pkfma_blo(v2f& a, v2f x, v2f b){
    asm("v_pk_fma_f32 %0, %1, %2, %0 op_sel:[0,0,0] op_sel_hi:[1,0,1]"
        : "+v"(a) : "v"(x), "v"(b));
}
// a.lo += x.lo*b.hi ; a.hi += x.hi*b.hi   (broadcast HIGH half of b)
__device__ __forceinline__ void pkfma_bhi(v2f& a, v2f x, v2f b){
    asm("v_pk_fma_f32 %0, %1, %2, %0 op_sel:[0,1,0] op_sel_hi:[1,1,1]"
        : "+v"(a) : "v"(x), "v"(b));
}

#define LO2(F) ((v2f){F.x, F.y})
#define HI2(F) ((v2f){F.z, F.w})

__device__ __forceinline__ float fsig(float x){
    return __builtin_amdgcn_rcpf(1.f + __expf(-x));
}
__device__ __forceinline__ float ftanh(float x){
    // tanh(x) = 1 - 2/(exp(2x)+1); exp overflow -> inf -> rcp -> 0 -> 1 (correct)
    return 1.f - 2.f*__builtin_amdgcn_rcpf(1.f + __expf(2.f*x));
}

// ---------------- note_fc: x0 = tanh(nodes @ W + b); nh = [0(192) | x0] ------------
__global__ void k_note_fc(const float* __restrict__ nodes, const float* __restrict__ W,
                          const float* __restrict__ b, float* __restrict__ nh){
    int n = blockIdx.x, s = threadIdx.x;           // 128 threads
    __shared__ float xrow[INDIM];
    if (s < INDIM) xrow[s] = nodes[n*INDIM + s];
    __syncthreads();
    float acc = b[s];
    for (int k = 0; k < INDIM; ++k) acc += xrow[k]*W[k*128 + s];
    nh[n*SS + 192 + s] = ftanh(acc);
    nh[n*SS + s] = 0.f;
    if (s < 64) nh[n*SS + 128 + s] = 0.f;
}

// ---------------- CSR build: float4 scan of each adj row ---------------------------
__global__ void k_csr_build(const float* __restrict__ adj, int* __restrict__ cnt,
                            int* __restrict__ idx){
    int em = blockIdx.x;                   // e*NN + m  (row of adj[e])
    int e = em / NN, m = em % NN;
    const float4* row4 = (const float4*)(adj + (size_t)em * NN);
    int q = threadIdx.x;                   // 256 threads, 256 float4 = 1024 cols
    float4 v = row4[q];
    int n0 = q*4;
    if (v.x != 0.f){ int p = atomicAdd(&cnt[e*NN + n0+0], 1); if (p < CAP) idx[((size_t)e*NN + n0+0)*CAP + p] = m; }
    if (v.y != 0.f){ int p = atomicAdd(&cnt[e*NN + n0+1], 1); if (p < CAP) idx[((size_t)e*NN + n0+1)*CAP + p] = m; }
    if (v.z != 0.f){ int p = atomicAdd(&cnt[e*NN + n0+2], 1); if (p < CAP) idx[((size_t)e*NN + n0+2)*CAP + p] = m; }
    if (v.w != 0.f){ int p = atomicAdd(&cnt[e*NN + n0+3], 1); if (p < CAP) idx[((size_t)e*NN + n0+3)*CAP + p] = m; }
}

// ---------------- full gather (320 cols), float4: 80 quads/en, 4 en/block ----------
__global__ void k_gather_full(const float* __restrict__ x, const int* __restrict__ cnt,
                              const int* __restrict__ idx, float* __restrict__ act){
    int en = blockIdx.x*4 + threadIdx.x/80;        // 320 threads
    int q  = threadIdx.x % 80;
    int c = cnt[en]; if (c > CAP) c = CAP;
    const int* lst = idx + (size_t)en*CAP;
    float4 acc = {0.f,0.f,0.f,0.f};
    const float* xb = x + q*4;
    for (int j = 0; j < c; ++j){
        float4 v = *(const float4*)(xb + (size_t)lst[j]*SS);
        acc.x += v.x; acc.y += v.y; acc.z += v.z; acc.w += v.w;
    }
    *(float4*)(act + (size_t)en*SS + q*4) = acc;
}

// ---------------- dyn gather (cols 192..320), float4: 32 quads/en, 8 en/block ------
__global__ void k_gather_dyn(const float* __restrict__ x, const int* __restrict__ cnt,
                             const int* __restrict__ idx, float* __restrict__ act){
    int en = blockIdx.x*8 + (threadIdx.x >> 5);    // 256 threads
    int q  = threadIdx.x & 31;
    int c = cnt[en]; if (c > CAP) c = CAP;
    const int* lst = idx + (size_t)en*CAP;
    float4 acc = {0.f,0.f,0.f,0.f};
    const float* xb = x + 192 + q*4;
    for (int j = 0; j < c; ++j){
        float4 v = *(const float4*)(xb + (size_t)lst[j]*SS);
        acc.x += v.x; acc.y += v.y; acc.z += v.z; acc.w += v.w;
    }
    *(float4*)(act + (size_t)en*SS + 192 + q*4) = acc;
}

// ---------------- gate GEMM core (runtime K range) ---------------------------------
__device__ __forceinline__ void gemm_body(const float* __restrict__ act,
        const float* __restrict__ W, float* __restrict__ outp,
        const float* __restrict__ addv, int K0, int K1, int nt, int z,
        float* A, float* B){
    int tid = threadIdx.x;
    int tx = tid & 31;             // cols tx*4 .. +3
    int ty = tid >> 5;             // rows ty*4 .. +3
    v2f acc[2][4];
    #pragma unroll
    for (int i=0;i<2;i++)
        #pragma unroll
        for (int j=0;j<4;j++) acc[i][j] = (v2f){0.f,0.f};
    for (int eh = 0; eh < 2; ++eh){
        int e = z*2 + eh;
        const float* Ae = act + (size_t)e*NN*SS + (size_t)nt*32*SS;
        const float* We = W   + (size_t)e*SS*SECD;
        for (int kc = K0; kc < K1; kc += 32){
            {                                      // A: 32 rows x 32 k = 256 float4
                int r  = tid >> 3;
                int k4 = (tid & 7) << 2;
                float4 v = *(const float4*)(Ae + r*SS + kc + k4);
                A[(k4+0)*36 + r] = v.x; A[(k4+1)*36 + r] = v.y;
                A[(k4+2)*36 + r] = v.z; A[(k4+3)*36 + r] = v.w;
            }
            #pragma unroll
            for (int i=0;i<4;i++){                 // B: 32 k x 128 cols
                int lin4 = tid + i*256;            // 1024 float4
                int kk = lin4 >> 5;
                int c4 = (lin4 & 31) << 2;
                *((float4*)(B + kk*132 + c4)) = *(const float4*)(We + (kc+kk)*SECD + c4);
            }
            __syncthreads();
            #pragma unroll 8
            for (int k=0;k<32;k++){
                float4 a4 = *(const float4*)(A + k*36 + ty*4);   // wave-uniform b128
                v2f a01 = LO2(a4), a23 = HI2(a4);
                float4 b = *(const float4*)(B + k*132 + tx*4);   // r8-proven pattern
                v2f b01 = {b.x, b.y}, b23 = {b.z, b.w};
                pkfma_blo(acc[0][0], a01, b01); pkfma_bhi(acc[0][1], a01, b01);
                pkfma_blo(acc[0][2], a01, b23); pkfma_bhi(acc[0][3], a01, b23);
                pkfma_blo(acc[1][0], a23, b01); pkfma_bhi(acc[1][1], a23, b01);
                pkfma_blo(acc[1][2], a23, b23); pkfma_bhi(acc[1][3], a23, b23);
            }
            __syncthreads();
        }
    }
    size_t base = ((size_t)z*NN + (size_t)nt*32)*384;   // +g*SECD folded by caller
    float* P = outp + base;
    int r0 = ty*4;
    float4 o0 = make_float4(acc[0][0].x, acc[0][1].x, acc[0][2].x, acc[0][3].x);
    float4 o1 = make_float4(acc[0][0].y, acc[0][1].y, acc[0][2].y, acc[0][3].y);
    float4 o2 = make_float4(acc[1][0].x, acc[1][1].x, acc[1][2].x, acc[1][3].x);
    float4 o3 = make_float4(acc[1][0].y, acc[1][1].y, acc[1][2].y, acc[1][3].y);
    if (addv){
        const float* Q = addv + base;
        float4 q0 = *(const float4*)(Q + (size_t)(r0+0)*384 + tx*4);
        float4 q1 = *(const float4*)(Q + (size_t)(r0+1)*384 + tx*4);
        float4 q2 = *(const float4*)(Q + (size_t)(r0+2)*384 + tx*4);
        float4 q3 = *(const float4*)(Q + (size_t)(r0+3)*384 + tx*4);
        o0.x+=q0.x; o0.y+=q0.y; o0.z+=q0.z; o0.w+=q0.w;
        o1.x+=q1.x; o1.y+=q1.y; o1.z+=q1.z; o1.w+=q1.w;
        o2.x+=q2.x; o2.y+=q2.y; o2.z+=q2.z; o2.w+=q2.w;
        o3.x+=q3.x; o3.y+=q3.y; o3.z+=q3.z; o3.w+=q3.w;
    }
    *(float4*)(P + (size_t)(r0+0)*384 + tx*4) = o0;
    *(float4*)(P + (size_t)(r0+1)*384 + tx*4) = o1;
    *(float4*)(P + (size_t)(r0+2)*384 + tx*4) = o2;
    *(float4*)(P + (size_t)(r0+3)*384 + tx*4) = o3;
}

// dyn-only (with optional addv fold): grid (32,3,5)
__global__ __launch_bounds__(256) void k_gate_gemm_dyn(const float* __restrict__ act,
        const float* __restrict__ wz, const float* __restrict__ wr,
        const float* __restrict__ wh, float* __restrict__ part,
        const float* __restrict__ addv){
    __shared__ float A[32*36];
    __shared__ float B[32*132];
    int g = blockIdx.y;
    const float* W = (g==0) ? wz : ((g==1) ? wr : wh);
    const float* av = addv ? (addv + g*SECD) : nullptr;
    gemm_body(act, W, part + g*SECD, av, 192, 320, blockIdx.x, blockIdx.z, A, B);
}

// merged it=0: static (y<3 -> part_s, K 0..192) + dyn (y>=3 -> part, K 192..320),
// grid (32,6,5), no addv (gru reads 10 slices this iteration).
__global__ __launch_bounds__(256) void k_gate_gemm_both(const float* __restrict__ act,
        const float* __restrict__ wz, const float* __restrict__ wr,
        const float* __restrict__ wh, float* __restrict__ part,
        float* __restrict__ part_s){
    __shared__ float A[32*36];
    __shared__ float B[32*132];
    int y = blockIdx.y;            // 0..5
    int g = (y >= 3) ? (y - 3) : y;
    const float* W = (g==0) ? wz : ((g==1) ? wr : wh);
    if (y >= 3)
        gemm_body(act, W, part   + g*SECD, nullptr, 192, 320, blockIdx.x, blockIdx.z, A, B);
    else
        gemm_body(act, W, part_s + g*SECD, nullptr,   0, 192, blockIdx.x, blockIdx.z, A, B);
}

// ---------------- GRU update v2: 256 thr, 2 notes, k split across wave-halves ------
// h = tid>>7 (wave-aligned): half 0 handles k 0..63 + m-slice loads + gates;
// half 1 handles k 64..127. Partials reduced in LDS. Serial loops halved,
// occupancy 2 blocks/CU x 4 waves = 2 waves/SIMD (was 1).
__global__ __launch_bounds__(256) void k_gru(float* __restrict__ x,
        const float* __restrict__ part, int nsp,
        const float* __restrict__ uz, const float* __restrict__ ur, const float* __restrict__ uh,
        const float* __restrict__ bz, const float* __restrict__ br, const float* __restrict__ bh){
    int n0 = blockIdx.x*2;
    int tid = threadIdx.x;
    int s = tid & 127;                 // col
    int h = tid >> 7;                  // k-half (wave-uniform)
    int k0 = h*64;
    __shared__ float xs[2][SECD], rx[2][SECD];
    __shared__ float red[2][2][2][SECD];   // [dz|dr][half][note][col] (reused for dh)
    if (h == 0){
        xs[0][s] = x[(n0+0)*SS + 192 + s];
        xs[1][s] = x[(n0+1)*SS + 192 + s];
    }
    __syncthreads();
    float mz[2]={0,0}, mr[2]={0,0}, mh[2]={0,0};
    if (h == 0){
        for (int sp=0; sp<nsp; sp++){
            const float* Pp = part + ((size_t)sp*NN + n0)*384;
            #pragma unroll
            for (int j=0;j<2;j++){
                mz[j] += Pp[j*384 + s];
                mr[j] += Pp[j*384 + 128 + s];
                mh[j] += Pp[j*384 + 256 + s];
            }
        }
    }
    float dz[2]={0,0}, dr[2]={0,0};
    #pragma unroll 8
    for (int k=k0;k<k0+64;k++){
        float wz_ = uz[k*SECD + s], wr_ = ur[k*SECD + s];
        #pragma unroll
        for (int j=0;j<2;j++){ float xv = xs[j][k]; dz[j] += xv*wz_; dr[j] += xv*wr_; }
    }
    red[0][h][0][s]=dz[0]; red[0][h][1][s]=dz[1];
    red[1][h][0][s]=dr[0]; red[1][h][1][s]=dr[1];
    __syncthreads();
    float zz[2], rr[2];
    if (h == 0){
        #pragma unroll
        for (int j=0;j<2;j++){
            float dzf = red[0][0][j][s] + red[0][1][j][s];
            float drf = red[1][0][j][s] + red[1][1][j][s];
            zz[j] = fsig(mz[j] + dzf + bz[s]);
            rr[j] = fsig(mr[j] + drf + br[s]);
            rx[j][s] = rr[j]*xs[j][s];
        }
    }
    __syncthreads();
    float dh[2]={0,0};
    #pragma unroll 8
    for (int k=k0;k<k0+64;k++){
        float wh_ = uh[k*SECD + s];
        #pragma unroll
        for (int j=0;j<2;j++) dh[j] += rx[j][k]*wh_;
    }
    red[0][h][0][s]=dh[0]; red[0][h][1][s]=dh[1];
    __syncthreads();
    if (h == 0){
        #pragma unroll
        for (int j=0;j<2;j++){
            float dhf = red[0][0][j][s] + red[0][1][j][s];
            float hc = ftanh(mh[j] + dhf + bh[s]);
            x[(n0+j)*SS + 192 + s] = (1.f - zz[j])*xs[j][s] + rr[j]*hc;
        }
    }
}

// ---------------- nb = relu(nh @ gb_w + gb_b) -> nh2; 4 notes/block, 256 blocks ----
__global__ void k_gb(const float* __restrict__ nh, const float* __restrict__ W,
                     const float* __restrict__ b, float* __restrict__ nb){
    int n0 = blockIdx.x*4, s = threadIdx.x;        // 320 threads
    __shared__ float xr_t[SS*4];                   // [k][j] — j-pairs adjacent
    {
        float v0 = nh[(n0+0)*SS + s], v1 = nh[(n0+1)*SS + s];
        float v2 = nh[(n0+2)*SS + s], v3 = nh[(n0+3)*SS + s];
        *(float4*)(xr_t + s*4) = make_float4(v0,v1,v2,v3);
    }
    __syncthreads();
    float bv = b[s];
    v2f a01={bv,bv}, a23={bv,bv};
    for (int k=0;k<SS;k++){
        float wv = W[k*SS + s];
        v2f ws = {wv, wv};
        const v2f* xp = (const v2f*)(xr_t + k*4);  // uniform addr -> broadcast
        pkfma(a01, xp[0], ws);
        pkfma(a23, xp[1], ws);
    }
    nb[(n0+0)*SS + s] = fmaxf(a01.x, 0.f);
    nb[(n0+1)*SS + s] = fmaxf(a01.y, 0.f);
    nb[(n0+2)*SS + s] = fmaxf(a23.x, 0.f);
    nb[(n0+3)*SS + s] = fmaxf(a23.y, 0.f);
}

// ---------------- FUSED beat attention + lstm_pre (transposed tile + pkfma) --------
__global__ __launch_bounds__(256) void k_batt_fused(
        const float* __restrict__ nh, const float* __restrict__ nh2,
        const float* __restrict__ W, const float* __restrict__ b,
        const float* __restrict__ cvec,
        const float* __restrict__ wi_f, const float* __restrict__ b_f,
        const float* __restrict__ wi_b, const float* __restrict__ b_b,
        float* __restrict__ gf, float* __restrict__ gbo){
    int g = blockIdx.x, s = threadIdx.x;           // 256 threads
    __shared__ float xr_t[256*4];                  // [k][j]
    __shared__ float simw[4][8];
    __shared__ float wgt[4][8];
    __shared__ float bnode[256];
    {
        float c0,c1,c2,c3;
        if (s < 128){
            c0 = nh[(g*4+0)*SS + 192 + s]; c1 = nh[(g*4+1)*SS + 192 + s];
            c2 = nh[(g*4+2)*SS + 192 + s]; c3 = nh[(g*4+3)*SS + 192 + s];
        } else {
            c0 = nh2[(g*4+0)*SS + 64 + s]; c1 = nh2[(g*4+1)*SS + 64 + s];
            c2 = nh2[(g*4+2)*SS + 64 + s]; c3 = nh2[(g*4+3)*SS + 64 + s];
        }
        *(float4*)(xr_t + s*4) = make_float4(c0,c1,c2,c3);
    }
    __syncthreads();
    float bias = b[s];
    v2f ac01 = {bias,bias}, ac23 = {bias,bias};
    for (int k=0;k<256;k++){
        float wv = W[k*256 + s];
        v2f ws = {wv, wv};
        const v2f* xp = (const v2f*)(xr_t + k*4);
        pkfma(ac01, xp[0], ws);
        pkfma(ac23, xp[1], ws);
    }
    float accj[4] = {ac01.x, ac01.y, ac23.x, ac23.y};
    float cv = cvec[s];
    int h = s >> 5;                                // head (HD=32)
    #pragma unroll
    for (int j=0;j<4;j++){
        float p = ftanh(accj[j])*cv;
        #pragma unroll
        for (int off=16; off>0; off>>=1) p += __shfl_down(p, off);
        if ((s & 31) == 0) simw[j][h] = p;
    }
    __syncthreads();
    if (s < 8){
        float v0=simw[0][s], v1=simw[1][s], v2=simw[2][s], v3=simw[3][s];
        float mx = fmaxf(fmaxf(v0,v1), fmaxf(v2,v3));
        float e0=__expf(v0-mx), e1=__expf(v1-mx), e2=__expf(v2-mx), e3=__expf(v3-mx);
        float den = e0+e1+e2+e3;
        wgt[0][s]=e0/den; wgt[1][s]=e1/den; wgt[2][s]=e2/den; wgt[3][s]=e3/den;
    }
    __syncthreads();
    float4 xs4 = *(const float4*)(xr_t + s*4);
    float o = xs4.x*wgt[0][h] + xs4.y*wgt[1][h] + xs4.z*wgt[2][h] + xs4.w*wgt[3][h];
    bnode[s] = o;
    __syncthreads();
    // pre-GEMV, both directions: contiguous weight rows as v2f, elementwise pkfma
    v2f afA = {b_f[s], 0.f}, afB = {0.f, 0.f};
    v2f abA = {b_b[s], 0.f}, abB = {0.f, 0.f};
    const v2f* wfp = (const v2f*)(wi_f + (size_t)s*256);
    const v2f* wbp = (const v2f*)(wi_b + (size_t)s*256);
    const v2f* bp  = (const v2f*)bnode;
    for (int k2=0;k2<128;k2+=2){
        v2f x01 = bp[k2], x23 = bp[k2+1];
        pkfma(afA, wfp[k2], x01); pkfma(afB, wfp[k2+1], x23);
        pkfma(abA, wbp[k2], x01); pkfma(abB, wbp[k2+1], x23);
    }
    gf [g*256 + s] = (afA.x + afA.y) + (afB.x + afB.y);
    gbo[g*256 + s] = (abA.x + abA.y) + (abB.x + abB.y);
}

// ---------------- FUSED measure attention + lstm_pre -------------------------------
__global__ __launch_bounds__(128) void k_matt_fused(
        const float* __restrict__ bh,   // beat_hidden [256][128]
        const float* __restrict__ W, const float* __restrict__ b,
        const float* __restrict__ cvec,
        const float* __restrict__ wi_f, const float* __restrict__ b_f,
        const float* __restrict__ wi_b, const float* __restrict__ b_b,
        float* __restrict__ gf, float* __restrict__ gbo){
    int g = blockIdx.x, s = threadIdx.x;           // 128 threads
    __shared__ float xr_t[128*4];                  // [k][j]
    __shared__ float simw[4][8];
    __shared__ float wgt[4][8];
    __shared__ float mnode[128];
    {
        float c0 = bh[(g*4+0)*128 + s], c1 = bh[(g*4+1)*128 + s];
        float c2 = bh[(g*4+2)*128 + s], c3 = bh[(g*4+3)*128 + s];
        *(float4*)(xr_t + s*4) = make_float4(c0,c1,c2,c3);
    }
    __syncthreads();
    float bias = b[s];
    v2f ac01 = {bias,bias}, ac23 = {bias,bias};
    for (int k=0;k<128;k++){
        float wv = W[k*128 + s];
        v2f ws = {wv, wv};
        const v2f* xp = (const v2f*)(xr_t + k*4);
        pkfma(ac01, xp[0], ws);
        pkfma(ac23, xp[1], ws);
    }
    float accj[4] = {ac01.x, ac01.y, ac23.x, ac23.y};
    float cv = cvec[s];
    int h = s >> 4;                                // head (HD=16)
    #pragma unroll
    for (int j=0;j<4;j++){
        float p = ftanh(accj[j])*cv;
        #pragma unroll
        for (int off=8; off>0; off>>=1) p += __shfl_down(p, off);
        if ((s & 15) == 0) simw[j][h] = p;
    }
    __syncthreads();
    if (s < 8){
        float v0=simw[0][s], v1=simw[1][s], v2=simw[2][s], v3=simw[3][s];
        float mx = fmaxf(fmaxf(v0,v1), fmaxf(v2,v3));
        float e0=__expf(v0-mx), e1=__expf(v1-mx), e2=__expf(v2-mx), e3=__expf(v3-mx);
        float den = e0+e1+e2+e3;
        wgt[0][s]=e0/den; wgt[1][s]=e1/den; wgt[2][s]=e2/den; wgt[3][s]=e3/den;
    }
    __syncthreads();
    float4 xs4 = *(const float4*)(xr_t + s*4);
    float o = xs4.x*wgt[0][h] + xs4.y*wgt[1][h] + xs4.z*wgt[2][h] + xs4.w*wgt[3][h];
    mnode[s] = o;
    __syncthreads();
    v2f afA = {b_f[s], 0.f}, afB = {0.f, 0.f};
    v2f abA = {b_b[s], 0.f}, abB = {0.f, 0.f};
    const v2f* wfp = (const v2f*)(wi_f + (size_t)s*128);
    const v2f* wbp = (const v2f*)(wi_b + (size_t)s*128);
    const v2f* bp  = (const v2f*)mnode;
    for (int k2=0;k2<64;k2+=2){
        v2f x01 = bp[k2], x23 = bp[k2+1];
        pkfma(afA, wfp[k2], x01); pkfma(afB, wfp[k2+1], x23);
        pkfma(abA, wbp[k2], x01); pkfma(abB, wbp[k2+1], x23);
    }
    gf [g*128 + s] = (afA.x + afA.y) + (afB.x + afB.y);
    gbo[g*128 + s] = (abA.x + abA.y) + (abB.x + abB.y);
}

// ---------------- LSTM recurrence, H=64 T=256: frozen r14 form ---------------------
__global__ __launch_bounds__(256)
__attribute__((amdgpu_waves_per_eu(1, 1)))
void k_lstm_rec64(
        const float* __restrict__ gin_f, const float* __restrict__ wh_f,
        const float* __restrict__ gin_b, const float* __restrict__ wh_b,
        float* __restrict__ hid /* [T][128] */){
    const int H = 64, T = 256;
    int dir = blockIdx.x;
    const float* gin = dir ? gin_b : gin_f;
    const float* wh  = dir ? wh_b  : wh_f;
    int gi = threadIdx.x;
    int w  = gi >> 6;                      // wave
    int j  = gi & 63;                      // lane
    int o  = j & 15;                       // h offset within wave's range
    int g  = j >> 4;                       // gate (0=i,1=f,2=g,3=o)
    int l  = (w << 4) + o;                 // h index
    int row = (g << 6) + l;                // gate row in [0,256)
    const v2f* wp = (const v2f*)(wh + (size_t)row*H);
    v2f w00=wp[0], w01=wp[1], w02=wp[2], w03=wp[3], w04=wp[4], w05=wp[5], w06=wp[6], w07=wp[7],
        w08=wp[8], w09=wp[9], w10=wp[10],w11=wp[11],w12=wp[12],w13=wp[13],w14=wp[14],w15=wp[15],
        w16=wp[16],w17=wp[17],w18=wp[18],w19=wp[19],w20=wp[20],w21=wp[21],w22=wp[22],w23=wp[23],
        w24=wp[24],w25=wp[25],w26=wp[26],w27=wp[27],w28=wp[28],w29=wp[29],w30=wp[30],w31=wp[31];
    __shared__ __align__(16) float hsb[2][H];
    float c = 0.f;
    if (gi < H) hsb[0][gi] = 0.f;
    __syncthreads();
    const float* gp = gin + row;
    float gcur = gp[(dir ? (T-1) : 0)*256];
    for (int step=0; step<T; step++){
        int t = dir ? (T-1-step) : step;
        float gnext = 0.f;
        if (step+1 < T) gnext = gp[(dir ? (T-2-step) : (step+1))*256];
        const float4* hv = (const float4*)hsb[step & 1];   // uniform addr, b128
        float4 H0=hv[0],  H1=hv[1],  H2=hv[2],  H3=hv[3];
        float4 H4=hv[4],  H5=hv[5],  H6=hv[6],  H7=hv[7];
        float4 H8=hv[8],  H9=hv[9],  H10=hv[10],H11=hv[11];
        float4 H12=hv[12],H13=hv[13],H14=hv[14],H15=hv[15];
        v2f A0={gcur,0.f}, A1={0.f,0.f}, A2={0.f,0.f}, A3={0.f,0.f};
        pkfma(A0,w00,LO2(H0));  pkfma(A1,w01,HI2(H0));  pkfma(A2,w02,LO2(H1));  pkfma(A3,w03,HI2(H1));
        pkfma(A0,w04,LO2(H2));  pkfma(A1,w05,HI2(H2));  pkfma(A2,w06,LO2(H3));  pkfma(A3,w07,HI2(H3));
        pkfma(A0,w08,LO2(H4));  pkfma(A1,w09,HI2(H4));  pkfma(A2,w10,LO2(H5));  pkfma(A3,w11,HI2(H5));
        pkfma(A0,w12,LO2(H6));  pkfma(A1,w13,HI2(H6));  pkfma(A2,w14,LO2(H7));  pkfma(A3,w15,HI2(H7));
        pkfma(A0,w16,LO2(H8));  pkfma(A1,w17,HI2(H8));  pkfma(A2,w18,LO2(H9));  pkfma(A3,w19,HI2(H9));
        pkfma(A0,w20,LO2(H10)); pkfma(A1,w21,HI2(H10)); pkfma(A2,w22,LO2(H11)); pkfma(A3,w23,HI2(H11));
        pkfma(A0,w24,LO2(H12)); pkfma(A1,w25,HI2(H12)); pkfma(A2,w26,LO2(H13)); pkfma(A3,w27,HI2(H13));
        pkfma(A0,w28,LO2(H14)); pkfma(A1,w29,HI2(H14)); pkfma(A2,w30,LO2(H15)); pkfma(A3,w31,HI2(H15));
        float val = ((A0.x+A0.y) + (A1.x+A1.y)) + ((A2.x+A2.y) + (A3.x+A3.y));
        // intra-wave gate exchange: i/f/g/o for h=l live in lanes o, o+16, o+32, o+48
        float i_ = __shfl(val, o);
        float f_ = __shfl(val, o + 16);
        float g_ = __shfl(val, o + 32);
        float o_ = __shfl(val, o + 48);
        c = fsig(f_)*c + fsig(i_)*ftanh(g_);   // 4 lanes per l: identical update
        float hn = fsig(o_)*ftanh(c);
        if (g == 0){
            hsb[(step+1)&1][l] = hn;           // partitioned write, other buffer
            hid[t*2*H + dir*H + l] = hn;
        }
        __syncthreads();                       // the ONLY barrier per step
        gcur = gnext;
    }
}

// ---------------- LSTM recurrence, H=32 T=64: single wave, NO barrier --------------
__global__ __launch_bounds__(64)
__attribute__((amdgpu_waves_per_eu(1, 1)))
void k_lstm_rec32(
        const float* __restrict__ gin_f, const float* __restrict__ wh_f,
        const float* __restrict__ gin_b, const float* __restrict__ wh_b,
        float* __restrict__ hid /* [T][64] */){
    const int H = 32, T = 64;
    int dir = blockIdx.x;
    const float* gin = dir ? gin_b : gin_f;
    const float* wh  = dir ? wh_b  : wh_f;
    int gi = threadIdx.x;                  // 0..63
    v2f wA[16], wB[16];
    {
        const v2f* rA = (const v2f*)(wh + (size_t)(     gi)*H);   // rows 0..63:  i|f
        const v2f* rB = (const v2f*)(wh + (size_t)(64 + gi)*H);   // rows 64..127: g|o
        #pragma unroll
        for (int k=0;k<16;k++){ wA[k]=rA[k]; wB[k]=rB[k]; }
    }
    __shared__ __align__(16) float hs[H];
    float c = 0.f;
    if (gi < H) hs[gi] = 0.f;
    __syncthreads();
    const float* gp = gin + gi;
    int ts0 = dir ? (T-1) : 0, ts1 = dir ? (T-2) : 1;
    float g0 = gp[ts0*128], g1 = gp[ts0*128 + 64];
    float n0 = gp[ts1*128], n1 = gp[ts1*128 + 64];
    bool lo = (gi < H);
    for (int step=0; step<T; step++){
        int t = dir ? (T-1-step) : step;
        float p0=0.f, p1=0.f;
        if (step+2 < T){
            int tp = dir ? (T-3-step) : (step+2);
            p0 = gp[tp*128]; p1 = gp[tp*128 + 64];
        }
        v2f aA = {g0, 0.f}, aB = {g1, 0.f};
        const float4* hv = (const float4*)hs;      // uniform addr, b128 reads
        #pragma unroll
        for (int k=0;k<8;k++){
            float4 h4 = hv[k];
            pkfma(aA, wA[2*k],   LO2(h4));
            pkfma(aB, wB[2*k],   LO2(h4));
            pkfma(aA, wA[2*k+1], HI2(h4));
            pkfma(aB, wB[2*k+1], HI2(h4));
        }
        float sA = aA.x + aA.y;            // lane<32: i ; lane>=32: f
        float sB = aB.x + aB.y;            // lane<32: g ; lane>=32: o
        float pA = __shfl(sA, gi ^ 32);
        float pB = __shfl(sB, gi ^ 32);
        float i_ = lo ? sA : pA;
        float f_ = lo ? pA : sA;
        float g_ = lo ? sB : pB;
        float o_ = lo ? pB : sB;
        c = fsig(f_)*c + fsig(i_)*ftanh(g_);
        float hn = fsig(o_)*ftanh(c);
        if (lo){
            hid[t*2*H + dir*H + gi] = hn;
            hs[gi] = hn;                   // same wave: in-order LDS, no barrier
        }
        g0 = n0; g1 = n1; n0 = p0; n1 = p1;
    }
}

// ---------------- si=0: rebuild nh in place = [beat_span | meas_span | nh_sec] -----
__global__ void k_spans(float* __restrict__ nh, const float* __restrict__ bh,
                        const float* __restrict__ mh,
                        const int* __restrict__ bn, const int* __restrict__ mn){
    int n = blockIdx.x, s = threadIdx.x;           // 320 threads
    float v;
    if (s < 128)      v = bh[bn[n]*128 + s];
    else if (s < 192) v = mh[mn[n]*64 + (s-128)];
    else              v = nh[n*SS + s];            // own-thread read-then-write: safe
    nh[n*SS + s] = v;
}

// ---------------- si=1: spans + final output fused ---------------------------------
__global__ void k_spans_out(const float* __restrict__ bh, const float* __restrict__ mh,
                            const float* __restrict__ nh, const float* __restrict__ nh2,
                            const int* __restrict__ bn, const int* __restrict__ mn,
                            float* __restrict__ out){
    int n = blockIdx.x, s = threadIdx.x;           // 448 threads
    float v;
    if (s < 128)      v = bh[bn[n]*128 + s];
    else if (s < 192) v = mh[mn[n]*64 + (s-128)];
    else if (s < 320) v = nh[n*SS + s];
    else              v = nh2[n*SS + 192 + (s-320)];
    out[n*448 + s] = v;
}

// ===========================================================================
extern "C" void kernel_launch(void* const* d_in, const int* in_sizes, int n_in,
                              void* d_out, int out_size, void* d_ws, size_t ws_size,
                              hipStream_t stream) {
    const float* nodes    = (const float*)d_in[0];
    const float* adj      = (const float*)d_in[1];
    const int*   bn       = (const int*)  d_in[2];
    const int*   mn       = (const int*)  d_in[3];
    const float* fc_w     = (const float*)d_in[6];
    const float* fc_b     = (const float*)d_in[7];
    const float* g_wz[2]  = {(const float*)d_in[8],  (const float*)d_in[17]};
    const float* g_wr[2]  = {(const float*)d_in[9],  (const float*)d_in[18]};
    const float* g_wh[2]  = {(const float*)d_in[10], (const float*)d_in[19]};
    const float* g_uz[2]  = {(const float*)d_in[11], (const float*)d_in[20]};
    const float* g_ur[2]  = {(const float*)d_in[12], (const float*)d_in[21]};
    const float* g_uh[2]  = {(const float*)d_in[13], (const float*)d_in[22]};
    const float* g_bz[2]  = {(const float*)d_in[14], (const float*)d_in[23]};
    const float* g_br[2]  = {(const float*)d_in[15], (const float*)d_in[24]};
    const float* g_bh[2]  = {(const float*)d_in[16], (const float*)d_in[25]};
    const float* gb_w     = (const float*)d_in[26];
    const float* gb_b     = (const float*)d_in[27];
    const float* batt_w   = (const float*)d_in[28];
    const float* batt_b   = (const float*)d_in[29];
    const float* batt_c   = (const float*)d_in[30];
    const float* matt_w   = (const float*)d_in[31];
    const float* matt_b   = (const float*)d_in[32];
    const float* matt_c   = (const float*)d_in[33];
    const float* bwi_f    = (const float*)d_in[34];
    const float* bwh_f    = (const float*)d_in[35];
    const float* bb_f     = (const float*)d_in[36];
    const float* bwi_b    = (const float*)d_in[37];
    const float* bwh_b    = (const float*)d_in[38];
    const float* bb_b     = (const float*)d_in[39];
    const float* mwi_f    = (const float*)d_in[40];
    const float* mwh_f    = (const float*)d_in[41];
    const float* mb_f     = (const float*)d_in[42];
    const float* mwi_b    = (const float*)d_in[43];
    const float* mwh_b    = (const float*)d_in[44];
    const float* mb_b     = (const float*)d_in[45];
    float* out = (float*)d_out;

    // --- workspace layout (floats; ~27.7 MB, under the 31.2MB proven in r0) ---
    float* W_   = (float*)d_ws;
    float* nh   = W_;                       // 1024*320
    float* nh2  = nh   + 327680;            // 1024*320
    float* act  = nh2  + 327680;            // 10*1024*320
    float* part = act  + 3276800;           // 10*1024*384 (slices 0-4 dyn, 5-9 static)
    float* bgf  = part + 3932160;           // 256*256
    float* bgb  = bgf  + 65536;             // 256*256
    float* beat_hidden = bgb + 65536;       // 256*128
    float* mgf  = beat_hidden + 32768;      // 64*128
    float* mgb  = mgf  + 8192;              // 64*128
    float* meas_hidden = mgb + 8192;        // 64*64
    int*   cnt  = (int*)(meas_hidden + 4096);  // 10*1024
    int*   idx  = cnt + 10240;                  // 10*1024*64

    float* part_s = part + 5*NN*384;        // static slices base (contiguous: 5-9)

    hipMemsetAsync(cnt, 0, EE*NN*sizeof(int), stream);
    k_csr_build<<<EE*NN, 256, 0, stream>>>(adj, cnt, idx);
    k_note_fc<<<NN, 128, 0, stream>>>(nodes, fc_w, fc_b, nh);

    for (int si = 0; si < 2; ++si){
        for (int half = 0; half < 2; ++half){
            float* x = half ? nh2 : nh;
            int w = half;                     // weight set index
            bool zerostatic = (si == 0 && half == 0);   // nh[:, :192] == 0
            if (half == 1)                    // nb = relu(nh @ gb_w) -> nh2
                k_gb<<<NN/4, SS, 0, stream>>>(nh, gb_w, gb_b, nh2);
            for (int it = 0; it < 2; ++it){
                if (!zerostatic && it == 0){
                    // one full 320-col gather; static+dyn gemms in ONE launch
                    k_gather_full<<<EE*NN/4, 320, 0, stream>>>(x, cnt, idx, act);
                    k_gate_gemm_both<<<dim3(32,6,5), 256, 0, stream>>>(
                            act, g_wz[w], g_wr[w], g_wh[w], part, part_s);
                } else {
                    k_gather_dyn<<<EE*NN/8, 256, 0, stream>>>(x, cnt, idx, act);
                    // it=1 (or zerostatic): dyn gemm, fold static via addv when present
                    k_gate_gemm_dyn<<<dim3(32,3,5), 256, 0, stream>>>(
                            act, g_wz[w], g_wr[w], g_wh[w], part,
                            zerostatic ? nullptr : part_s);
                }
                int nsp = (!zerostatic && it == 0) ? 10 : 5;
                k_gru<<<NN/2, 256, 0, stream>>>(x, part, nsp,
                        g_uz[w], g_ur[w], g_uh[w], g_bz[w], g_br[w], g_bh[w]);
            }
        }
        k_batt_fused<<<NB, 256, 0, stream>>>(nh, nh2, batt_w, batt_b, batt_c,
                                             bwi_f, bb_f, bwi_b, bb_b, bgf, bgb);
        k_lstm_rec64<<<2, 256, 0, stream>>>(bgf, bwh_f, bgb, bwh_b, beat_hidden);
        k_matt_fused<<<NM, 128, 0, stream>>>(beat_hidden, matt_w, matt_b, matt_c,
                                             mwi_f, mb_f, mwi_b, mb_b, mgf, mgb);
        k_lstm_rec32<<<2, 64, 0, stream>>>(mgf, mwh_f, mgb, mwh_b, meas_hidden);
        if (si == 0)
            k_spans<<<NN, SS, 0, stream>>>(nh, beat_hidden, meas_hidden, bn, mn);
        else
            k_spans_out<<<NN, 448, 0, stream>>>(beat_hidden, meas_hidden, nh, nh2,
                                                bn, mn, out);
    }
}

// Round 13
// 970.817 us; speedup vs baseline: 1.3276x; 1.0293x over previous
//
#include <hip/hip_runtime.h>
#include <math.h>

// ---------------------------------------------------------------------------
// IsgnBeatMeasEncoder — round 17: k-split gb/batt/matt (the gru recipe).
// Round-16: gru k-split + merged it=0 GEMM = 1028 -> 999us (matched). The
// working recipe in this latency regime: halve the serial load-FMA chain,
// double wave-parallelism, LDS-reduce partials.
// Round 17 applies it to the remaining serial GEMVs:
//   - k_gb: 640 thr (2 wave-aligned halves of 320), k 320 -> 160/half.
//   - k_batt_fused: 512 thr; main GEMV 256k -> 128/half; sim/softmax/bnode
//     on half 0; pre-GEMV 128 v2f -> 64/half; LDS-reduce both stages.
//   - k_matt_fused: 256 thr, same two-stage split.
// All else frozen (rec64 @116us latency floor, VGPR-132 canary; gemm/gru/
// gather at r16 forms).
// Falsification: total >=992 -> recipe doesn't transfer; declare plateau.
// ---------------------------------------------------------------------------

#define NN    1024
#define EE    10
#define INDIM 78
#define SS    320
#define SECD  128
#define NB    256
#define NM    64
#define CAP   64     // max nonzeros per adjacency column (mean ~10.2)

typedef float v2f __attribute__((ext_vector_type(2)));

__device__ __forceinline__ void pkfma(v2f& a, v2f x, v2f y){
    asm("v_pk_fma_f32 %0, %1, %2, %0" : "+v"(a) : "v"(x), "v"(y));
}
// a.lo += x.lo*b.lo ; a.hi += x.hi*b.lo   (broadcast LOW half of b)
__device__ __forceinline__ void pkfma_blo(v2f& a, v2f x, v2f b){
    asm("v_pk_fma_f32 %0, %1, %2, %0 op_sel:[0,0,0] op_sel_hi:[1,0,1]"
        : "+v"(a) : "v"(x), "v"(b));
}
// a.lo += x.lo*b.hi ; a.hi += x.hi*b.hi   (broadcast HIGH half of b)
__device__ __forceinline__ void pkfma_bhi(v2f& a, v2f x, v2f b){
    asm("v_pk_fma_f32 %0, %1, %2, %0 op_sel:[0,1,0] op_sel_hi:[1,1,1]"
        : "+v"(a) : "v"(x), "v"(b));
}

#define LO2(F) ((v2f){F.x, F.y})
#define HI2(F) ((v2f){F.z, F.w})

__device__ __forceinline__ float fsig(float x){
    return __builtin_amdgcn_rcpf(1.f + __expf(-x));
}
__device__ __forceinline__ float ftanh(float x){
    // tanh(x) = 1 - 2/(exp(2x)+1); exp overflow -> inf -> rcp -> 0 -> 1 (correct)
    return 1.f - 2.f*__builtin_amdgcn_rcpf(1.f + __expf(2.f*x));
}

// ---------------- note_fc: x0 = tanh(nodes @ W + b); nh = [0(192) | x0] ------------
__global__ void k_note_fc(const float* __restrict__ nodes, const float* __restrict__ W,
                          const float* __restrict__ b, float* __restrict__ nh){
    int n = blockIdx.x, s = threadIdx.x;           // 128 threads
    __shared__ float xrow[INDIM];
    if (s < INDIM) xrow[s] = nodes[n*INDIM + s];
    __syncthreads();
    float acc = b[s];
    for (int k = 0; k < INDIM; ++k) acc += xrow[k]*W[k*128 + s];
    nh[n*SS + 192 + s] = ftanh(acc);
    nh[n*SS + s] = 0.f;
    if (s < 64) nh[n*SS + 128 + s] = 0.f;
}

// ---------------- CSR build: float4 scan of each adj row ---------------------------
__global__ void k_csr_build(const float* __restrict__ adj, int* __restrict__ cnt,
                            int* __restrict__ idx){
    int em = blockIdx.x;                   // e*NN + m  (row of adj[e])
    int e = em / NN, m = em % NN;
    const float4* row4 = (const float4*)(adj + (size_t)em * NN);
    int q = threadIdx.x;                   // 256 threads, 256 float4 = 1024 cols
    float4 v = row4[q];
    int n0 = q*4;
    if (v.x != 0.f){ int p = atomicAdd(&cnt[e*NN + n0+0], 1); if (p < CAP) idx[((size_t)e*NN + n0+0)*CAP + p] = m; }
    if (v.y != 0.f){ int p = atomicAdd(&cnt[e*NN + n0+1], 1); if (p < CAP) idx[((size_t)e*NN + n0+1)*CAP + p] = m; }
    if (v.z != 0.f){ int p = atomicAdd(&cnt[e*NN + n0+2], 1); if (p < CAP) idx[((size_t)e*NN + n0+2)*CAP + p] = m; }
    if (v.w != 0.f){ int p = atomicAdd(&cnt[e*NN + n0+3], 1); if (p < CAP) idx[((size_t)e*NN + n0+3)*CAP + p] = m; }
}

// ---------------- full gather (320 cols), float4: 80 quads/en, 4 en/block ----------
__global__ void k_gather_full(const float* __restrict__ x, const int* __restrict__ cnt,
                              const int* __restrict__ idx, float* __restrict__ act){
    int en = blockIdx.x*4 + threadIdx.x/80;        // 320 threads
    int q  = threadIdx.x % 80;
    int c = cnt[en]; if (c > CAP) c = CAP;
    const int* lst = idx + (size_t)en*CAP;
    float4 acc = {0.f,0.f,0.f,0.f};
    const float* xb = x + q*4;
    for (int j = 0; j < c; ++j){
        float4 v = *(const float4*)(xb + (size_t)lst[j]*SS);
        acc.x += v.x; acc.y += v.y; acc.z += v.z; acc.w += v.w;
    }
    *(float4*)(act + (size_t)en*SS + q*4) = acc;
}

// ---------------- dyn gather (cols 192..320), float4: 32 quads/en, 8 en/block ------
__global__ void k_gather_dyn(const float* __restrict__ x, const int* __restrict__ cnt,
                             const int* __restrict__ idx, float* __restrict__ act){
    int en = blockIdx.x*8 + (threadIdx.x >> 5);    // 256 threads
    int q  = threadIdx.x & 31;
    int c = cnt[en]; if (c > CAP) c = CAP;
    const int* lst = idx + (size_t)en*CAP;
    float4 acc = {0.f,0.f,0.f,0.f};
    const float* xb = x + 192 + q*4;
    for (int j = 0; j < c; ++j){
        float4 v = *(const float4*)(xb + (size_t)lst[j]*SS);
        acc.x += v.x; acc.y += v.y; acc.z += v.z; acc.w += v.w;
    }
    *(float4*)(act + (size_t)en*SS + 192 + q*4) = acc;
}

// ---------------- gate GEMM core (runtime K range) ---------------------------------
__device__ __forceinline__ void gemm_body(const float* __restrict__ act,
        const float* __restrict__ W, float* __restrict__ outp,
        const float* __restrict__ addv, int K0, int K1, int nt, int z,
        float* A, float* B){
    int tid = threadIdx.x;
    int tx = tid & 31;             // cols tx*4 .. +3
    int ty = tid >> 5;             // rows ty*4 .. +3
    v2f acc[2][4];
    #pragma unroll
    for (int i=0;i<2;i++)
        #pragma unroll
        for (int j=0;j<4;j++) acc[i][j] = (v2f){0.f,0.f};
    for (int eh = 0; eh < 2; ++eh){
        int e = z*2 + eh;
        const float* Ae = act + (size_t)e*NN*SS + (size_t)nt*32*SS;
        const float* We = W   + (size_t)e*SS*SECD;
        for (int kc = K0; kc < K1; kc += 32){
            {                                      // A: 32 rows x 32 k = 256 float4
                int r  = tid >> 3;
                int k4 = (tid & 7) << 2;
                float4 v = *(const float4*)(Ae + r*SS + kc + k4);
                A[(k4+0)*36 + r] = v.x; A[(k4+1)*36 + r] = v.y;
                A[(k4+2)*36 + r] = v.z; A[(k4+3)*36 + r] = v.w;
            }
            #pragma unroll
            for (int i=0;i<4;i++){                 // B: 32 k x 128 cols
                int lin4 = tid + i*256;            // 1024 float4
                int kk = lin4 >> 5;
                int c4 = (lin4 & 31) << 2;
                *((float4*)(B + kk*132 + c4)) = *(const float4*)(We + (kc+kk)*SECD + c4);
            }
            __syncthreads();
            #pragma unroll 8
            for (int k=0;k<32;k++){
                float4 a4 = *(const float4*)(A + k*36 + ty*4);   // wave-uniform b128
                v2f a01 = LO2(a4), a23 = HI2(a4);
                float4 b = *(const float4*)(B + k*132 + tx*4);   // r8-proven pattern
                v2f b01 = {b.x, b.y}, b23 = {b.z, b.w};
                pkfma_blo(acc[0][0], a01, b01); pkfma_bhi(acc[0][1], a01, b01);
                pkfma_blo(acc[0][2], a01, b23); pkfma_bhi(acc[0][3], a01, b23);
                pkfma_blo(acc[1][0], a23, b01); pkfma_bhi(acc[1][1], a23, b01);
                pkfma_blo(acc[1][2], a23, b23); pkfma_bhi(acc[1][3], a23, b23);
            }
            __syncthreads();
        }
    }
    size_t base = ((size_t)z*NN + (size_t)nt*32)*384;   // +g*SECD folded by caller
    float* P = outp + base;
    int r0 = ty*4;
    float4 o0 = make_float4(acc[0][0].x, acc[0][1].x, acc[0][2].x, acc[0][3].x);
    float4 o1 = make_float4(acc[0][0].y, acc[0][1].y, acc[0][2].y, acc[0][3].y);
    float4 o2 = make_float4(acc[1][0].x, acc[1][1].x, acc[1][2].x, acc[1][3].x);
    float4 o3 = make_float4(acc[1][0].y, acc[1][1].y, acc[1][2].y, acc[1][3].y);
    if (addv){
        const float* Q = addv + base;
        float4 q0 = *(const float4*)(Q + (size_t)(r0+0)*384 + tx*4);
        float4 q1 = *(const float4*)(Q + (size_t)(r0+1)*384 + tx*4);
        float4 q2 = *(const float4*)(Q + (size_t)(r0+2)*384 + tx*4);
        float4 q3 = *(const float4*)(Q + (size_t)(r0+3)*384 + tx*4);
        o0.x+=q0.x; o0.y+=q0.y; o0.z+=q0.z; o0.w+=q0.w;
        o1.x+=q1.x; o1.y+=q1.y; o1.z+=q1.z; o1.w+=q1.w;
        o2.x+=q2.x; o2.y+=q2.y; o2.z+=q2.z; o2.w+=q2.w;
        o3.x+=q3.x; o3.y+=q3.y; o3.z+=q3.z; o3.w+=q3.w;
    }
    *(float4*)(P + (size_t)(r0+0)*384 + tx*4) = o0;
    *(float4*)(P + (size_t)(r0+1)*384 + tx*4) = o1;
    *(float4*)(P + (size_t)(r0+2)*384 + tx*4) = o2;
    *(float4*)(P + (size_t)(r0+3)*384 + tx*4) = o3;
}

// dyn-only (with optional addv fold): grid (32,3,5)
__global__ __launch_bounds__(256) void k_gate_gemm_dyn(const float* __restrict__ act,
        const float* __restrict__ wz, const float* __restrict__ wr,
        const float* __restrict__ wh, float* __restrict__ part,
        const float* __restrict__ addv){
    __shared__ float A[32*36];
    __shared__ float B[32*132];
    int g = blockIdx.y;
    const float* W = (g==0) ? wz : ((g==1) ? wr : wh);
    const float* av = addv ? (addv + g*SECD) : nullptr;
    gemm_body(act, W, part + g*SECD, av, 192, 320, blockIdx.x, blockIdx.z, A, B);
}

// merged it=0: static (y<3 -> part_s, K 0..192) + dyn (y>=3 -> part, K 192..320),
// grid (32,6,5), no addv (gru reads 10 slices this iteration).
__global__ __launch_bounds__(256) void k_gate_gemm_both(const float* __restrict__ act,
        const float* __restrict__ wz, const float* __restrict__ wr,
        const float* __restrict__ wh, float* __restrict__ part,
        float* __restrict__ part_s){
    __shared__ float A[32*36];
    __shared__ float B[32*132];
    int y = blockIdx.y;            // 0..5
    int g = (y >= 3) ? (y - 3) : y;
    const float* W = (g==0) ? wz : ((g==1) ? wr : wh);
    if (y >= 3)
        gemm_body(act, W, part   + g*SECD, nullptr, 192, 320, blockIdx.x, blockIdx.z, A, B);
    else
        gemm_body(act, W, part_s + g*SECD, nullptr,   0, 192, blockIdx.x, blockIdx.z, A, B);
}

// ---------------- GRU update v2: 256 thr, 2 notes, k split across wave-halves ------
__global__ __launch_bounds__(256) void k_gru(float* __restrict__ x,
        const float* __restrict__ part, int nsp,
        const float* __restrict__ uz, const float* __restrict__ ur, const float* __restrict__ uh,
        const float* __restrict__ bz, const float* __restrict__ br, const float* __restrict__ bh){
    int n0 = blockIdx.x*2;
    int tid = threadIdx.x;
    int s = tid & 127;                 // col
    int h = tid >> 7;                  // k-half (wave-uniform)
    int k0 = h*64;
    __shared__ float xs[2][SECD], rx[2][SECD];
    __shared__ float red[2][2][2][SECD];   // [dz|dr][half][note][col] (reused for dh)
    if (h == 0){
        xs[0][s] = x[(n0+0)*SS + 192 + s];
        xs[1][s] = x[(n0+1)*SS + 192 + s];
    }
    __syncthreads();
    float mz[2]={0,0}, mr[2]={0,0}, mh[2]={0,0};
    if (h == 0){
        for (int sp=0; sp<nsp; sp++){
            const float* Pp = part + ((size_t)sp*NN + n0)*384;
            #pragma unroll
            for (int j=0;j<2;j++){
                mz[j] += Pp[j*384 + s];
                mr[j] += Pp[j*384 + 128 + s];
                mh[j] += Pp[j*384 + 256 + s];
            }
        }
    }
    float dz[2]={0,0}, dr[2]={0,0};
    #pragma unroll 8
    for (int k=k0;k<k0+64;k++){
        float wz_ = uz[k*SECD + s], wr_ = ur[k*SECD + s];
        #pragma unroll
        for (int j=0;j<2;j++){ float xv = xs[j][k]; dz[j] += xv*wz_; dr[j] += xv*wr_; }
    }
    red[0][h][0][s]=dz[0]; red[0][h][1][s]=dz[1];
    red[1][h][0][s]=dr[0]; red[1][h][1][s]=dr[1];
    __syncthreads();
    float zz[2], rr[2];
    if (h == 0){
        #pragma unroll
        for (int j=0;j<2;j++){
            float dzf = red[0][0][j][s] + red[0][1][j][s];
            float drf = red[1][0][j][s] + red[1][1][j][s];
            zz[j] = fsig(mz[j] + dzf + bz[s]);
            rr[j] = fsig(mr[j] + drf + br[s]);
            rx[j][s] = rr[j]*xs[j][s];
        }
    }
    __syncthreads();
    float dh[2]={0,0};
    #pragma unroll 8
    for (int k=k0;k<k0+64;k++){
        float wh_ = uh[k*SECD + s];
        #pragma unroll
        for (int j=0;j<2;j++) dh[j] += rx[j][k]*wh_;
    }
    red[0][h][0][s]=dh[0]; red[0][h][1][s]=dh[1];
    __syncthreads();
    if (h == 0){
        #pragma unroll
        for (int j=0;j<2;j++){
            float dhf = red[0][0][j][s] + red[0][1][j][s];
            float hc = ftanh(mh[j] + dhf + bh[s]);
            x[(n0+j)*SS + 192 + s] = (1.f - zz[j])*xs[j][s] + rr[j]*hc;
        }
    }
}

// ---------------- nb = relu(nh @ gb_w + gb_b) -> nh2; 640 thr, k split -------------
// Halves at thread 320 (wave-aligned: 320 = 5 waves). k loop 320 -> 160/half.
__global__ __launch_bounds__(640) void k_gb(const float* __restrict__ nh,
                     const float* __restrict__ W,
                     const float* __restrict__ b, float* __restrict__ nb){
    int n0 = blockIdx.x*4;
    int tid = threadIdx.x;
    int h = (tid >= 320) ? 1 : 0;
    int s = tid - h*320;
    int k0 = h*160;
    __shared__ float xr_t[SS*4];                   // [k][j]
    __shared__ float red[2][4][SS];                // [half][note][col]
    if (h == 0){
        float v0 = nh[(n0+0)*SS + s], v1 = nh[(n0+1)*SS + s];
        float v2 = nh[(n0+2)*SS + s], v3 = nh[(n0+3)*SS + s];
        *(float4*)(xr_t + s*4) = make_float4(v0,v1,v2,v3);
    }
    __syncthreads();
    v2f a01={0.f,0.f}, a23={0.f,0.f};
    #pragma unroll 8
    for (int k=k0;k<k0+160;k++){
        float wv = W[k*SS + s];
        v2f ws = {wv, wv};
        const v2f* xp = (const v2f*)(xr_t + k*4);  // uniform addr -> broadcast
        pkfma(a01, xp[0], ws);
        pkfma(a23, xp[1], ws);
    }
    red[h][0][s]=a01.x; red[h][1][s]=a01.y; red[h][2][s]=a23.x; red[h][3][s]=a23.y;
    __syncthreads();
    if (h == 0){
        float bv = b[s];
        nb[(n0+0)*SS + s] = fmaxf(bv + red[0][0][s] + red[1][0][s], 0.f);
        nb[(n0+1)*SS + s] = fmaxf(bv + red[0][1][s] + red[1][1][s], 0.f);
        nb[(n0+2)*SS + s] = fmaxf(bv + red[0][2][s] + red[1][2][s], 0.f);
        nb[(n0+3)*SS + s] = fmaxf(bv + red[0][3][s] + red[1][3][s], 0.f);
    }
}

// ---------------- FUSED beat attention + lstm_pre, 512 thr, two-stage k-split ------
__global__ __launch_bounds__(512) void k_batt_fused(
        const float* __restrict__ nh, const float* __restrict__ nh2,
        const float* __restrict__ W, const float* __restrict__ b,
        const float* __restrict__ cvec,
        const float* __restrict__ wi_f, const float* __restrict__ b_f,
        const float* __restrict__ wi_b, const float* __restrict__ b_b,
        float* __restrict__ gf, float* __restrict__ gbo){
    int g = blockIdx.x;
    int tid = threadIdx.x;
    int s = tid & 255;                             // col
    int h = tid >> 8;                              // k-half (wave-uniform)
    __shared__ float xr_t[256*4];                  // [k][j]
    __shared__ float simw[4][8];
    __shared__ float wgt[4][8];
    __shared__ float bnode[256];
    __shared__ float red[2][4][256];               // [half][j][col] (reused)
    if (h == 0){
        float c0,c1,c2,c3;
        if (s < 128){
            c0 = nh[(g*4+0)*SS + 192 + s]; c1 = nh[(g*4+1)*SS + 192 + s];
            c2 = nh[(g*4+2)*SS + 192 + s]; c3 = nh[(g*4+3)*SS + 192 + s];
        } else {
            c0 = nh2[(g*4+0)*SS + 64 + s]; c1 = nh2[(g*4+1)*SS + 64 + s];
            c2 = nh2[(g*4+2)*SS + 64 + s]; c3 = nh2[(g*4+3)*SS + 64 + s];
        }
        *(float4*)(xr_t + s*4) = make_float4(c0,c1,c2,c3);
    }
    __syncthreads();
    {   // main GEMV: k-half per thread-half
        int k0 = h*128;
        v2f ac01 = {0.f,0.f}, ac23 = {0.f,0.f};
        #pragma unroll 8
        for (int k=k0;k<k0+128;k++){
            float wv = W[k*256 + s];
            v2f ws = {wv, wv};
            const v2f* xp = (const v2f*)(xr_t + k*4);
            pkfma(ac01, xp[0], ws);
            pkfma(ac23, xp[1], ws);
        }
        red[h][0][s]=ac01.x; red[h][1][s]=ac01.y; red[h][2][s]=ac23.x; red[h][3][s]=ac23.y;
    }
    __syncthreads();
    int hd = s >> 5;                               // head (HD=32)
    if (h == 0){
        float bias = b[s];
        float cv = cvec[s];
        #pragma unroll
        for (int j=0;j<4;j++){
            float p = ftanh(bias + red[0][j][s] + red[1][j][s])*cv;
            #pragma unroll
            for (int off=16; off>0; off>>=1) p += __shfl_down(p, off);
            if ((s & 31) == 0) simw[j][hd] = p;
        }
    }
    __syncthreads();
    if (tid < 8){
        float v0=simw[0][tid], v1=simw[1][tid], v2=simw[2][tid], v3=simw[3][tid];
        float mx = fmaxf(fmaxf(v0,v1), fmaxf(v2,v3));
        float e0=__expf(v0-mx), e1=__expf(v1-mx), e2=__expf(v2-mx), e3=__expf(v3-mx);
        float den = e0+e1+e2+e3;
        wgt[0][tid]=e0/den; wgt[1][tid]=e1/den; wgt[2][tid]=e2/den; wgt[3][tid]=e3/den;
    }
    __syncthreads();
    if (h == 0){
        float4 xs4 = *(const float4*)(xr_t + s*4);
        bnode[s] = xs4.x*wgt[0][hd] + xs4.y*wgt[1][hd] + xs4.z*wgt[2][hd] + xs4.w*wgt[3][hd];
    }
    __syncthreads();
    {   // pre-GEMV, both directions, k-half per thread-half
        v2f afA = {0.f,0.f}, afB = {0.f,0.f};
        v2f abA = {0.f,0.f}, abB = {0.f,0.f};
        const v2f* wfp = (const v2f*)(wi_f + (size_t)s*256);
        const v2f* wbp = (const v2f*)(wi_b + (size_t)s*256);
        const v2f* bp  = (const v2f*)bnode;
        int q0 = h*64;
        #pragma unroll 8
        for (int k2=q0;k2<q0+64;k2+=2){
            v2f x01 = bp[k2], x23 = bp[k2+1];
            pkfma(afA, wfp[k2], x01); pkfma(afB, wfp[k2+1], x23);
            pkfma(abA, wbp[k2], x01); pkfma(abB, wbp[k2+1], x23);
        }
        red[h][0][s] = (afA.x + afA.y) + (afB.x + afB.y);
        red[h][1][s] = (abA.x + abA.y) + (abB.x + abB.y);
    }
    __syncthreads();
    if (h == 0){
        gf [g*256 + s] = b_f[s] + red[0][0][s] + red[1][0][s];
        gbo[g*256 + s] = b_b[s] + red[0][1][s] + red[1][1][s];
    }
}

// ---------------- FUSED measure attention + lstm_pre, 256 thr, two-stage split -----
__global__ __launch_bounds__(256) void k_matt_fused(
        const float* __restrict__ bh,   // beat_hidden [256][128]
        const float* __restrict__ W, const float* __restrict__ b,
        const float* __restrict__ cvec,
        const float* __restrict__ wi_f, const float* __restrict__ b_f,
        const float* __restrict__ wi_b, const float* __restrict__ b_b,
        float* __restrict__ gf, float* __restrict__ gbo){
    int g = blockIdx.x;
    int tid = threadIdx.x;
    int s = tid & 127;                             // col
    int h = tid >> 7;                              // k-half (wave-uniform)
    __shared__ float xr_t[128*4];                  // [k][j]
    __shared__ float simw[4][8];
    __shared__ float wgt[4][8];
    __shared__ float mnode[128];
    __shared__ float red[2][4][128];               // [half][j][col] (reused)
    if (h == 0){
        float c0 = bh[(g*4+0)*128 + s], c1 = bh[(g*4+1)*128 + s];
        float c2 = bh[(g*4+2)*128 + s], c3 = bh[(g*4+3)*128 + s];
        *(float4*)(xr_t + s*4) = make_float4(c0,c1,c2,c3);
    }
    __syncthreads();
    {   // main GEMV: k-half per thread-half
        int k0 = h*64;
        v2f ac01 = {0.f,0.f}, ac23 = {0.f,0.f};
        #pragma unroll 8
        for (int k=k0;k<k0+64;k++){
            float wv = W[k*128 + s];
            v2f ws = {wv, wv};
            const v2f* xp = (const v2f*)(xr_t + k*4);
            pkfma(ac01, xp[0], ws);
            pkfma(ac23, xp[1], ws);
        }
        red[h][0][s]=ac01.x; red[h][1][s]=ac01.y; red[h][2][s]=ac23.x; red[h][3][s]=ac23.y;
    }
    __syncthreads();
    int hd = s >> 4;                               // head (HD=16)
    if (h == 0){
        float bias = b[s];
        float cv = cvec[s];
        #pragma unroll
        for (int j=0;j<4;j++){
            float p = ftanh(bias + red[0][j][s] + red[1][j][s])*cv;
            #pragma unroll
            for (int off=8; off>0; off>>=1) p += __shfl_down(p, off);
            if ((s & 15) == 0) simw[j][hd] = p;
        }
    }
    __syncthreads();
    if (tid < 8){
        float v0=simw[0][tid], v1=simw[1][tid], v2=simw[2][tid], v3=simw[3][tid];
        float mx = fmaxf(fmaxf(v0,v1), fmaxf(v2,v3));
        float e0=__expf(v0-mx), e1=__expf(v1-mx), e2=__expf(v2-mx), e3=__expf(v3-mx);
        float den = e0+e1+e2+e3;
        wgt[0][tid]=e0/den; wgt[1][tid]=e1/den; wgt[2][tid]=e2/den; wgt[3][tid]=e3/den;
    }
    __syncthreads();
    if (h == 0){
        float4 xs4 = *(const float4*)(xr_t + s*4);
        mnode[s] = xs4.x*wgt[0][hd] + xs4.y*wgt[1][hd] + xs4.z*wgt[2][hd] + xs4.w*wgt[3][hd];
    }
    __syncthreads();
    {   // pre-GEMV, both directions, k-half per thread-half
        v2f afA = {0.f,0.f}, afB = {0.f,0.f};
        v2f abA = {0.f,0.f}, abB = {0.f,0.f};
        const v2f* wfp = (const v2f*)(wi_f + (size_t)s*128);
        const v2f* wbp = (const v2f*)(wi_b + (size_t)s*128);
        const v2f* bp  = (const v2f*)mnode;
        int q0 = h*32;
        #pragma unroll 8
        for (int k2=q0;k2<q0+32;k2+=2){
            v2f x01 = bp[k2], x23 = bp[k2+1];
            pkfma(afA, wfp[k2], x01); pkfma(afB, wfp[k2+1], x23);
            pkfma(abA, wbp[k2], x01); pkfma(abB, wbp[k2+1], x23);
        }
        red[h][0][s] = (afA.x + afA.y) + (afB.x + afB.y);
        red[h][1][s] = (abA.x + abA.y) + (abB.x + abB.y);
    }
    __syncthreads();
    if (h == 0){
        gf [g*128 + s] = b_f[s] + red[0][0][s] + red[1][0][s];
        gbo[g*128 + s] = b_b[s] + red[0][1][s] + red[1][1][s];
    }
}

// ---------------- LSTM recurrence, H=64 T=256: frozen r14 form ---------------------
__global__ __launch_bounds__(256)
__attribute__((amdgpu_waves_per_eu(1, 1)))
void k_lstm_rec64(
        const float* __restrict__ gin_f, const float* __restrict__ wh_f,
        const float* __restrict__ gin_b, const float* __restrict__ wh_b,
        float* __restrict__ hid /* [T][128] */){
    const int H = 64, T = 256;
    int dir = blockIdx.x;
    const float* gin = dir ? gin_b : gin_f;
    const float* wh  = dir ? wh_b  : wh_f;
    int gi = threadIdx.x;
    int w  = gi >> 6;                      // wave
    int j  = gi & 63;                      // lane
    int o  = j & 15;                       // h offset within wave's range
    int g  = j >> 4;                       // gate (0=i,1=f,2=g,3=o)
    int l  = (w << 4) + o;                 // h index
    int row = (g << 6) + l;                // gate row in [0,256)
    const v2f* wp = (const v2f*)(wh + (size_t)row*H);
    v2f w00=wp[0], w01=wp[1], w02=wp[2], w03=wp[3], w04=wp[4], w05=wp[5], w06=wp[6], w07=wp[7],
        w08=wp[8], w09=wp[9], w10=wp[10],w11=wp[11],w12=wp[12],w13=wp[13],w14=wp[14],w15=wp[15],
        w16=wp[16],w17=wp[17],w18=wp[18],w19=wp[19],w20=wp[20],w21=wp[21],w22=wp[22],w23=wp[23],
        w24=wp[24],w25=wp[25],w26=wp[26],w27=wp[27],w28=wp[28],w29=wp[29],w30=wp[30],w31=wp[31];
    __shared__ __align__(16) float hsb[2][H];
    float c = 0.f;
    if (gi < H) hsb[0][gi] = 0.f;
    __syncthreads();
    const float* gp = gin + row;
    float gcur = gp[(dir ? (T-1) : 0)*256];
    for (int step=0; step<T; step++){
        int t = dir ? (T-1-step) : step;
        float gnext = 0.f;
        if (step+1 < T) gnext = gp[(dir ? (T-2-step) : (step+1))*256];
        const float4* hv = (const float4*)hsb[step & 1];   // uniform addr, b128
        float4 H0=hv[0],  H1=hv[1],  H2=hv[2],  H3=hv[3];
        float4 H4=hv[4],  H5=hv[5],  H6=hv[6],  H7=hv[7];
        float4 H8=hv[8],  H9=hv[9],  H10=hv[10],H11=hv[11];
        float4 H12=hv[12],H13=hv[13],H14=hv[14],H15=hv[15];
        v2f A0={gcur,0.f}, A1={0.f,0.f}, A2={0.f,0.f}, A3={0.f,0.f};
        pkfma(A0,w00,LO2(H0));  pkfma(A1,w01,HI2(H0));  pkfma(A2,w02,LO2(H1));  pkfma(A3,w03,HI2(H1));
        pkfma(A0,w04,LO2(H2));  pkfma(A1,w05,HI2(H2));  pkfma(A2,w06,LO2(H3));  pkfma(A3,w07,HI2(H3));
        pkfma(A0,w08,LO2(H4));  pkfma(A1,w09,HI2(H4));  pkfma(A2,w10,LO2(H5));  pkfma(A3,w11,HI2(H5));
        pkfma(A0,w12,LO2(H6));  pkfma(A1,w13,HI2(H6));  pkfma(A2,w14,LO2(H7));  pkfma(A3,w15,HI2(H7));
        pkfma(A0,w16,LO2(H8));  pkfma(A1,w17,HI2(H8));  pkfma(A2,w18,LO2(H9));  pkfma(A3,w19,HI2(H9));
        pkfma(A0,w20,LO2(H10)); pkfma(A1,w21,HI2(H10)); pkfma(A2,w22,LO2(H11)); pkfma(A3,w23,HI2(H11));
        pkfma(A0,w24,LO2(H12)); pkfma(A1,w25,HI2(H12)); pkfma(A2,w26,LO2(H13)); pkfma(A3,w27,HI2(H13));
        pkfma(A0,w28,LO2(H14)); pkfma(A1,w29,HI2(H14)); pkfma(A2,w30,LO2(H15)); pkfma(A3,w31,HI2(H15));
        float val = ((A0.x+A0.y) + (A1.x+A1.y)) + ((A2.x+A2.y) + (A3.x+A3.y));
        // intra-wave gate exchange: i/f/g/o for h=l live in lanes o, o+16, o+32, o+48
        float i_ = __shfl(val, o);
        float f_ = __shfl(val, o + 16);
        float g_ = __shfl(val, o + 32);
        float o_ = __shfl(val, o + 48);
        c = fsig(f_)*c + fsig(i_)*ftanh(g_);   // 4 lanes per l: identical update
        float hn = fsig(o_)*ftanh(c);
        if (g == 0){
            hsb[(step+1)&1][l] = hn;           // partitioned write, other buffer
            hid[t*2*H + dir*H + l] = hn;
        }
        __syncthreads();                       // the ONLY barrier per step
        gcur = gnext;
    }
}

// ---------------- LSTM recurrence, H=32 T=64: single wave, NO barrier --------------
__global__ __launch_bounds__(64)
__attribute__((amdgpu_waves_per_eu(1, 1)))
void k_lstm_rec32(
        const float* __restrict__ gin_f, const float* __restrict__ wh_f,
        const float* __restrict__ gin_b, const float* __restrict__ wh_b,
        float* __restrict__ hid /* [T][64] */){
    const int H = 32, T = 64;
    int dir = blockIdx.x;
    const float* gin = dir ? gin_b : gin_f;
    const float* wh  = dir ? wh_b  : wh_f;
    int gi = threadIdx.x;                  // 0..63
    v2f wA[16], wB[16];
    {
        const v2f* rA = (const v2f*)(wh + (size_t)(     gi)*H);   // rows 0..63:  i|f
        const v2f* rB = (const v2f*)(wh + (size_t)(64 + gi)*H);   // rows 64..127: g|o
        #pragma unroll
        for (int k=0;k<16;k++){ wA[k]=rA[k]; wB[k]=rB[k]; }
    }
    __shared__ __align__(16) float hs[H];
    float c = 0.f;
    if (gi < H) hs[gi] = 0.f;
    __syncthreads();
    const float* gp = gin + gi;
    int ts0 = dir ? (T-1) : 0, ts1 = dir ? (T-2) : 1;
    float g0 = gp[ts0*128], g1 = gp[ts0*128 + 64];
    float n0 = gp[ts1*128], n1 = gp[ts1*128 + 64];
    bool lo = (gi < H);
    for (int step=0; step<T; step++){
        int t = dir ? (T-1-step) : step;
        float p0=0.f, p1=0.f;
        if (step+2 < T){
            int tp = dir ? (T-3-step) : (step+2);
            p0 = gp[tp*128]; p1 = gp[tp*128 + 64];
        }
        v2f aA = {g0, 0.f}, aB = {g1, 0.f};
        const float4* hv = (const float4*)hs;      // uniform addr, b128 reads
        #pragma unroll
        for (int k=0;k<8;k++){
            float4 h4 = hv[k];
            pkfma(aA, wA[2*k],   LO2(h4));
            pkfma(aB, wB[2*k],   LO2(h4));
            pkfma(aA, wA[2*k+1], HI2(h4));
            pkfma(aB, wB[2*k+1], HI2(h4));
        }
        float sA = aA.x + aA.y;            // lane<32: i ; lane>=32: f
        float sB = aB.x + aB.y;            // lane<32: g ; lane>=32: o
        float pA = __shfl(sA, gi ^ 32);
        float pB = __shfl(sB, gi ^ 32);
        float i_ = lo ? sA : pA;
        float f_ = lo ? pA : sA;
        float g_ = lo ? sB : pB;
        float o_ = lo ? pB : sB;
        c = fsig(f_)*c + fsig(i_)*ftanh(g_);
        float hn = fsig(o_)*ftanh(c);
        if (lo){
            hid[t*2*H + dir*H + gi] = hn;
            hs[gi] = hn;                   // same wave: in-order LDS, no barrier
        }
        g0 = n0; g1 = n1; n0 = p0; n1 = p1;
    }
}

// ---------------- si=0: rebuild nh in place = [beat_span | meas_span | nh_sec] -----
__global__ void k_spans(float* __restrict__ nh, const float* __restrict__ bh,
                        const float* __restrict__ mh,
                        const int* __restrict__ bn, const int* __restrict__ mn){
    int n = blockIdx.x, s = threadIdx.x;           // 320 threads
    float v;
    if (s < 128)      v = bh[bn[n]*128 + s];
    else if (s < 192) v = mh[mn[n]*64 + (s-128)];
    else              v = nh[n*SS + s];            // own-thread read-then-write: safe
    nh[n*SS + s] = v;
}

// ---------------- si=1: spans + final output fused ---------------------------------
__global__ void k_spans_out(const float* __restrict__ bh, const float* __restrict__ mh,
                            const float* __restrict__ nh, const float* __restrict__ nh2,
                            const int* __restrict__ bn, const int* __restrict__ mn,
                            float* __restrict__ out){
    int n = blockIdx.x, s = threadIdx.x;           // 448 threads
    float v;
    if (s < 128)      v = bh[bn[n]*128 + s];
    else if (s < 192) v = mh[mn[n]*64 + (s-128)];
    else if (s < 320) v = nh[n*SS + s];
    else              v = nh2[n*SS + 192 + (s-320)];
    out[n*448 + s] = v;
}

// ===========================================================================
extern "C" void kernel_launch(void* const* d_in, const int* in_sizes, int n_in,
                              void* d_out, int out_size, void* d_ws, size_t ws_size,
                              hipStream_t stream) {
    const float* nodes    = (const float*)d_in[0];
    const float* adj      = (const float*)d_in[1];
    const int*   bn       = (const int*)  d_in[2];
    const int*   mn       = (const int*)  d_in[3];
    const float* fc_w     = (const float*)d_in[6];
    const float* fc_b     = (const float*)d_in[7];
    const float* g_wz[2]  = {(const float*)d_in[8],  (const float*)d_in[17]};
    const float* g_wr[2]  = {(const float*)d_in[9],  (const float*)d_in[18]};
    const float* g_wh[2]  = {(const float*)d_in[10], (const float*)d_in[19]};
    const float* g_uz[2]  = {(const float*)d_in[11], (const float*)d_in[20]};
    const float* g_ur[2]  = {(const float*)d_in[12], (const float*)d_in[21]};
    const float* g_uh[2]  = {(const float*)d_in[13], (const float*)d_in[22]};
    const float* g_bz[2]  = {(const float*)d_in[14], (const float*)d_in[23]};
    const float* g_br[2]  = {(const float*)d_in[15], (const float*)d_in[24]};
    const float* g_bh[2]  = {(const float*)d_in[16], (const float*)d_in[25]};
    const float* gb_w     = (const float*)d_in[26];
    const float* gb_b     = (const float*)d_in[27];
    const float* batt_w   = (const float*)d_in[28];
    const float* batt_b   = (const float*)d_in[29];
    const float* batt_c   = (const float*)d_in[30];
    const float* matt_w   = (const float*)d_in[31];
    const float* matt_b   = (const float*)d_in[32];
    const float* matt_c   = (const float*)d_in[33];
    const float* bwi_f    = (const float*)d_in[34];
    const float* bwh_f    = (const float*)d_in[35];
    const float* bb_f     = (const float*)d_in[36];
    const float* bwi_b    = (const float*)d_in[37];
    const float* bwh_b    = (const float*)d_in[38];
    const float* bb_b     = (const float*)d_in[39];
    const float* mwi_f    = (const float*)d_in[40];
    const float* mwh_f    = (const float*)d_in[41];
    const float* mb_f     = (const float*)d_in[42];
    const float* mwi_b    = (const float*)d_in[43];
    const float* mwh_b    = (const float*)d_in[44];
    const float* mb_b     = (const float*)d_in[45];
    float* out = (float*)d_out;

    // --- workspace layout (floats; ~27.7 MB, under the 31.2MB proven in r0) ---
    float* W_   = (float*)d_ws;
    float* nh   = W_;                       // 1024*320
    float* nh2  = nh   + 327680;            // 1024*320
    float* act  = nh2  + 327680;            // 10*1024*320
    float* part = act  + 3276800;           // 10*1024*384 (slices 0-4 dyn, 5-9 static)
    float* bgf  = part + 3932160;           // 256*256
    float* bgb  = bgf  + 65536;             // 256*256
    float* beat_hidden = bgb + 65536;       // 256*128
    float* mgf  = beat_hidden + 32768;      // 64*128
    float* mgb  = mgf  + 8192;              // 64*128
    float* meas_hidden = mgb + 8192;        // 64*64
    int*   cnt  = (int*)(meas_hidden + 4096);  // 10*1024
    int*   idx  = cnt + 10240;                  // 10*1024*64

    float* part_s = part + 5*NN*384;        // static slices base (contiguous: 5-9)

    hipMemsetAsync(cnt, 0, EE*NN*sizeof(int), stream);
    k_csr_build<<<EE*NN, 256, 0, stream>>>(adj, cnt, idx);
    k_note_fc<<<NN, 128, 0, stream>>>(nodes, fc_w, fc_b, nh);

    for (int si = 0; si < 2; ++si){
        for (int half = 0; half < 2; ++half){
            float* x = half ? nh2 : nh;
            int w = half;                     // weight set index
            bool zerostatic = (si == 0 && half == 0);   // nh[:, :192] == 0
            if (half == 1)                    // nb = relu(nh @ gb_w) -> nh2
                k_gb<<<NN/4, 640, 0, stream>>>(nh, gb_w, gb_b, nh2);
            for (int it = 0; it < 2; ++it){
                if (!zerostatic && it == 0){
                    // one full 320-col gather; static+dyn gemms in ONE launch
                    k_gather_full<<<EE*NN/4, 320, 0, stream>>>(x, cnt, idx, act);
                    k_gate_gemm_both<<<dim3(32,6,5), 256, 0, stream>>>(
                            act, g_wz[w], g_wr[w], g_wh[w], part, part_s);
                } else {
                    k_gather_dyn<<<EE*NN/8, 256, 0, stream>>>(x, cnt, idx, act);
                    // it=1 (or zerostatic): dyn gemm, fold static via addv when present
                    k_gate_gemm_dyn<<<dim3(32,3,5), 256, 0, stream>>>(
                            act, g_wz[w], g_wr[w], g_wh[w], part,
                            zerostatic ? nullptr : part_s);
                }
                int nsp = (!zerostatic && it == 0) ? 10 : 5;
                k_gru<<<NN/2, 256, 0, stream>>>(x, part, nsp,
                        g_uz[w], g_ur[w], g_uh[w], g_bz[w], g_br[w], g_bh[w]);
            }
        }
        k_batt_fused<<<NB, 512, 0, stream>>>(nh, nh2, batt_w, batt_b, batt_c,
                                             bwi_f, bb_f, bwi_b, bb_b, bgf, bgb);
        k_lstm_rec64<<<2, 256, 0, stream>>>(bgf, bwh_f, bgb, bwh_b, beat_hidden);
        k_matt_fused<<<NM, 256, 0, stream>>>(beat_hidden, matt_w, matt_b, matt_c,
                                             mwi_f, mb_f, mwi_b, mb_b, mgf, mgb);
        k_lstm_rec32<<<2, 64, 0, stream>>>(mgf, mwh_f, mgb, mwh_b, meas_hidden);
        if (si == 0)
            k_spans<<<NN, SS, 0, stream>>>(nh, beat_hidden, meas_hidden, bn, mn);
        else
            k_spans_out<<<NN, 448, 0, stream>>>(beat_hidden, meas_hidden, nh, nh2,
                                                bn, mn, out);
    }
}

// Round 14
// 952.132 us; speedup vs baseline: 1.3536x; 1.0196x over previous
//
#include <hip/hip_runtime.h>
#include <math.h>

// ---------------------------------------------------------------------------
// IsgnBeatMeasEncoder — round 18: global_load_lds B-staging + gru quarter-split.
// Round-17: gb/batt/matt k-split = 999 -> 971 (matched). Remaining unfrozen
// blocks: gate_gemm (~200us, biggest), gru (~95), gathers (~100).
//   - gate_gemm: B LDS made exactly linear (stride 128, pad dropped; read
//     conflicts unchanged — all lanes read the same k-row). Staging via
//     __builtin_amdgcn_global_load_lds width=16: per wave both global src and
//     LDS dest are wave-uniform + lane*16B (the intrinsic's contract, m97).
//     Removes 4 float4 VGPR round-trips + 4 LDS writes /thread/kc x 11 calls.
//   - gru quarter-split (512 thr): k loops 64 -> 32/quarter; the 30-60 serial
//     m-slice loads move OFF the critical path to quarters 2-3, concurrent
//     with quarters 0-1's k-partials. 4-way LDS reduce; gates on quarter 0.
//   - all else frozen (rec64 @116us latency floor, VGPR-132 canary).
// Falsification: total >=962 -> both mechanisms exhausted; declare plateau.
// ---------------------------------------------------------------------------

#define NN    1024
#define EE    10
#define INDIM 78
#define SS    320
#define SECD  128
#define NB    256
#define NM    64
#define CAP   64     // max nonzeros per adjacency column (mean ~10.2)

typedef float v2f __attribute__((ext_vector_type(2)));

__device__ __forceinline__ void pkfma(v2f& a, v2f x, v2f y){
    asm("v_pk_fma_f32 %0, %1, %2, %0" : "+v"(a) : "v"(x), "v"(y));
}
// a.lo += x.lo*b.lo ; a.hi += x.hi*b.lo   (broadcast LOW half of b)
__device__ __forceinline__ void pkfma_blo(v2f& a, v2f x, v2f b){
    asm("v_pk_fma_f32 %0, %1, %2, %0 op_sel:[0,0,0] op_sel_hi:[1,0,1]"
        : "+v"(a) : "v"(x), "v"(b));
}
// a.lo += x.lo*b.hi ; a.hi += x.hi*b.hi   (broadcast HIGH half of b)
__device__ __forceinline__ void pkfma_bhi(v2f& a, v2f x, v2f b){
    asm("v_pk_fma_f32 %0, %1, %2, %0 op_sel:[0,1,0] op_sel_hi:[1,1,1]"
        : "+v"(a) : "v"(x), "v"(b));
}

#define LO2(F) ((v2f){F.x, F.y})
#define HI2(F) ((v2f){F.z, F.w})

__device__ __forceinline__ float fsig(float x){
    return __builtin_amdgcn_rcpf(1.f + __expf(-x));
}
__device__ __forceinline__ float ftanh(float x){
    // tanh(x) = 1 - 2/(exp(2x)+1); exp overflow -> inf -> rcp -> 0 -> 1 (correct)
    return 1.f - 2.f*__builtin_amdgcn_rcpf(1.f + __expf(2.f*x));
}

// ---------------- note_fc: x0 = tanh(nodes @ W + b); nh = [0(192) | x0] ------------
__global__ void k_note_fc(const float* __restrict__ nodes, const float* __restrict__ W,
                          const float* __restrict__ b, float* __restrict__ nh){
    int n = blockIdx.x, s = threadIdx.x;           // 128 threads
    __shared__ float xrow[INDIM];
    if (s < INDIM) xrow[s] = nodes[n*INDIM + s];
    __syncthreads();
    float acc = b[s];
    for (int k = 0; k < INDIM; ++k) acc += xrow[k]*W[k*128 + s];
    nh[n*SS + 192 + s] = ftanh(acc);
    nh[n*SS + s] = 0.f;
    if (s < 64) nh[n*SS + 128 + s] = 0.f;
}

// ---------------- CSR build: float4 scan of each adj row ---------------------------
__global__ void k_csr_build(const float* __restrict__ adj, int* __restrict__ cnt,
                            int* __restrict__ idx){
    int em = blockIdx.x;                   // e*NN + m  (row of adj[e])
    int e = em / NN, m = em % NN;
    const float4* row4 = (const float4*)(adj + (size_t)em * NN);
    int q = threadIdx.x;                   // 256 threads, 256 float4 = 1024 cols
    float4 v = row4[q];
    int n0 = q*4;
    if (v.x != 0.f){ int p = atomicAdd(&cnt[e*NN + n0+0], 1); if (p < CAP) idx[((size_t)e*NN + n0+0)*CAP + p] = m; }
    if (v.y != 0.f){ int p = atomicAdd(&cnt[e*NN + n0+1], 1); if (p < CAP) idx[((size_t)e*NN + n0+1)*CAP + p] = m; }
    if (v.z != 0.f){ int p = atomicAdd(&cnt[e*NN + n0+2], 1); if (p < CAP) idx[((size_t)e*NN + n0+2)*CAP + p] = m; }
    if (v.w != 0.f){ int p = atomicAdd(&cnt[e*NN + n0+3], 1); if (p < CAP) idx[((size_t)e*NN + n0+3)*CAP + p] = m; }
}

// ---------------- full gather (320 cols), float4: 80 quads/en, 4 en/block ----------
__global__ void k_gather_full(const float* __restrict__ x, const int* __restrict__ cnt,
                              const int* __restrict__ idx, float* __restrict__ act){
    int en = blockIdx.x*4 + threadIdx.x/80;        // 320 threads
    int q  = threadIdx.x % 80;
    int c = cnt[en]; if (c > CAP) c = CAP;
    const int* lst = idx + (size_t)en*CAP;
    float4 acc = {0.f,0.f,0.f,0.f};
    const float* xb = x + q*4;
    for (int j = 0; j < c; ++j){
        float4 v = *(const float4*)(xb + (size_t)lst[j]*SS);
        acc.x += v.x; acc.y += v.y; acc.z += v.z; acc.w += v.w;
    }
    *(float4*)(act + (size_t)en*SS + q*4) = acc;
}

// ---------------- dyn gather (cols 192..320), float4: 32 quads/en, 8 en/block ------
__global__ void k_gather_dyn(const float* __restrict__ x, const int* __restrict__ cnt,
                             const int* __restrict__ idx, float* __restrict__ act){
    int en = blockIdx.x*8 + (threadIdx.x >> 5);    // 256 threads
    int q  = threadIdx.x & 31;
    int c = cnt[en]; if (c > CAP) c = CAP;
    const int* lst = idx + (size_t)en*CAP;
    float4 acc = {0.f,0.f,0.f,0.f};
    const float* xb = x + 192 + q*4;
    for (int j = 0; j < c; ++j){
        float4 v = *(const float4*)(xb + (size_t)lst[j]*SS);
        acc.x += v.x; acc.y += v.y; acc.z += v.z; acc.w += v.w;
    }
    *(float4*)(act + (size_t)en*SS + 192 + q*4) = acc;
}

// ---------------- gate GEMM core (runtime K range) ---------------------------------
// B LDS layout: LINEAR stride 128 (no pad) -> staging via global_load_lds:
// per wave, global src and LDS dest are both wave-uniform + lane*16B.
__device__ __forceinline__ void gemm_body(const float* __restrict__ act,
        const float* __restrict__ W, float* __restrict__ outp,
        const float* __restrict__ addv, int K0, int K1, int nt, int z,
        float* A, float* B){
    int tid = threadIdx.x;
    int tx = tid & 31;             // cols tx*4 .. +3
    int ty = tid >> 5;             // rows ty*4 .. +3
    v2f acc[2][4];
    #pragma unroll
    for (int i=0;i<2;i++)
        #pragma unroll
        for (int j=0;j<4;j++) acc[i][j] = (v2f){0.f,0.f};
    for (int eh = 0; eh < 2; ++eh){
        int e = z*2 + eh;
        const float* Ae = act + (size_t)e*NN*SS + (size_t)nt*32*SS;
        const float* We = W   + (size_t)e*SS*SECD;
        for (int kc = K0; kc < K1; kc += 32){
            {                                      // A: 32 rows x 32 k = 256 float4
                int r  = tid >> 3;
                int k4 = (tid & 7) << 2;
                float4 v = *(const float4*)(Ae + r*SS + kc + k4);
                A[(k4+0)*36 + r] = v.x; A[(k4+1)*36 + r] = v.y;
                A[(k4+2)*36 + r] = v.z; A[(k4+3)*36 + r] = v.w;
            }
            #pragma unroll
            for (int i=0;i<4;i++){                 // B: 32 k x 128 cols, DMA to LDS
                int lin4 = tid + i*256;            // float4 index; linear in LDS
                __builtin_amdgcn_global_load_lds(
                    (const __attribute__((address_space(1))) unsigned int*)
                        (We + (size_t)kc*SECD + (size_t)lin4*4),
                    (__attribute__((address_space(3))) unsigned int*)(B + lin4*4),
                    16, 0, 0);
            }
            __syncthreads();                       // drains vmcnt+lgkm (B, A ready)
            #pragma unroll 8
            for (int k=0;k<32;k++){
                float4 a4 = *(const float4*)(A + k*36 + ty*4);   // wave-uniform b128
                v2f a01 = LO2(a4), a23 = HI2(a4);
                float4 b = *(const float4*)(B + k*128 + tx*4);
                v2f b01 = {b.x, b.y}, b23 = {b.z, b.w};
                pkfma_blo(acc[0][0], a01, b01); pkfma_bhi(acc[0][1], a01, b01);
                pkfma_blo(acc[0][2], a01, b23); pkfma_bhi(acc[0][3], a01, b23);
                pkfma_blo(acc[1][0], a23, b01); pkfma_bhi(acc[1][1], a23, b01);
                pkfma_blo(acc[1][2], a23, b23); pkfma_bhi(acc[1][3], a23, b23);
            }
            __syncthreads();
        }
    }
    size_t base = ((size_t)z*NN + (size_t)nt*32)*384;   // +g*SECD folded by caller
    float* P = outp + base;
    int r0 = ty*4;
    float4 o0 = make_float4(acc[0][0].x, acc[0][1].x, acc[0][2].x, acc[0][3].x);
    float4 o1 = make_float4(acc[0][0].y, acc[0][1].y, acc[0][2].y, acc[0][3].y);
    float4 o2 = make_float4(acc[1][0].x, acc[1][1].x, acc[1][2].x, acc[1][3].x);
    float4 o3 = make_float4(acc[1][0].y, acc[1][1].y, acc[1][2].y, acc[1][3].y);
    if (addv){
        const float* Q = addv + base;
        float4 q0 = *(const float4*)(Q + (size_t)(r0+0)*384 + tx*4);
        float4 q1 = *(const float4*)(Q + (size_t)(r0+1)*384 + tx*4);
        float4 q2 = *(const float4*)(Q + (size_t)(r0+2)*384 + tx*4);
        float4 q3 = *(const float4*)(Q + (size_t)(r0+3)*384 + tx*4);
        o0.x+=q0.x; o0.y+=q0.y; o0.z+=q0.z; o0.w+=q0.w;
        o1.x+=q1.x; o1.y+=q1.y; o1.z+=q1.z; o1.w+=q1.w;
        o2.x+=q2.x; o2.y+=q2.y; o2.z+=q2.z; o2.w+=q2.w;
        o3.x+=q3.x; o3.y+=q3.y; o3.z+=q3.z; o3.w+=q3.w;
    }
    *(float4*)(P + (size_t)(r0+0)*384 + tx*4) = o0;
    *(float4*)(P + (size_t)(r0+1)*384 + tx*4) = o1;
    *(float4*)(P + (size_t)(r0+2)*384 + tx*4) = o2;
    *(float4*)(P + (size_t)(r0+3)*384 + tx*4) = o3;
}

// dyn-only (with optional addv fold): grid (32,3,5)
__global__ __launch_bounds__(256) void k_gate_gemm_dyn(const float* __restrict__ act,
        const float* __restrict__ wz, const float* __restrict__ wr,
        const float* __restrict__ wh, float* __restrict__ part,
        const float* __restrict__ addv){
    __shared__ float A[32*36];
    __shared__ float B[32*128];
    int g = blockIdx.y;
    const float* W = (g==0) ? wz : ((g==1) ? wr : wh);
    const float* av = addv ? (addv + g*SECD) : nullptr;
    gemm_body(act, W, part + g*SECD, av, 192, 320, blockIdx.x, blockIdx.z, A, B);
}

// merged it=0: static (y<3 -> part_s, K 0..192) + dyn (y>=3 -> part, K 192..320),
// grid (32,6,5), no addv (gru reads 10 slices this iteration).
__global__ __launch_bounds__(256) void k_gate_gemm_both(const float* __restrict__ act,
        const float* __restrict__ wz, const float* __restrict__ wr,
        const float* __restrict__ wh, float* __restrict__ part,
        float* __restrict__ part_s){
    __shared__ float A[32*36];
    __shared__ float B[32*128];
    int y = blockIdx.y;            // 0..5
    int g = (y >= 3) ? (y - 3) : y;
    const float* W = (g==0) ? wz : ((g==1) ? wr : wh);
    if (y >= 3)
        gemm_body(act, W, part   + g*SECD, nullptr, 192, 320, blockIdx.x, blockIdx.z, A, B);
    else
        gemm_body(act, W, part_s + g*SECD, nullptr,   0, 192, blockIdx.x, blockIdx.z, A, B);
}

// ---------------- GRU update v3: 512 thr, 2 notes, k split across 4 quarters -------
// Quarter qh = tid>>7 (wave-pair-aligned). Quarters 0-3 each do 32 k-iters;
// the serial m-slice loads run on quarters 2,3 CONCURRENT with the k-partials
// (off the critical path). 4-way LDS reduce; gates on quarter 0.
__global__ __launch_bounds__(512) void k_gru(float* __restrict__ x,
        const float* __restrict__ part, int nsp,
        const float* __restrict__ uz, const float* __restrict__ ur, const float* __restrict__ uh,
        const float* __restrict__ bz, const float* __restrict__ br, const float* __restrict__ bh){
    int n0 = blockIdx.x*2;
    int tid = threadIdx.x;
    int s  = tid & 127;                // col
    int qh = tid >> 7;                 // quarter (wave-uniform)
    int k0 = qh*32;
    __shared__ float xs[2][SECD], rx[2][SECD];
    __shared__ float redz[4][2][SECD], redr[4][2][SECD];   // redz reused for dh
    __shared__ float redm[2][3][2][SECD];                  // [half][gate][note][col]
    if (qh == 0){
        xs[0][s] = x[(n0+0)*SS + 192 + s];
        xs[1][s] = x[(n0+1)*SS + 192 + s];
    }
    if (qh >= 2){                      // m-slice loads, split across quarters 2,3
        float mz[2]={0,0}, mr[2]={0,0}, mh[2]={0,0};
        for (int sp = qh-2; sp < nsp; sp += 2){
            const float* Pp = part + ((size_t)sp*NN + n0)*384;
            #pragma unroll
            for (int j=0;j<2;j++){
                mz[j] += Pp[j*384 + s];
                mr[j] += Pp[j*384 + 128 + s];
                mh[j] += Pp[j*384 + 256 + s];
            }
        }
        int hh = qh - 2;
        redm[hh][0][0][s]=mz[0]; redm[hh][0][1][s]=mz[1];
        redm[hh][1][0][s]=mr[0]; redm[hh][1][1][s]=mr[1];
        redm[hh][2][0][s]=mh[0]; redm[hh][2][1][s]=mh[1];
    }
    __syncthreads();                   // xs ready for all quarters
    float dz[2]={0,0}, dr[2]={0,0};
    #pragma unroll 8
    for (int k=k0;k<k0+32;k++){
        float wz_ = uz[k*SECD + s], wr_ = ur[k*SECD + s];
        #pragma unroll
        for (int j=0;j<2;j++){ float xv = xs[j][k]; dz[j] += xv*wz_; dr[j] += xv*wr_; }
    }
    redz[qh][0][s]=dz[0]; redz[qh][1][s]=dz[1];
    redr[qh][0][s]=dr[0]; redr[qh][1][s]=dr[1];
    __syncthreads();
    float zz[2], rr[2];
    if (qh == 0){
        #pragma unroll
        for (int j=0;j<2;j++){
            float mzf = redm[0][0][j][s] + redm[1][0][j][s];
            float mrf = redm[0][1][j][s] + redm[1][1][j][s];
            float dzf = (redz[0][j][s]+redz[1][j][s]) + (redz[2][j][s]+redz[3][j][s]);
            float drf = (redr[0][j][s]+redr[1][j][s]) + (redr[2][j][s]+redr[3][j][s]);
            zz[j] = fsig(mzf + dzf + bz[s]);
            rr[j] = fsig(mrf + drf + br[s]);
            rx[j][s] = rr[j]*xs[j][s];
        }
    }
    __syncthreads();
    float dh[2]={0,0};
    #pragma unroll 8
    for (int k=k0;k<k0+32;k++){
        float wh_ = uh[k*SECD + s];
        #pragma unroll
        for (int j=0;j<2;j++) dh[j] += rx[j][k]*wh_;
    }
    redz[qh][0][s]=dh[0]; redz[qh][1][s]=dh[1];
    __syncthreads();
    if (qh == 0){
        #pragma unroll
        for (int j=0;j<2;j++){
            float mhf = redm[0][2][j][s] + redm[1][2][j][s];
            float dhf = (redz[0][j][s]+redz[1][j][s]) + (redz[2][j][s]+redz[3][j][s]);
            float hc = ftanh(mhf + dhf + bh[s]);
            x[(n0+j)*SS + 192 + s] = (1.f - zz[j])*xs[j][s] + rr[j]*hc;
        }
    }
}

// ---------------- nb = relu(nh @ gb_w + gb_b) -> nh2; 640 thr, k split -------------
__global__ __launch_bounds__(640) void k_gb(const float* __restrict__ nh,
                     const float* __restrict__ W,
                     const float* __restrict__ b, float* __restrict__ nb){
    int n0 = blockIdx.x*4;
    int tid = threadIdx.x;
    int h = (tid >= 320) ? 1 : 0;
    int s = tid - h*320;
    int k0 = h*160;
    __shared__ float xr_t[SS*4];                   // [k][j]
    __shared__ float red[2][4][SS];                // [half][note][col]
    if (h == 0){
        float v0 = nh[(n0+0)*SS + s], v1 = nh[(n0+1)*SS + s];
        float v2 = nh[(n0+2)*SS + s], v3 = nh[(n0+3)*SS + s];
        *(float4*)(xr_t + s*4) = make_float4(v0,v1,v2,v3);
    }
    __syncthreads();
    v2f a01={0.f,0.f}, a23={0.f,0.f};
    #pragma unroll 8
    for (int k=k0;k<k0+160;k++){
        float wv = W[k*SS + s];
        v2f ws = {wv, wv};
        const v2f* xp = (const v2f*)(xr_t + k*4);  // uniform addr -> broadcast
        pkfma(a01, xp[0], ws);
        pkfma(a23, xp[1], ws);
    }
    red[h][0][s]=a01.x; red[h][1][s]=a01.y; red[h][2][s]=a23.x; red[h][3][s]=a23.y;
    __syncthreads();
    if (h == 0){
        float bv = b[s];
        nb[(n0+0)*SS + s] = fmaxf(bv + red[0][0][s] + red[1][0][s], 0.f);
        nb[(n0+1)*SS + s] = fmaxf(bv + red[0][1][s] + red[1][1][s], 0.f);
        nb[(n0+2)*SS + s] = fmaxf(bv + red[0][2][s] + red[1][2][s], 0.f);
        nb[(n0+3)*SS + s] = fmaxf(bv + red[0][3][s] + red[1][3][s], 0.f);
    }
}

// ---------------- FUSED beat attention + lstm_pre, 512 thr, two-stage k-split ------
__global__ __launch_bounds__(512) void k_batt_fused(
        const float* __restrict__ nh, const float* __restrict__ nh2,
        const float* __restrict__ W, const float* __restrict__ b,
        const float* __restrict__ cvec,
        const float* __restrict__ wi_f, const float* __restrict__ b_f,
        const float* __restrict__ wi_b, const float* __restrict__ b_b,
        float* __restrict__ gf, float* __restrict__ gbo){
    int g = blockIdx.x;
    int tid = threadIdx.x;
    int s = tid & 255;                             // col
    int h = tid >> 8;                              // k-half (wave-uniform)
    __shared__ float xr_t[256*4];                  // [k][j]
    __shared__ float simw[4][8];
    __shared__ float wgt[4][8];
    __shared__ float bnode[256];
    __shared__ float red[2][4][256];               // [half][j][col] (reused)
    if (h == 0){
        float c0,c1,c2,c3;
        if (s < 128){
            c0 = nh[(g*4+0)*SS + 192 + s]; c1 = nh[(g*4+1)*SS + 192 + s];
            c2 = nh[(g*4+2)*SS + 192 + s]; c3 = nh[(g*4+3)*SS + 192 + s];
        } else {
            c0 = nh2[(g*4+0)*SS + 64 + s]; c1 = nh2[(g*4+1)*SS + 64 + s];
            c2 = nh2[(g*4+2)*SS + 64 + s]; c3 = nh2[(g*4+3)*SS + 64 + s];
        }
        *(float4*)(xr_t + s*4) = make_float4(c0,c1,c2,c3);
    }
    __syncthreads();
    {   // main GEMV: k-half per thread-half
        int k0 = h*128;
        v2f ac01 = {0.f,0.f}, ac23 = {0.f,0.f};
        #pragma unroll 8
        for (int k=k0;k<k0+128;k++){
            float wv = W[k*256 + s];
            v2f ws = {wv, wv};
            const v2f* xp = (const v2f*)(xr_t + k*4);
            pkfma(ac01, xp[0], ws);
            pkfma(ac23, xp[1], ws);
        }
        red[h][0][s]=ac01.x; red[h][1][s]=ac01.y; red[h][2][s]=ac23.x; red[h][3][s]=ac23.y;
    }
    __syncthreads();
    int hd = s >> 5;                               // head (HD=32)
    if (h == 0){
        float bias = b[s];
        float cv = cvec[s];
        #pragma unroll
        for (int j=0;j<4;j++){
            float p = ftanh(bias + red[0][j][s] + red[1][j][s])*cv;
            #pragma unroll
            for (int off=16; off>0; off>>=1) p += __shfl_down(p, off);
            if ((s & 31) == 0) simw[j][hd] = p;
        }
    }
    __syncthreads();
    if (tid < 8){
        float v0=simw[0][tid], v1=simw[1][tid], v2=simw[2][tid], v3=simw[3][tid];
        float mx = fmaxf(fmaxf(v0,v1), fmaxf(v2,v3));
        float e0=__expf(v0-mx), e1=__expf(v1-mx), e2=__expf(v2-mx), e3=__expf(v3-mx);
        float den = e0+e1+e2+e3;
        wgt[0][tid]=e0/den; wgt[1][tid]=e1/den; wgt[2][tid]=e2/den; wgt[3][tid]=e3/den;
    }
    __syncthreads();
    if (h == 0){
        float4 xs4 = *(const float4*)(xr_t + s*4);
        bnode[s] = xs4.x*wgt[0][hd] + xs4.y*wgt[1][hd] + xs4.z*wgt[2][hd] + xs4.w*wgt[3][hd];
    }
    __syncthreads();
    {   // pre-GEMV, both directions, k-half per thread-half
        v2f afA = {0.f,0.f}, afB = {0.f,0.f};
        v2f abA = {0.f,0.f}, abB = {0.f,0.f};
        const v2f* wfp = (const v2f*)(wi_f + (size_t)s*256);
        const v2f* wbp = (const v2f*)(wi_b + (size_t)s*256);
        const v2f* bp  = (const v2f*)bnode;
        int q0 = h*64;
        #pragma unroll 8
        for (int k2=q0;k2<q0+64;k2+=2){
            v2f x01 = bp[k2], x23 = bp[k2+1];
            pkfma(afA, wfp[k2], x01); pkfma(afB, wfp[k2+1], x23);
            pkfma(abA, wbp[k2], x01); pkfma(abB, wbp[k2+1], x23);
        }
        red[h][0][s] = (afA.x + afA.y) + (afB.x + afB.y);
        red[h][1][s] = (abA.x + abA.y) + (abB.x + abB.y);
    }
    __syncthreads();
    if (h == 0){
        gf [g*256 + s] = b_f[s] + red[0][0][s] + red[1][0][s];
        gbo[g*256 + s] = b_b[s] + red[0][1][s] + red[1][1][s];
    }
}

// ---------------- FUSED measure attention + lstm_pre, 256 thr, two-stage split -----
__global__ __launch_bounds__(256) void k_matt_fused(
        const float* __restrict__ bh,   // beat_hidden [256][128]
        const float* __restrict__ W, const float* __restrict__ b,
        const float* __restrict__ cvec,
        const float* __restrict__ wi_f, const float* __restrict__ b_f,
        const float* __restrict__ wi_b, const float* __restrict__ b_b,
        float* __restrict__ gf, float* __restrict__ gbo){
    int g = blockIdx.x;
    int tid = threadIdx.x;
    int s = tid & 127;                             // col
    int h = tid >> 7;                              // k-half (wave-uniform)
    __shared__ float xr_t[128*4];                  // [k][j]
    __shared__ float simw[4][8];
    __shared__ float wgt[4][8];
    __shared__ float mnode[128];
    __shared__ float red[2][4][128];               // [half][j][col] (reused)
    if (h == 0){
        float c0 = bh[(g*4+0)*128 + s], c1 = bh[(g*4+1)*128 + s];
        float c2 = bh[(g*4+2)*128 + s], c3 = bh[(g*4+3)*128 + s];
        *(float4*)(xr_t + s*4) = make_float4(c0,c1,c2,c3);
    }
    __syncthreads();
    {   // main GEMV: k-half per thread-half
        int k0 = h*64;
        v2f ac01 = {0.f,0.f}, ac23 = {0.f,0.f};
        #pragma unroll 8
        for (int k=k0;k<k0+64;k++){
            float wv = W[k*128 + s];
            v2f ws = {wv, wv};
            const v2f* xp = (const v2f*)(xr_t + k*4);
            pkfma(ac01, xp[0], ws);
            pkfma(ac23, xp[1], ws);
        }
        red[h][0][s]=ac01.x; red[h][1][s]=ac01.y; red[h][2][s]=ac23.x; red[h][3][s]=ac23.y;
    }
    __syncthreads();
    int hd = s >> 4;                               // head (HD=16)
    if (h == 0){
        float bias = b[s];
        float cv = cvec[s];
        #pragma unroll
        for (int j=0;j<4;j++){
            float p = ftanh(bias + red[0][j][s] + red[1][j][s])*cv;
            #pragma unroll
            for (int off=8; off>0; off>>=1) p += __shfl_down(p, off);
            if ((s & 15) == 0) simw[j][hd] = p;
        }
    }
    __syncthreads();
    if (tid < 8){
        float v0=simw[0][tid], v1=simw[1][tid], v2=simw[2][tid], v3=simw[3][tid];
        float mx = fmaxf(fmaxf(v0,v1), fmaxf(v2,v3));
        float e0=__expf(v0-mx), e1=__expf(v1-mx), e2=__expf(v2-mx), e3=__expf(v3-mx);
        float den = e0+e1+e2+e3;
        wgt[0][tid]=e0/den; wgt[1][tid]=e1/den; wgt[2][tid]=e2/den; wgt[3][tid]=e3/den;
    }
    __syncthreads();
    if (h == 0){
        float4 xs4 = *(const float4*)(xr_t + s*4);
        mnode[s] = xs4.x*wgt[0][hd] + xs4.y*wgt[1][hd] + xs4.z*wgt[2][hd] + xs4.w*wgt[3][hd];
    }
    __syncthreads();
    {   // pre-GEMV, both directions, k-half per thread-half
        v2f afA = {0.f,0.f}, afB = {0.f,0.f};
        v2f abA = {0.f,0.f}, abB = {0.f,0.f};
        const v2f* wfp = (const v2f*)(wi_f + (size_t)s*128);
        const v2f* wbp = (const v2f*)(wi_b + (size_t)s*128);
        const v2f* bp  = (const v2f*)mnode;
        int q0 = h*32;
        #pragma unroll 8
        for (int k2=q0;k2<q0+32;k2+=2){
            v2f x01 = bp[k2], x23 = bp[k2+1];
            pkfma(afA, wfp[k2], x01); pkfma(afB, wfp[k2+1], x23);
            pkfma(abA, wbp[k2], x01); pkfma(abB, wbp[k2+1], x23);
        }
        red[h][0][s] = (afA.x + afA.y) + (afB.x + afB.y);
        red[h][1][s] = (abA.x + abA.y) + (abB.x + abB.y);
    }
    __syncthreads();
    if (h == 0){
        gf [g*128 + s] = b_f[s] + red[0][0][s] + red[1][0][s];
        gbo[g*128 + s] = b_b[s] + red[0][1][s] + red[1][1][s];
    }
}

// ---------------- LSTM recurrence, H=64 T=256: frozen r14 form ---------------------
__global__ __launch_bounds__(256)
__attribute__((amdgpu_waves_per_eu(1, 1)))
void k_lstm_rec64(
        const float* __restrict__ gin_f, const float* __restrict__ wh_f,
        const float* __restrict__ gin_b, const float* __restrict__ wh_b,
        float* __restrict__ hid /* [T][128] */){
    const int H = 64, T = 256;
    int dir = blockIdx.x;
    const float* gin = dir ? gin_b : gin_f;
    const float* wh  = dir ? wh_b  : wh_f;
    int gi = threadIdx.x;
    int w  = gi >> 6;                      // wave
    int j  = gi & 63;                      // lane
    int o  = j & 15;                       // h offset within wave's range
    int g  = j >> 4;                       // gate (0=i,1=f,2=g,3=o)
    int l  = (w << 4) + o;                 // h index
    int row = (g << 6) + l;                // gate row in [0,256)
    const v2f* wp = (const v2f*)(wh + (size_t)row*H);
    v2f w00=wp[0], w01=wp[1], w02=wp[2], w03=wp[3], w04=wp[4], w05=wp[5], w06=wp[6], w07=wp[7],
        w08=wp[8], w09=wp[9], w10=wp[10],w11=wp[11],w12=wp[12],w13=wp[13],w14=wp[14],w15=wp[15],
        w16=wp[16],w17=wp[17],w18=wp[18],w19=wp[19],w20=wp[20],w21=wp[21],w22=wp[22],w23=wp[23],
        w24=wp[24],w25=wp[25],w26=wp[26],w27=wp[27],w28=wp[28],w29=wp[29],w30=wp[30],w31=wp[31];
    __shared__ __align__(16) float hsb[2][H];
    float c = 0.f;
    if (gi < H) hsb[0][gi] = 0.f;
    __syncthreads();
    const float* gp = gin + row;
    float gcur = gp[(dir ? (T-1) : 0)*256];
    for (int step=0; step<T; step++){
        int t = dir ? (T-1-step) : step;
        float gnext = 0.f;
        if (step+1 < T) gnext = gp[(dir ? (T-2-step) : (step+1))*256];
        const float4* hv = (const float4*)hsb[step & 1];   // uniform addr, b128
        float4 H0=hv[0],  H1=hv[1],  H2=hv[2],  H3=hv[3];
        float4 H4=hv[4],  H5=hv[5],  H6=hv[6],  H7=hv[7];
        float4 H8=hv[8],  H9=hv[9],  H10=hv[10],H11=hv[11];
        float4 H12=hv[12],H13=hv[13],H14=hv[14],H15=hv[15];
        v2f A0={gcur,0.f}, A1={0.f,0.f}, A2={0.f,0.f}, A3={0.f,0.f};
        pkfma(A0,w00,LO2(H0));  pkfma(A1,w01,HI2(H0));  pkfma(A2,w02,LO2(H1));  pkfma(A3,w03,HI2(H1));
        pkfma(A0,w04,LO2(H2));  pkfma(A1,w05,HI2(H2));  pkfma(A2,w06,LO2(H3));  pkfma(A3,w07,HI2(H3));
        pkfma(A0,w08,LO2(H4));  pkfma(A1,w09,HI2(H4));  pkfma(A2,w10,LO2(H5));  pkfma(A3,w11,HI2(H5));
        pkfma(A0,w12,LO2(H6));  pkfma(A1,w13,HI2(H6));  pkfma(A2,w14,LO2(H7));  pkfma(A3,w15,HI2(H7));
        pkfma(A0,w16,LO2(H8));  pkfma(A1,w17,HI2(H8));  pkfma(A2,w18,LO2(H9));  pkfma(A3,w19,HI2(H9));
        pkfma(A0,w20,LO2(H10)); pkfma(A1,w21,HI2(H10)); pkfma(A2,w22,LO2(H11)); pkfma(A3,w23,HI2(H11));
        pkfma(A0,w24,LO2(H12)); pkfma(A1,w25,HI2(H12)); pkfma(A2,w26,LO2(H13)); pkfma(A3,w27,HI2(H13));
        pkfma(A0,w28,LO2(H14)); pkfma(A1,w29,HI2(H14)); pkfma(A2,w30,LO2(H15)); pkfma(A3,w31,HI2(H15));
        float val = ((A0.x+A0.y) + (A1.x+A1.y)) + ((A2.x+A2.y) + (A3.x+A3.y));
        // intra-wave gate exchange: i/f/g/o for h=l live in lanes o, o+16, o+32, o+48
        float i_ = __shfl(val, o);
        float f_ = __shfl(val, o + 16);
        float g_ = __shfl(val, o + 32);
        float o_ = __shfl(val, o + 48);
        c = fsig(f_)*c + fsig(i_)*ftanh(g_);   // 4 lanes per l: identical update
        float hn = fsig(o_)*ftanh(c);
        if (g == 0){
            hsb[(step+1)&1][l] = hn;           // partitioned write, other buffer
            hid[t*2*H + dir*H + l] = hn;
        }
        __syncthreads();                       // the ONLY barrier per step
        gcur = gnext;
    }
}

// ---------------- LSTM recurrence, H=32 T=64: single wave, NO barrier --------------
__global__ __launch_bounds__(64)
__attribute__((amdgpu_waves_per_eu(1, 1)))
void k_lstm_rec32(
        const float* __restrict__ gin_f, const float* __restrict__ wh_f,
        const float* __restrict__ gin_b, const float* __restrict__ wh_b,
        float* __restrict__ hid /* [T][64] */){
    const int H = 32, T = 64;
    int dir = blockIdx.x;
    const float* gin = dir ? gin_b : gin_f;
    const float* wh  = dir ? wh_b  : wh_f;
    int gi = threadIdx.x;                  // 0..63
    v2f wA[16], wB[16];
    {
        const v2f* rA = (const v2f*)(wh + (size_t)(     gi)*H);   // rows 0..63:  i|f
        const v2f* rB = (const v2f*)(wh + (size_t)(64 + gi)*H);   // rows 64..127: g|o
        #pragma unroll
        for (int k=0;k<16;k++){ wA[k]=rA[k]; wB[k]=rB[k]; }
    }
    __shared__ __align__(16) float hs[H];
    float c = 0.f;
    if (gi < H) hs[gi] = 0.f;
    __syncthreads();
    const float* gp = gin + gi;
    int ts0 = dir ? (T-1) : 0, ts1 = dir ? (T-2) : 1;
    float g0 = gp[ts0*128], g1 = gp[ts0*128 + 64];
    float n0 = gp[ts1*128], n1 = gp[ts1*128 + 64];
    bool lo = (gi < H);
    for (int step=0; step<T; step++){
        int t = dir ? (T-1-step) : step;
        float p0=0.f, p1=0.f;
        if (step+2 < T){
            int tp = dir ? (T-3-step) : (step+2);
            p0 = gp[tp*128]; p1 = gp[tp*128 + 64];
        }
        v2f aA = {g0, 0.f}, aB = {g1, 0.f};
        const float4* hv = (const float4*)hs;      // uniform addr, b128 reads
        #pragma unroll
        for (int k=0;k<8;k++){
            float4 h4 = hv[k];
            pkfma(aA, wA[2*k],   LO2(h4));
            pkfma(aB, wB[2*k],   LO2(h4));
            pkfma(aA, wA[2*k+1], HI2(h4));
            pkfma(aB, wB[2*k+1], HI2(h4));
        }
        float sA = aA.x + aA.y;            // lane<32: i ; lane>=32: f
        float sB = aB.x + aB.y;            // lane<32: g ; lane>=32: o
        float pA = __shfl(sA, gi ^ 32);
        float pB = __shfl(sB, gi ^ 32);
        float i_ = lo ? sA : pA;
        float f_ = lo ? pA : sA;
        float g_ = lo ? sB : pB;
        float o_ = lo ? pB : sB;
        c = fsig(f_)*c + fsig(i_)*ftanh(g_);
        float hn = fsig(o_)*ftanh(c);
        if (lo){
            hid[t*2*H + dir*H + gi] = hn;
            hs[gi] = hn;                   // same wave: in-order LDS, no barrier
        }
        g0 = n0; g1 = n1; n0 = p0; n1 = p1;
    }
}

// ---------------- si=0: rebuild nh in place = [beat_span | meas_span | nh_sec] -----
__global__ void k_spans(float* __restrict__ nh, const float* __restrict__ bh,
                        const float* __restrict__ mh,
                        const int* __restrict__ bn, const int* __restrict__ mn){
    int n = blockIdx.x, s = threadIdx.x;           // 320 threads
    float v;
    if (s < 128)      v = bh[bn[n]*128 + s];
    else if (s < 192) v = mh[mn[n]*64 + (s-128)];
    else              v = nh[n*SS + s];            // own-thread read-then-write: safe
    nh[n*SS + s] = v;
}

// ---------------- si=1: spans + final output fused ---------------------------------
__global__ void k_spans_out(const float* __restrict__ bh, const float* __restrict__ mh,
                            const float* __restrict__ nh, const float* __restrict__ nh2,
                            const int* __restrict__ bn, const int* __restrict__ mn,
                            float* __restrict__ out){
    int n = blockIdx.x, s = threadIdx.x;           // 448 threads
    float v;
    if (s < 128)      v = bh[bn[n]*128 + s];
    else if (s < 192) v = mh[mn[n]*64 + (s-128)];
    else if (s < 320) v = nh[n*SS + s];
    else              v = nh2[n*SS + 192 + (s-320)];
    out[n*448 + s] = v;
}

// ===========================================================================
extern "C" void kernel_launch(void* const* d_in, const int* in_sizes, int n_in,
                              void* d_out, int out_size, void* d_ws, size_t ws_size,
                              hipStream_t stream) {
    const float* nodes    = (const float*)d_in[0];
    const float* adj      = (const float*)d_in[1];
    const int*   bn       = (const int*)  d_in[2];
    const int*   mn       = (const int*)  d_in[3];
    const float* fc_w     = (const float*)d_in[6];
    const float* fc_b     = (const float*)d_in[7];
    const float* g_wz[2]  = {(const float*)d_in[8],  (const float*)d_in[17]};
    const float* g_wr[2]  = {(const float*)d_in[9],  (const float*)d_in[18]};
    const float* g_wh[2]  = {(const float*)d_in[10], (const float*)d_in[19]};
    const float* g_uz[2]  = {(const float*)d_in[11], (const float*)d_in[20]};
    const float* g_ur[2]  = {(const float*)d_in[12], (const float*)d_in[21]};
    const float* g_uh[2]  = {(const float*)d_in[13], (const float*)d_in[22]};
    const float* g_bz[2]  = {(const float*)d_in[14], (const float*)d_in[23]};
    const float* g_br[2]  = {(const float*)d_in[15], (const float*)d_in[24]};
    const float* g_bh[2]  = {(const float*)d_in[16], (const float*)d_in[25]};
    const float* gb_w     = (const float*)d_in[26];
    const float* gb_b     = (const float*)d_in[27];
    const float* batt_w   = (const float*)d_in[28];
    const float* batt_b   = (const float*)d_in[29];
    const float* batt_c   = (const float*)d_in[30];
    const float* matt_w   = (const float*)d_in[31];
    const float* matt_b   = (const float*)d_in[32];
    const float* matt_c   = (const float*)d_in[33];
    const float* bwi_f    = (const float*)d_in[34];
    const float* bwh_f    = (const float*)d_in[35];
    const float* bb_f     = (const float*)d_in[36];
    const float* bwi_b    = (const float*)d_in[37];
    const float* bwh_b    = (const float*)d_in[38];
    const float* bb_b     = (const float*)d_in[39];
    const float* mwi_f    = (const float*)d_in[40];
    const float* mwh_f    = (const float*)d_in[41];
    const float* mb_f     = (const float*)d_in[42];
    const float* mwi_b    = (const float*)d_in[43];
    const float* mwh_b    = (const float*)d_in[44];
    const float* mb_b     = (const float*)d_in[45];
    float* out = (float*)d_out;

    // --- workspace layout (floats; ~27.7 MB, under the 31.2MB proven in r0) ---
    float* W_   = (float*)d_ws;
    float* nh   = W_;                       // 1024*320
    float* nh2  = nh   + 327680;            // 1024*320
    float* act  = nh2  + 327680;            // 10*1024*320
    float* part = act  + 3276800;           // 10*1024*384 (slices 0-4 dyn, 5-9 static)
    float* bgf  = part + 3932160;           // 256*256
    float* bgb  = bgf  + 65536;             // 256*256
    float* beat_hidden = bgb + 65536;       // 256*128
    float* mgf  = beat_hidden + 32768;      // 64*128
    float* mgb  = mgf  + 8192;              // 64*128
    float* meas_hidden = mgb + 8192;        // 64*64
    int*   cnt  = (int*)(meas_hidden + 4096);  // 10*1024
    int*   idx  = cnt + 10240;                  // 10*1024*64

    float* part_s = part + 5*NN*384;        // static slices base (contiguous: 5-9)

    hipMemsetAsync(cnt, 0, EE*NN*sizeof(int), stream);
    k_csr_build<<<EE*NN, 256, 0, stream>>>(adj, cnt, idx);
    k_note_fc<<<NN, 128, 0, stream>>>(nodes, fc_w, fc_b, nh);

    for (int si = 0; si < 2; ++si){
        for (int half = 0; half < 2; ++half){
            float* x = half ? nh2 : nh;
            int w = half;                     // weight set index
            bool zerostatic = (si == 0 && half == 0);   // nh[:, :192] == 0
            if (half == 1)                    // nb = relu(nh @ gb_w) -> nh2
                k_gb<<<NN/4, 640, 0, stream>>>(nh, gb_w, gb_b, nh2);
            for (int it = 0; it < 2; ++it){
                if (!zerostatic && it == 0){
                    // one full 320-col gather; static+dyn gemms in ONE launch
                    k_gather_full<<<EE*NN/4, 320, 0, stream>>>(x, cnt, idx, act);
                    k_gate_gemm_both<<<dim3(32,6,5), 256, 0, stream>>>(
                            act, g_wz[w], g_wr[w], g_wh[w], part, part_s);
                } else {
                    k_gather_dyn<<<EE*NN/8, 256, 0, stream>>>(x, cnt, idx, act);
                    // it=1 (or zerostatic): dyn gemm, fold static via addv when present
                    k_gate_gemm_dyn<<<dim3(32,3,5), 256, 0, stream>>>(
                            act, g_wz[w], g_wr[w], g_wh[w], part,
                            zerostatic ? nullptr : part_s);
                }
                int nsp = (!zerostatic && it == 0) ? 10 : 5;
                k_gru<<<NN/2, 512, 0, stream>>>(x, part, nsp,
                        g_uz[w], g_ur[w], g_uh[w], g_bz[w], g_br[w], g_bh[w]);
            }
        }
        k_batt_fused<<<NB, 512, 0, stream>>>(nh, nh2, batt_w, batt_b, batt_c,
                                             bwi_f, bb_f, bwi_b, bb_b, bgf, bgb);
        k_lstm_rec64<<<2, 256, 0, stream>>>(bgf, bwh_f, bgb, bwh_b, beat_hidden);
        k_matt_fused<<<NM, 256, 0, stream>>>(beat_hidden, matt_w, matt_b, matt_c,
                                             mwi_f, mb_f, mwi_b, mb_b, mgf, mgb);
        k_lstm_rec32<<<2, 64, 0, stream>>>(mgf, mwh_f, mgb, mwh_b, meas_hidden);
        if (si == 0)
            k_spans<<<NN, SS, 0, stream>>>(nh, beat_hidden, meas_hidden, bn, mn);
        else
            k_spans_out<<<NN, 448, 0, stream>>>(beat_hidden, meas_hidden, nh, nh2,
                                                bn, mn, out);
    }
}

// Round 15
// 918.875 us; speedup vs baseline: 1.4026x; 1.0362x over previous
//
#include <hip/hip_runtime.h>
#include <math.h>

// ---------------------------------------------------------------------------
// IsgnBeatMeasEncoder — round 19: de-chain the CSR gathers.
// Round-18: global_load_lds B-staging + gru quarter-split = 971 -> 952
// (matched). Biggest untouched block: the 8 gather dispatches (~90-100us).
// Mechanism: runtime-c loop -> compiler can't unroll; in-order issue exposes
// a full global chain (lst[j] load -> x load -> acc) per iteration
// (~400-900cy x c~10 = the observed ~12us/dispatch).
// Round 19:
//   - en-group cooperatively caches its CSR list in LDS (one latency, not c
//     serial scalar loads); j-loop reads addresses from LDS.
//   - 4-way manual unroll: 4 independent x-loads issued back-to-back before
//     accumulation -> chain amortized 4x. (Pairwise-sum reorder within the
//     tolerance that has held through 12 reorderings.)
//   - all else frozen (rec64 @116us latency floor, VGPR-132 canary).
// Falsification: total >=945 -> gathers issue/BW-bound; declare plateau.
// ---------------------------------------------------------------------------

#define NN    1024
#define EE    10
#define INDIM 78
#define SS    320
#define SECD  128
#define NB    256
#define NM    64
#define CAP   64     // max nonzeros per adjacency column (mean ~10.2)

typedef float v2f __attribute__((ext_vector_type(2)));

__device__ __forceinline__ void pkfma(v2f& a, v2f x, v2f y){
    asm("v_pk_fma_f32 %0, %1, %2, %0" : "+v"(a) : "v"(x), "v"(y));
}
// a.lo += x.lo*b.lo ; a.hi += x.hi*b.lo   (broadcast LOW half of b)
__device__ __forceinline__ void pkfma_blo(v2f& a, v2f x, v2f b){
    asm("v_pk_fma_f32 %0, %1, %2, %0 op_sel:[0,0,0] op_sel_hi:[1,0,1]"
        : "+v"(a) : "v"(x), "v"(b));
}
// a.lo += x.lo*b.hi ; a.hi += x.hi*b.hi   (broadcast HIGH half of b)
__device__ __forceinline__ void pkfma_bhi(v2f& a, v2f x, v2f b){
    asm("v_pk_fma_f32 %0, %1, %2, %0 op_sel:[0,1,0] op_sel_hi:[1,1,1]"
        : "+v"(a) : "v"(x), "v"(b));
}

#define LO2(F) ((v2f){F.x, F.y})
#define HI2(F) ((v2f){F.z, F.w})

__device__ __forceinline__ float fsig(float x){
    return __builtin_amdgcn_rcpf(1.f + __expf(-x));
}
__device__ __forceinline__ float ftanh(float x){
    // tanh(x) = 1 - 2/(exp(2x)+1); exp overflow -> inf -> rcp -> 0 -> 1 (correct)
    return 1.f - 2.f*__builtin_amdgcn_rcpf(1.f + __expf(2.f*x));
}

// ---------------- note_fc: x0 = tanh(nodes @ W + b); nh = [0(192) | x0] ------------
__global__ void k_note_fc(const float* __restrict__ nodes, const float* __restrict__ W,
                          const float* __restrict__ b, float* __restrict__ nh){
    int n = blockIdx.x, s = threadIdx.x;           // 128 threads
    __shared__ float xrow[INDIM];
    if (s < INDIM) xrow[s] = nodes[n*INDIM + s];
    __syncthreads();
    float acc = b[s];
    for (int k = 0; k < INDIM; ++k) acc += xrow[k]*W[k*128 + s];
    nh[n*SS + 192 + s] = ftanh(acc);
    nh[n*SS + s] = 0.f;
    if (s < 64) nh[n*SS + 128 + s] = 0.f;
}

// ---------------- CSR build: float4 scan of each adj row ---------------------------
__global__ void k_csr_build(const float* __restrict__ adj, int* __restrict__ cnt,
                            int* __restrict__ idx){
    int em = blockIdx.x;                   // e*NN + m  (row of adj[e])
    int e = em / NN, m = em % NN;
    const float4* row4 = (const float4*)(adj + (size_t)em * NN);
    int q = threadIdx.x;                   // 256 threads, 256 float4 = 1024 cols
    float4 v = row4[q];
    int n0 = q*4;
    if (v.x != 0.f){ int p = atomicAdd(&cnt[e*NN + n0+0], 1); if (p < CAP) idx[((size_t)e*NN + n0+0)*CAP + p] = m; }
    if (v.y != 0.f){ int p = atomicAdd(&cnt[e*NN + n0+1], 1); if (p < CAP) idx[((size_t)e*NN + n0+1)*CAP + p] = m; }
    if (v.z != 0.f){ int p = atomicAdd(&cnt[e*NN + n0+2], 1); if (p < CAP) idx[((size_t)e*NN + n0+2)*CAP + p] = m; }
    if (v.w != 0.f){ int p = atomicAdd(&cnt[e*NN + n0+3], 1); if (p < CAP) idx[((size_t)e*NN + n0+3)*CAP + p] = m; }
}

// ---------------- full gather (320 cols): LDS list cache + 4-way prefetch ----------
// 4 en/block, 320 threads (80 quads per en).
__global__ void k_gather_full(const float* __restrict__ x, const int* __restrict__ cnt,
                              const int* __restrict__ idx, float* __restrict__ act){
    int tid = threadIdx.x;
    int eg = tid / 80;                     // en group 0..3
    int q  = tid % 80;
    int en = blockIdx.x*4 + eg;
    __shared__ int lst_l[4][CAP];
    int c = cnt[en]; if (c > CAP) c = CAP; // same addr per group -> broadcast
    for (int j = q; j < c; j += 80) lst_l[eg][j] = idx[(size_t)en*CAP + j];
    __syncthreads();
    float4 acc = {0.f,0.f,0.f,0.f};
    const float* xb = x + q*4;
    int j = 0;
    for (; j + 4 <= c; j += 4){            // 4 independent loads in flight
        int m0=lst_l[eg][j], m1=lst_l[eg][j+1], m2=lst_l[eg][j+2], m3=lst_l[eg][j+3];
        float4 v0 = *(const float4*)(xb + (size_t)m0*SS);
        float4 v1 = *(const float4*)(xb + (size_t)m1*SS);
        float4 v2 = *(const float4*)(xb + (size_t)m2*SS);
        float4 v3 = *(const float4*)(xb + (size_t)m3*SS);
        acc.x += (v0.x+v1.x)+(v2.x+v3.x);
        acc.y += (v0.y+v1.y)+(v2.y+v3.y);
        acc.z += (v0.z+v1.z)+(v2.z+v3.z);
        acc.w += (v0.w+v1.w)+(v2.w+v3.w);
    }
    for (; j < c; ++j){
        float4 v = *(const float4*)(xb + (size_t)lst_l[eg][j]*SS);
        acc.x += v.x; acc.y += v.y; acc.z += v.z; acc.w += v.w;
    }
    *(float4*)(act + (size_t)en*SS + q*4) = acc;
}

// ---------------- dyn gather (cols 192..320): LDS list cache + 4-way prefetch ------
// 8 en/block, 256 threads (32 quads per en).
__global__ void k_gather_dyn(const float* __restrict__ x, const int* __restrict__ cnt,
                             const int* __restrict__ idx, float* __restrict__ act){
    int tid = threadIdx.x;
    int eg = tid >> 5;                     // en group 0..7
    int q  = tid & 31;
    int en = blockIdx.x*8 + eg;
    __shared__ int lst_l[8][CAP];
    int c = cnt[en]; if (c > CAP) c = CAP;
    for (int j = q; j < c; j += 32) lst_l[eg][j] = idx[(size_t)en*CAP + j];
    __syncthreads();
    float4 acc = {0.f,0.f,0.f,0.f};
    const float* xb = x + 192 + q*4;
    int j = 0;
    for (; j + 4 <= c; j += 4){
        int m0=lst_l[eg][j], m1=lst_l[eg][j+1], m2=lst_l[eg][j+2], m3=lst_l[eg][j+3];
        float4 v0 = *(const float4*)(xb + (size_t)m0*SS);
        float4 v1 = *(const float4*)(xb + (size_t)m1*SS);
        float4 v2 = *(const float4*)(xb + (size_t)m2*SS);
        float4 v3 = *(const float4*)(xb + (size_t)m3*SS);
        acc.x += (v0.x+v1.x)+(v2.x+v3.x);
        acc.y += (v0.y+v1.y)+(v2.y+v3.y);
        acc.z += (v0.z+v1.z)+(v2.z+v3.z);
        acc.w += (v0.w+v1.w)+(v2.w+v3.w);
    }
    for (; j < c; ++j){
        float4 v = *(const float4*)(xb + (size_t)lst_l[eg][j]*SS);
        acc.x += v.x; acc.y += v.y; acc.z += v.z; acc.w += v.w;
    }
    *(float4*)(act + (size_t)en*SS + 192 + q*4) = acc;
}

// ---------------- gate GEMM core (runtime K range) ---------------------------------
// B LDS layout: LINEAR stride 128 (no pad) -> staging via global_load_lds:
// per wave, global src and LDS dest are both wave-uniform + lane*16B.
__device__ __forceinline__ void gemm_body(const float* __restrict__ act,
        const float* __restrict__ W, float* __restrict__ outp,
        const float* __restrict__ addv, int K0, int K1, int nt, int z,
        float* A, float* B){
    int tid = threadIdx.x;
    int tx = tid & 31;             // cols tx*4 .. +3
    int ty = tid >> 5;             // rows ty*4 .. +3
    v2f acc[2][4];
    #pragma unroll
    for (int i=0;i<2;i++)
        #pragma unroll
        for (int j=0;j<4;j++) acc[i][j] = (v2f){0.f,0.f};
    for (int eh = 0; eh < 2; ++eh){
        int e = z*2 + eh;
        const float* Ae = act + (size_t)e*NN*SS + (size_t)nt*32*SS;
        const float* We = W   + (size_t)e*SS*SECD;
        for (int kc = K0; kc < K1; kc += 32){
            {                                      // A: 32 rows x 32 k = 256 float4
                int r  = tid >> 3;
                int k4 = (tid & 7) << 2;
                float4 v = *(const float4*)(Ae + r*SS + kc + k4);
                A[(k4+0)*36 + r] = v.x; A[(k4+1)*36 + r] = v.y;
                A[(k4+2)*36 + r] = v.z; A[(k4+3)*36 + r] = v.w;
            }
            #pragma unroll
            for (int i=0;i<4;i++){                 // B: 32 k x 128 cols, DMA to LDS
                int lin4 = tid + i*256;            // float4 index; linear in LDS
                __builtin_amdgcn_global_load_lds(
                    (const __attribute__((address_space(1))) unsigned int*)
                        (We + (size_t)kc*SECD + (size_t)lin4*4),
                    (__attribute__((address_space(3))) unsigned int*)(B + lin4*4),
                    16, 0, 0);
            }
            __syncthreads();                       // drains vmcnt+lgkm (B, A ready)
            #pragma unroll 8
            for (int k=0;k<32;k++){
                float4 a4 = *(const float4*)(A + k*36 + ty*4);   // wave-uniform b128
                v2f a01 = LO2(a4), a23 = HI2(a4);
                float4 b = *(const float4*)(B + k*128 + tx*4);
                v2f b01 = {b.x, b.y}, b23 = {b.z, b.w};
                pkfma_blo(acc[0][0], a01, b01); pkfma_bhi(acc[0][1], a01, b01);
                pkfma_blo(acc[0][2], a01, b23); pkfma_bhi(acc[0][3], a01, b23);
                pkfma_blo(acc[1][0], a23, b01); pkfma_bhi(acc[1][1], a23, b01);
                pkfma_blo(acc[1][2], a23, b23); pkfma_bhi(acc[1][3], a23, b23);
            }
            __syncthreads();
        }
    }
    size_t base = ((size_t)z*NN + (size_t)nt*32)*384;   // +g*SECD folded by caller
    float* P = outp + base;
    int r0 = ty*4;
    float4 o0 = make_float4(acc[0][0].x, acc[0][1].x, acc[0][2].x, acc[0][3].x);
    float4 o1 = make_float4(acc[0][0].y, acc[0][1].y, acc[0][2].y, acc[0][3].y);
    float4 o2 = make_float4(acc[1][0].x, acc[1][1].x, acc[1][2].x, acc[1][3].x);
    float4 o3 = make_float4(acc[1][0].y, acc[1][1].y, acc[1][2].y, acc[1][3].y);
    if (addv){
        const float* Q = addv + base;
        float4 q0 = *(const float4*)(Q + (size_t)(r0+0)*384 + tx*4);
        float4 q1 = *(const float4*)(Q + (size_t)(r0+1)*384 + tx*4);
        float4 q2 = *(const float4*)(Q + (size_t)(r0+2)*384 + tx*4);
        float4 q3 = *(const float4*)(Q + (size_t)(r0+3)*384 + tx*4);
        o0.x+=q0.x; o0.y+=q0.y; o0.z+=q0.z; o0.w+=q0.w;
        o1.x+=q1.x; o1.y+=q1.y; o1.z+=q1.z; o1.w+=q1.w;
        o2.x+=q2.x; o2.y+=q2.y; o2.z+=q2.z; o2.w+=q2.w;
        o3.x+=q3.x; o3.y+=q3.y; o3.z+=q3.z; o3.w+=q3.w;
    }
    *(float4*)(P + (size_t)(r0+0)*384 + tx*4) = o0;
    *(float4*)(P + (size_t)(r0+1)*384 + tx*4) = o1;
    *(float4*)(P + (size_t)(r0+2)*384 + tx*4) = o2;
    *(float4*)(P + (size_t)(r0+3)*384 + tx*4) = o3;
}

// dyn-only (with optional addv fold): grid (32,3,5)
__global__ __launch_bounds__(256) void k_gate_gemm_dyn(const float* __restrict__ act,
        const float* __restrict__ wz, const float* __restrict__ wr,
        const float* __restrict__ wh, float* __restrict__ part,
        const float* __restrict__ addv){
    __shared__ float A[32*36];
    __shared__ float B[32*128];
    int g = blockIdx.y;
    const float* W = (g==0) ? wz : ((g==1) ? wr : wh);
    const float* av = addv ? (addv + g*SECD) : nullptr;
    gemm_body(act, W, part + g*SECD, av, 192, 320, blockIdx.x, blockIdx.z, A, B);
}

// merged it=0: static (y<3 -> part_s, K 0..192) + dyn (y>=3 -> part, K 192..320),
// grid (32,6,5), no addv (gru reads 10 slices this iteration).
__global__ __launch_bounds__(256) void k_gate_gemm_both(const float* __restrict__ act,
        const float* __restrict__ wz, const float* __restrict__ wr,
        const float* __restrict__ wh, float* __restrict__ part,
        float* __restrict__ part_s){
    __shared__ float A[32*36];
    __shared__ float B[32*128];
    int y = blockIdx.y;            // 0..5
    int g = (y >= 3) ? (y - 3) : y;
    const float* W = (g==0) ? wz : ((g==1) ? wr : wh);
    if (y >= 3)
        gemm_body(act, W, part   + g*SECD, nullptr, 192, 320, blockIdx.x, blockIdx.z, A, B);
    else
        gemm_body(act, W, part_s + g*SECD, nullptr,   0, 192, blockIdx.x, blockIdx.z, A, B);
}

// ---------------- GRU update v3: 512 thr, 2 notes, k split across 4 quarters -------
__global__ __launch_bounds__(512) void k_gru(float* __restrict__ x,
        const float* __restrict__ part, int nsp,
        const float* __restrict__ uz, const float* __restrict__ ur, const float* __restrict__ uh,
        const float* __restrict__ bz, const float* __restrict__ br, const float* __restrict__ bh){
    int n0 = blockIdx.x*2;
    int tid = threadIdx.x;
    int s  = tid & 127;                // col
    int qh = tid >> 7;                 // quarter (wave-uniform)
    int k0 = qh*32;
    __shared__ float xs[2][SECD], rx[2][SECD];
    __shared__ float redz[4][2][SECD], redr[4][2][SECD];   // redz reused for dh
    __shared__ float redm[2][3][2][SECD];                  // [half][gate][note][col]
    if (qh == 0){
        xs[0][s] = x[(n0+0)*SS + 192 + s];
        xs[1][s] = x[(n0+1)*SS + 192 + s];
    }
    if (qh >= 2){                      // m-slice loads, split across quarters 2,3
        float mz[2]={0,0}, mr[2]={0,0}, mh[2]={0,0};
        for (int sp = qh-2; sp < nsp; sp += 2){
            const float* Pp = part + ((size_t)sp*NN + n0)*384;
            #pragma unroll
            for (int j=0;j<2;j++){
                mz[j] += Pp[j*384 + s];
                mr[j] += Pp[j*384 + 128 + s];
                mh[j] += Pp[j*384 + 256 + s];
            }
        }
        int hh = qh - 2;
        redm[hh][0][0][s]=mz[0]; redm[hh][0][1][s]=mz[1];
        redm[hh][1][0][s]=mr[0]; redm[hh][1][1][s]=mr[1];
        redm[hh][2][0][s]=mh[0]; redm[hh][2][1][s]=mh[1];
    }
    __syncthreads();                   // xs ready for all quarters
    float dz[2]={0,0}, dr[2]={0,0};
    #pragma unroll 8
    for (int k=k0;k<k0+32;k++){
        float wz_ = uz[k*SECD + s], wr_ = ur[k*SECD + s];
        #pragma unroll
        for (int j=0;j<2;j++){ float xv = xs[j][k]; dz[j] += xv*wz_; dr[j] += xv*wr_; }
    }
    redz[qh][0][s]=dz[0]; redz[qh][1][s]=dz[1];
    redr[qh][0][s]=dr[0]; redr[qh][1][s]=dr[1];
    __syncthreads();
    float zz[2], rr[2];
    if (qh == 0){
        #pragma unroll
        for (int j=0;j<2;j++){
            float mzf = redm[0][0][j][s] + redm[1][0][j][s];
            float mrf = redm[0][1][j][s] + redm[1][1][j][s];
            float dzf = (redz[0][j][s]+redz[1][j][s]) + (redz[2][j][s]+redz[3][j][s]);
            float drf = (redr[0][j][s]+redr[1][j][s]) + (redr[2][j][s]+redr[3][j][s]);
            zz[j] = fsig(mzf + dzf + bz[s]);
            rr[j] = fsig(mrf + drf + br[s]);
            rx[j][s] = rr[j]*xs[j][s];
        }
    }
    __syncthreads();
    float dh[2]={0,0};
    #pragma unroll 8
    for (int k=k0;k<k0+32;k++){
        float wh_ = uh[k*SECD + s];
        #pragma unroll
        for (int j=0;j<2;j++) dh[j] += rx[j][k]*wh_;
    }
    redz[qh][0][s]=dh[0]; redz[qh][1][s]=dh[1];
    __syncthreads();
    if (qh == 0){
        #pragma unroll
        for (int j=0;j<2;j++){
            float mhf = redm[0][2][j][s] + redm[1][2][j][s];
            float dhf = (redz[0][j][s]+redz[1][j][s]) + (redz[2][j][s]+redz[3][j][s]);
            float hc = ftanh(mhf + dhf + bh[s]);
            x[(n0+j)*SS + 192 + s] = (1.f - zz[j])*xs[j][s] + rr[j]*hc;
        }
    }
}

// ---------------- nb = relu(nh @ gb_w + gb_b) -> nh2; 640 thr, k split -------------
__global__ __launch_bounds__(640) void k_gb(const float* __restrict__ nh,
                     const float* __restrict__ W,
                     const float* __restrict__ b, float* __restrict__ nb){
    int n0 = blockIdx.x*4;
    int tid = threadIdx.x;
    int h = (tid >= 320) ? 1 : 0;
    int s = tid - h*320;
    int k0 = h*160;
    __shared__ float xr_t[SS*4];                   // [k][j]
    __shared__ float red[2][4][SS];                // [half][note][col]
    if (h == 0){
        float v0 = nh[(n0+0)*SS + s], v1 = nh[(n0+1)*SS + s];
        float v2 = nh[(n0+2)*SS + s], v3 = nh[(n0+3)*SS + s];
        *(float4*)(xr_t + s*4) = make_float4(v0,v1,v2,v3);
    }
    __syncthreads();
    v2f a01={0.f,0.f}, a23={0.f,0.f};
    #pragma unroll 8
    for (int k=k0;k<k0+160;k++){
        float wv = W[k*SS + s];
        v2f ws = {wv, wv};
        const v2f* xp = (const v2f*)(xr_t + k*4);  // uniform addr -> broadcast
        pkfma(a01, xp[0], ws);
        pkfma(a23, xp[1], ws);
    }
    red[h][0][s]=a01.x; red[h][1][s]=a01.y; red[h][2][s]=a23.x; red[h][3][s]=a23.y;
    __syncthreads();
    if (h == 0){
        float bv = b[s];
        nb[(n0+0)*SS + s] = fmaxf(bv + red[0][0][s] + red[1][0][s], 0.f);
        nb[(n0+1)*SS + s] = fmaxf(bv + red[0][1][s] + red[1][1][s], 0.f);
        nb[(n0+2)*SS + s] = fmaxf(bv + red[0][2][s] + red[1][2][s], 0.f);
        nb[(n0+3)*SS + s] = fmaxf(bv + red[0][3][s] + red[1][3][s], 0.f);
    }
}

// ---------------- FUSED beat attention + lstm_pre, 512 thr, two-stage k-split ------
__global__ __launch_bounds__(512) void k_batt_fused(
        const float* __restrict__ nh, const float* __restrict__ nh2,
        const float* __restrict__ W, const float* __restrict__ b,
        const float* __restrict__ cvec,
        const float* __restrict__ wi_f, const float* __restrict__ b_f,
        const float* __restrict__ wi_b, const float* __restrict__ b_b,
        float* __restrict__ gf, float* __restrict__ gbo){
    int g = blockIdx.x;
    int tid = threadIdx.x;
    int s = tid & 255;                             // col
    int h = tid >> 8;                              // k-half (wave-uniform)
    __shared__ float xr_t[256*4];                  // [k][j]
    __shared__ float simw[4][8];
    __shared__ float wgt[4][8];
    __shared__ float bnode[256];
    __shared__ float red[2][4][256];               // [half][j][col] (reused)
    if (h == 0){
        float c0,c1,c2,c3;
        if (s < 128){
            c0 = nh[(g*4+0)*SS + 192 + s]; c1 = nh[(g*4+1)*SS + 192 + s];
            c2 = nh[(g*4+2)*SS + 192 + s]; c3 = nh[(g*4+3)*SS + 192 + s];
        } else {
            c0 = nh2[(g*4+0)*SS + 64 + s]; c1 = nh2[(g*4+1)*SS + 64 + s];
            c2 = nh2[(g*4+2)*SS + 64 + s]; c3 = nh2[(g*4+3)*SS + 64 + s];
        }
        *(float4*)(xr_t + s*4) = make_float4(c0,c1,c2,c3);
    }
    __syncthreads();
    {   // main GEMV: k-half per thread-half
        int k0 = h*128;
        v2f ac01 = {0.f,0.f}, ac23 = {0.f,0.f};
        #pragma unroll 8
        for (int k=k0;k<k0+128;k++){
            float wv = W[k*256 + s];
            v2f ws = {wv, wv};
            const v2f* xp = (const v2f*)(xr_t + k*4);
            pkfma(ac01, xp[0], ws);
            pkfma(ac23, xp[1], ws);
        }
        red[h][0][s]=ac01.x; red[h][1][s]=ac01.y; red[h][2][s]=ac23.x; red[h][3][s]=ac23.y;
    }
    __syncthreads();
    int hd = s >> 5;                               // head (HD=32)
    if (h == 0){
        float bias = b[s];
        float cv = cvec[s];
        #pragma unroll
        for (int j=0;j<4;j++){
            float p = ftanh(bias + red[0][j][s] + red[1][j][s])*cv;
            #pragma unroll
            for (int off=16; off>0; off>>=1) p += __shfl_down(p, off);
            if ((s & 31) == 0) simw[j][hd] = p;
        }
    }
    __syncthreads();
    if (tid < 8){
        float v0=simw[0][tid], v1=simw[1][tid], v2=simw[2][tid], v3=simw[3][tid];
        float mx = fmaxf(fmaxf(v0,v1), fmaxf(v2,v3));
        float e0=__expf(v0-mx), e1=__expf(v1-mx), e2=__expf(v2-mx), e3=__expf(v3-mx);
        float den = e0+e1+e2+e3;
        wgt[0][tid]=e0/den; wgt[1][tid]=e1/den; wgt[2][tid]=e2/den; wgt[3][tid]=e3/den;
    }
    __syncthreads();
    if (h == 0){
        float4 xs4 = *(const float4*)(xr_t + s*4);
        bnode[s] = xs4.x*wgt[0][hd] + xs4.y*wgt[1][hd] + xs4.z*wgt[2][hd] + xs4.w*wgt[3][hd];
    }
    __syncthreads();
    {   // pre-GEMV, both directions, k-half per thread-half
        v2f afA = {0.f,0.f}, afB = {0.f,0.f};
        v2f abA = {0.f,0.f}, abB = {0.f,0.f};
        const v2f* wfp = (const v2f*)(wi_f + (size_t)s*256);
        const v2f* wbp = (const v2f*)(wi_b + (size_t)s*256);
        const v2f* bp  = (const v2f*)bnode;
        int q0 = h*64;
        #pragma unroll 8
        for (int k2=q0;k2<q0+64;k2+=2){
            v2f x01 = bp[k2], x23 = bp[k2+1];
            pkfma(afA, wfp[k2], x01); pkfma(afB, wfp[k2+1], x23);
            pkfma(abA, wbp[k2], x01); pkfma(abB, wbp[k2+1], x23);
        }
        red[h][0][s] = (afA.x + afA.y) + (afB.x + afB.y);
        red[h][1][s] = (abA.x + abA.y) + (abB.x + abB.y);
    }
    __syncthreads();
    if (h == 0){
        gf [g*256 + s] = b_f[s] + red[0][0][s] + red[1][0][s];
        gbo[g*256 + s] = b_b[s] + red[0][1][s] + red[1][1][s];
    }
}

// ---------------- FUSED measure attention + lstm_pre, 256 thr, two-stage split -----
__global__ __launch_bounds__(256) void k_matt_fused(
        const float* __restrict__ bh,   // beat_hidden [256][128]
        const float* __restrict__ W, const float* __restrict__ b,
        const float* __restrict__ cvec,
        const float* __restrict__ wi_f, const float* __restrict__ b_f,
        const float* __restrict__ wi_b, const float* __restrict__ b_b,
        float* __restrict__ gf, float* __restrict__ gbo){
    int g = blockIdx.x;
    int tid = threadIdx.x;
    int s = tid & 127;                             // col
    int h = tid >> 7;                              // k-half (wave-uniform)
    __shared__ float xr_t[128*4];                  // [k][j]
    __shared__ float simw[4][8];
    __shared__ float wgt[4][8];
    __shared__ float mnode[128];
    __shared__ float red[2][4][128];               // [half][j][col] (reused)
    if (h == 0){
        float c0 = bh[(g*4+0)*128 + s], c1 = bh[(g*4+1)*128 + s];
        float c2 = bh[(g*4+2)*128 + s], c3 = bh[(g*4+3)*128 + s];
        *(float4*)(xr_t + s*4) = make_float4(c0,c1,c2,c3);
    }
    __syncthreads();
    {   // main GEMV: k-half per thread-half
        int k0 = h*64;
        v2f ac01 = {0.f,0.f}, ac23 = {0.f,0.f};
        #pragma unroll 8
        for (int k=k0;k<k0+64;k++){
            float wv = W[k*128 + s];
            v2f ws = {wv, wv};
            const v2f* xp = (const v2f*)(xr_t + k*4);
            pkfma(ac01, xp[0], ws);
            pkfma(ac23, xp[1], ws);
        }
        red[h][0][s]=ac01.x; red[h][1][s]=ac01.y; red[h][2][s]=ac23.x; red[h][3][s]=ac23.y;
    }
    __syncthreads();
    int hd = s >> 4;                               // head (HD=16)
    if (h == 0){
        float bias = b[s];
        float cv = cvec[s];
        #pragma unroll
        for (int j=0;j<4;j++){
            float p = ftanh(bias + red[0][j][s] + red[1][j][s])*cv;
            #pragma unroll
            for (int off=8; off>0; off>>=1) p += __shfl_down(p, off);
            if ((s & 15) == 0) simw[j][hd] = p;
        }
    }
    __syncthreads();
    if (tid < 8){
        float v0=simw[0][tid], v1=simw[1][tid], v2=simw[2][tid], v3=simw[3][tid];
        float mx = fmaxf(fmaxf(v0,v1), fmaxf(v2,v3));
        float e0=__expf(v0-mx), e1=__expf(v1-mx), e2=__expf(v2-mx), e3=__expf(v3-mx);
        float den = e0+e1+e2+e3;
        wgt[0][tid]=e0/den; wgt[1][tid]=e1/den; wgt[2][tid]=e2/den; wgt[3][tid]=e3/den;
    }
    __syncthreads();
    if (h == 0){
        float4 xs4 = *(const float4*)(xr_t + s*4);
        mnode[s] = xs4.x*wgt[0][hd] + xs4.y*wgt[1][hd] + xs4.z*wgt[2][hd] + xs4.w*wgt[3][hd];
    }
    __syncthreads();
    {   // pre-GEMV, both directions, k-half per thread-half
        v2f afA = {0.f,0.f}, afB = {0.f,0.f};
        v2f abA = {0.f,0.f}, abB = {0.f,0.f};
        const v2f* wfp = (const v2f*)(wi_f + (size_t)s*128);
        const v2f* wbp = (const v2f*)(wi_b + (size_t)s*128);
        const v2f* bp  = (const v2f*)mnode;
        int q0 = h*32;
        #pragma unroll 8
        for (int k2=q0;k2<q0+32;k2+=2){
            v2f x01 = bp[k2], x23 = bp[k2+1];
            pkfma(afA, wfp[k2], x01); pkfma(afB, wfp[k2+1], x23);
            pkfma(abA, wbp[k2], x01); pkfma(abB, wbp[k2+1], x23);
        }
        red[h][0][s] = (afA.x + afA.y) + (afB.x + afB.y);
        red[h][1][s] = (abA.x + abA.y) + (abB.x + abB.y);
    }
    __syncthreads();
    if (h == 0){
        gf [g*128 + s] = b_f[s] + red[0][0][s] + red[1][0][s];
        gbo[g*128 + s] = b_b[s] + red[0][1][s] + red[1][1][s];
    }
}

// ---------------- LSTM recurrence, H=64 T=256: frozen r14 form ---------------------
__global__ __launch_bounds__(256)
__attribute__((amdgpu_waves_per_eu(1, 1)))
void k_lstm_rec64(
        const float* __restrict__ gin_f, const float* __restrict__ wh_f,
        const float* __restrict__ gin_b, const float* __restrict__ wh_b,
        float* __restrict__ hid /* [T][128] */){
    const int H = 64, T = 256;
    int dir = blockIdx.x;
    const float* gin = dir ? gin_b : gin_f;
    const float* wh  = dir ? wh_b  : wh_f;
    int gi = threadIdx.x;
    int w  = gi >> 6;                      // wave
    int j  = gi & 63;                      // lane
    int o  = j & 15;                       // h offset within wave's range
    int g  = j >> 4;                       // gate (0=i,1=f,2=g,3=o)
    int l  = (w << 4) + o;                 // h index
    int row = (g << 6) + l;                // gate row in [0,256)
    const v2f* wp = (const v2f*)(wh + (size_t)row*H);
    v2f w00=wp[0], w01=wp[1], w02=wp[2], w03=wp[3], w04=wp[4], w05=wp[5], w06=wp[6], w07=wp[7],
        w08=wp[8], w09=wp[9], w10=wp[10],w11=wp[11],w12=wp[12],w13=wp[13],w14=wp[14],w15=wp[15],
        w16=wp[16],w17=wp[17],w18=wp[18],w19=wp[19],w20=wp[20],w21=wp[21],w22=wp[22],w23=wp[23],
        w24=wp[24],w25=wp[25],w26=wp[26],w27=wp[27],w28=wp[28],w29=wp[29],w30=wp[30],w31=wp[31];
    __shared__ __align__(16) float hsb[2][H];
    float c = 0.f;
    if (gi < H) hsb[0][gi] = 0.f;
    __syncthreads();
    const float* gp = gin + row;
    float gcur = gp[(dir ? (T-1) : 0)*256];
    for (int step=0; step<T; step++){
        int t = dir ? (T-1-step) : step;
        float gnext = 0.f;
        if (step+1 < T) gnext = gp[(dir ? (T-2-step) : (step+1))*256];
        const float4* hv = (const float4*)hsb[step & 1];   // uniform addr, b128
        float4 H0=hv[0],  H1=hv[1],  H2=hv[2],  H3=hv[3];
        float4 H4=hv[4],  H5=hv[5],  H6=hv[6],  H7=hv[7];
        float4 H8=hv[8],  H9=hv[9],  H10=hv[10],H11=hv[11];
        float4 H12=hv[12],H13=hv[13],H14=hv[14],H15=hv[15];
        v2f A0={gcur,0.f}, A1={0.f,0.f}, A2={0.f,0.f}, A3={0.f,0.f};
        pkfma(A0,w00,LO2(H0));  pkfma(A1,w01,HI2(H0));  pkfma(A2,w02,LO2(H1));  pkfma(A3,w03,HI2(H1));
        pkfma(A0,w04,LO2(H2));  pkfma(A1,w05,HI2(H2));  pkfma(A2,w06,LO2(H3));  pkfma(A3,w07,HI2(H3));
        pkfma(A0,w08,LO2(H4));  pkfma(A1,w09,HI2(H4));  pkfma(A2,w10,LO2(H5));  pkfma(A3,w11,HI2(H5));
        pkfma(A0,w12,LO2(H6));  pkfma(A1,w13,HI2(H6));  pkfma(A2,w14,LO2(H7));  pkfma(A3,w15,HI2(H7));
        pkfma(A0,w16,LO2(H8));  pkfma(A1,w17,HI2(H8));  pkfma(A2,w18,LO2(H9));  pkfma(A3,w19,HI2(H9));
        pkfma(A0,w20,LO2(H10)); pkfma(A1,w21,HI2(H10)); pkfma(A2,w22,LO2(H11)); pkfma(A3,w23,HI2(H11));
        pkfma(A0,w24,LO2(H12)); pkfma(A1,w25,HI2(H12)); pkfma(A2,w26,LO2(H13)); pkfma(A3,w27,HI2(H13));
        pkfma(A0,w28,LO2(H14)); pkfma(A1,w29,HI2(H14)); pkfma(A2,w30,LO2(H15)); pkfma(A3,w31,HI2(H15));
        float val = ((A0.x+A0.y) + (A1.x+A1.y)) + ((A2.x+A2.y) + (A3.x+A3.y));
        // intra-wave gate exchange: i/f/g/o for h=l live in lanes o, o+16, o+32, o+48
        float i_ = __shfl(val, o);
        float f_ = __shfl(val, o + 16);
        float g_ = __shfl(val, o + 32);
        float o_ = __shfl(val, o + 48);
        c = fsig(f_)*c + fsig(i_)*ftanh(g_);   // 4 lanes per l: identical update
        float hn = fsig(o_)*ftanh(c);
        if (g == 0){
            hsb[(step+1)&1][l] = hn;           // partitioned write, other buffer
            hid[t*2*H + dir*H + l] = hn;
        }
        __syncthreads();                       // the ONLY barrier per step
        gcur = gnext;
    }
}

// ---------------- LSTM recurrence, H=32 T=64: single wave, NO barrier --------------
__global__ __launch_bounds__(64)
__attribute__((amdgpu_waves_per_eu(1, 1)))
void k_lstm_rec32(
        const float* __restrict__ gin_f, const float* __restrict__ wh_f,
        const float* __restrict__ gin_b, const float* __restrict__ wh_b,
        float* __restrict__ hid /* [T][64] */){
    const int H = 32, T = 64;
    int dir = blockIdx.x;
    const float* gin = dir ? gin_b : gin_f;
    const float* wh  = dir ? wh_b  : wh_f;
    int gi = threadIdx.x;                  // 0..63
    v2f wA[16], wB[16];
    {
        const v2f* rA = (const v2f*)(wh + (size_t)(     gi)*H);   // rows 0..63:  i|f
        const v2f* rB = (const v2f*)(wh + (size_t)(64 + gi)*H);   // rows 64..127: g|o
        #pragma unroll
        for (int k=0;k<16;k++){ wA[k]=rA[k]; wB[k]=rB[k]; }
    }
    __shared__ __align__(16) float hs[H];
    float c = 0.f;
    if (gi < H) hs[gi] = 0.f;
    __syncthreads();
    const float* gp = gin + gi;
    int ts0 = dir ? (T-1) : 0, ts1 = dir ? (T-2) : 1;
    float g0 = gp[ts0*128], g1 = gp[ts0*128 + 64];
    float n0 = gp[ts1*128], n1 = gp[ts1*128 + 64];
    bool lo = (gi < H);
    for (int step=0; step<T; step++){
        int t = dir ? (T-1-step) : step;
        float p0=0.f, p1=0.f;
        if (step+2 < T){
            int tp = dir ? (T-3-step) : (step+2);
            p0 = gp[tp*128]; p1 = gp[tp*128 + 64];
        }
        v2f aA = {g0, 0.f}, aB = {g1, 0.f};
        const float4* hv = (const float4*)hs;      // uniform addr, b128 reads
        #pragma unroll
        for (int k=0;k<8;k++){
            float4 h4 = hv[k];
            pkfma(aA, wA[2*k],   LO2(h4));
            pkfma(aB, wB[2*k],   LO2(h4));
            pkfma(aA, wA[2*k+1], HI2(h4));
            pkfma(aB, wB[2*k+1], HI2(h4));
        }
        float sA = aA.x + aA.y;            // lane<32: i ; lane>=32: f
        float sB = aB.x + aB.y;            // lane<32: g ; lane>=32: o
        float pA = __shfl(sA, gi ^ 32);
        float pB = __shfl(sB, gi ^ 32);
        float i_ = lo ? sA : pA;
        float f_ = lo ? pA : sA;
        float g_ = lo ? sB : pB;
        float o_ = lo ? pB : sB;
        c = fsig(f_)*c + fsig(i_)*ftanh(g_);
        float hn = fsig(o_)*ftanh(c);
        if (lo){
            hid[t*2*H + dir*H + gi] = hn;
            hs[gi] = hn;                   // same wave: in-order LDS, no barrier
        }
        g0 = n0; g1 = n1; n0 = p0; n1 = p1;
    }
}

// ---------------- si=0: rebuild nh in place = [beat_span | meas_span | nh_sec] -----
__global__ void k_spans(float* __restrict__ nh, const float* __restrict__ bh,
                        const float* __restrict__ mh,
                        const int* __restrict__ bn, const int* __restrict__ mn){
    int n = blockIdx.x, s = threadIdx.x;           // 320 threads
    float v;
    if (s < 128)      v = bh[bn[n]*128 + s];
    else if (s < 192) v = mh[mn[n]*64 + (s-128)];
    else              v = nh[n*SS + s];            // own-thread read-then-write: safe
    nh[n*SS + s] = v;
}

// ---------------- si=1: spans + final output fused ---------------------------------
__global__ void k_spans_out(const float* __restrict__ bh, const float* __restrict__ mh,
                            const float* __restrict__ nh, const float* __restrict__ nh2,
                            const int* __restrict__ bn, const int* __restrict__ mn,
                            float* __restrict__ out){
    int n = blockIdx.x, s = threadIdx.x;           // 448 threads
    float v;
    if (s < 128)      v = bh[bn[n]*128 + s];
    else if (s < 192) v = mh[mn[n]*64 + (s-128)];
    else if (s < 320) v = nh[n*SS + s];
    else              v = nh2[n*SS + 192 + (s-320)];
    out[n*448 + s] = v;
}

// ===========================================================================
extern "C" void kernel_launch(void* const* d_in, const int* in_sizes, int n_in,
                              void* d_out, int out_size, void* d_ws, size_t ws_size,
                              hipStream_t stream) {
    const float* nodes    = (const float*)d_in[0];
    const float* adj      = (const float*)d_in[1];
    const int*   bn       = (const int*)  d_in[2];
    const int*   mn       = (const int*)  d_in[3];
    const float* fc_w     = (const float*)d_in[6];
    const float* fc_b     = (const float*)d_in[7];
    const float* g_wz[2]  = {(const float*)d_in[8],  (const float*)d_in[17]};
    const float* g_wr[2]  = {(const float*)d_in[9],  (const float*)d_in[18]};
    const float* g_wh[2]  = {(const float*)d_in[10], (const float*)d_in[19]};
    const float* g_uz[2]  = {(const float*)d_in[11], (const float*)d_in[20]};
    const float* g_ur[2]  = {(const float*)d_in[12], (const float*)d_in[21]};
    const float* g_uh[2]  = {(const float*)d_in[13], (const float*)d_in[22]};
    const float* g_bz[2]  = {(const float*)d_in[14], (const float*)d_in[23]};
    const float* g_br[2]  = {(const float*)d_in[15], (const float*)d_in[24]};
    const float* g_bh[2]  = {(const float*)d_in[16], (const float*)d_in[25]};
    const float* gb_w     = (const float*)d_in[26];
    const float* gb_b     = (const float*)d_in[27];
    const float* batt_w   = (const float*)d_in[28];
    const float* batt_b   = (const float*)d_in[29];
    const float* batt_c   = (const float*)d_in[30];
    const float* matt_w   = (const float*)d_in[31];
    const float* matt_b   = (const float*)d_in[32];
    const float* matt_c   = (const float*)d_in[33];
    const float* bwi_f    = (const float*)d_in[34];
    const float* bwh_f    = (const float*)d_in[35];
    const float* bb_f     = (const float*)d_in[36];
    const float* bwi_b    = (const float*)d_in[37];
    const float* bwh_b    = (const float*)d_in[38];
    const float* bb_b     = (const float*)d_in[39];
    const float* mwi_f    = (const float*)d_in[40];
    const float* mwh_f    = (const float*)d_in[41];
    const float* mb_f     = (const float*)d_in[42];
    const float* mwi_b    = (const float*)d_in[43];
    const float* mwh_b    = (const float*)d_in[44];
    const float* mb_b     = (const float*)d_in[45];
    float* out = (float*)d_out;

    // --- workspace layout (floats; ~27.7 MB, under the 31.2MB proven in r0) ---
    float* W_   = (float*)d_ws;
    float* nh   = W_;                       // 1024*320
    float* nh2  = nh   + 327680;            // 1024*320
    float* act  = nh2  + 327680;            // 10*1024*320
    float* part = act  + 3276800;           // 10*1024*384 (slices 0-4 dyn, 5-9 static)
    float* bgf  = part + 3932160;           // 256*256
    float* bgb  = bgf  + 65536;             // 256*256
    float* beat_hidden = bgb + 65536;       // 256*128
    float* mgf  = beat_hidden + 32768;      // 64*128
    float* mgb  = mgf  + 8192;              // 64*128
    float* meas_hidden = mgb + 8192;        // 64*64
    int*   cnt  = (int*)(meas_hidden + 4096);  // 10*1024
    int*   idx  = cnt + 10240;                  // 10*1024*64

    float* part_s = part + 5*NN*384;        // static slices base (contiguous: 5-9)

    hipMemsetAsync(cnt, 0, EE*NN*sizeof(int), stream);
    k_csr_build<<<EE*NN, 256, 0, stream>>>(adj, cnt, idx);
    k_note_fc<<<NN, 128, 0, stream>>>(nodes, fc_w, fc_b, nh);

    for (int si = 0; si < 2; ++si){
        for (int half = 0; half < 2; ++half){
            float* x = half ? nh2 : nh;
            int w = half;                     // weight set index
            bool zerostatic = (si == 0 && half == 0);   // nh[:, :192] == 0
            if (half == 1)                    // nb = relu(nh @ gb_w) -> nh2
                k_gb<<<NN/4, 640, 0, stream>>>(nh, gb_w, gb_b, nh2);
            for (int it = 0; it < 2; ++it){
                if (!zerostatic && it == 0){
                    // one full 320-col gather; static+dyn gemms in ONE launch
                    k_gather_full<<<EE*NN/4, 320, 0, stream>>>(x, cnt, idx, act);
                    k_gate_gemm_both<<<dim3(32,6,5), 256, 0, stream>>>(
                            act, g_wz[w], g_wr[w], g_wh[w], part, part_s);
                } else {
                    k_gather_dyn<<<EE*NN/8, 256, 0, stream>>>(x, cnt, idx, act);
                    // it=1 (or zerostatic): dyn gemm, fold static via addv when present
                    k_gate_gemm_dyn<<<dim3(32,3,5), 256, 0, stream>>>(
                            act, g_wz[w], g_wr[w], g_wh[w], part,
                            zerostatic ? nullptr : part_s);
                }
                int nsp = (!zerostatic && it == 0) ? 10 : 5;
                k_gru<<<NN/2, 512, 0, stream>>>(x, part, nsp,
                        g_uz[w], g_ur[w], g_uh[w], g_bz[w], g_br[w], g_bh[w]);
            }
        }
        k_batt_fused<<<NB, 512, 0, stream>>>(nh, nh2, batt_w, batt_b, batt_c,
                                             bwi_f, bb_f, bwi_b, bb_b, bgf, bgb);
        k_lstm_rec64<<<2, 256, 0, stream>>>(bgf, bwh_f, bgb, bwh_b, beat_hidden);
        k_matt_fused<<<NM, 256, 0, stream>>>(beat_hidden, matt_w, matt_b, matt_c,
                                             mwi_f, mb_f, mwi_b, mb_b, mgf, mgb);
        k_lstm_rec32<<<2, 64, 0, stream>>>(mgf, mwh_f, mgb, mwh_b, meas_hidden);
        if (si == 0)
            k_spans<<<NN, SS, 0, stream>>>(nh, beat_hidden, meas_hidden, bn, mn);
        else
            k_spans_out<<<NN, 448, 0, stream>>>(beat_hidden, meas_hidden, nh, nh2,
                                                bn, mn, out);
    }
}